// Round 1
// baseline (4158.948 us; speedup 1.0000x reference)
//
#include <hip/hip_runtime.h>

// ---------------- GEMM: C[M,N] = A[M,K] @ B[K,N], optional fused BN+ReLU on A ----
constexpr int BM = 64, BN_T = 64, BK = 16;

template<bool FUSE_BN>
__global__ __launch_bounds__(256) void gemm_f32(
    const float* __restrict__ A, const float* __restrict__ B,
    float* __restrict__ C, int M, int K, int N,
    const float* __restrict__ scsh)   // [K] scale, [K] shift (only if FUSE_BN)
{
  __shared__ float AsT[BK][BM];   // [k][m]
  __shared__ float Bs[BK][BN_T];  // [k][n]
  const int tid = threadIdx.x;
  const int tx = tid & 15;        // N dir (16)
  const int ty = tid >> 4;        // M dir (16)
  const int m0 = blockIdx.x * BM;
  const int n0 = blockIdx.y * BN_T;
  const int lm  = tid >> 2;            // 0..63  A-tile row
  const int lk4 = (tid & 3) * 4;       // 0,4,8,12 A-tile k chunk
  const int bk  = tid >> 4;            // 0..15  B-tile k row
  const int bn  = (tid & 15) * 4;      // B-tile col chunk

  float acc[4][4] = {};

  for (int k0 = 0; k0 < K; k0 += BK) {
    const int am = m0 + lm;
    float4 av = make_float4(0.f, 0.f, 0.f, 0.f);
    if (am < M) av = *(const float4*)&A[(size_t)am * K + k0 + lk4];
    if (FUSE_BN) {
      float4 sc = *(const float4*)&scsh[k0 + lk4];
      float4 sh = *(const float4*)&scsh[K + k0 + lk4];
      av.x = fmaxf(av.x * sc.x + sh.x, 0.f);
      av.y = fmaxf(av.y * sc.y + sh.y, 0.f);
      av.z = fmaxf(av.z * sc.z + sh.z, 0.f);
      av.w = fmaxf(av.w * sc.w + sh.w, 0.f);
    }
    AsT[lk4 + 0][lm] = av.x;
    AsT[lk4 + 1][lm] = av.y;
    AsT[lk4 + 2][lm] = av.z;
    AsT[lk4 + 3][lm] = av.w;
    *(float4*)&Bs[bk][bn] = *(const float4*)&B[(size_t)(k0 + bk) * N + n0 + bn];
    __syncthreads();
#pragma unroll
    for (int k = 0; k < BK; ++k) {
      float4 a4 = *(const float4*)&AsT[k][ty * 4];
      float4 b4 = *(const float4*)&Bs[k][tx * 4];
      float a[4] = {a4.x, a4.y, a4.z, a4.w};
      float b[4] = {b4.x, b4.y, b4.z, b4.w};
#pragma unroll
      for (int i = 0; i < 4; ++i)
#pragma unroll
        for (int j = 0; j < 4; ++j)
          acc[i][j] = fmaf(a[i], b[j], acc[i][j]);
    }
    __syncthreads();
  }
#pragma unroll
  for (int i = 0; i < 4; ++i) {
    int m = m0 + ty * 4 + i;
    if (m < M)
      *(float4*)&C[(size_t)m * N + n0 + tx * 4] =
          make_float4(acc[i][0], acc[i][1], acc[i][2], acc[i][3]);
  }
}

// ---------------- SpMM: out[rows[e],:] += vals[e] * D[cols[e],:]  (atomic) ------
template<int F>
__global__ __launch_bounds__(256) void spmm(
    const int* __restrict__ rows, const int* __restrict__ cols,
    const float* __restrict__ vals, const float* __restrict__ D,
    float* __restrict__ out, int E)
{
  constexpr int F4 = F / 4;
  int gid = blockIdx.x * 256 + threadIdx.x;
  int e = gid / F4;
  int f = (gid % F4) * 4;
  if (e >= E) return;
  int r = rows[e], c = cols[e];
  float v = vals[e];
  float4 d = *(const float4*)&D[(size_t)c * F + f];
  float* o = &out[(size_t)r * F + f];
  unsafeAtomicAdd(o + 0, v * d.x);
  unsafeAtomicAdd(o + 1, v * d.y);
  unsafeAtomicAdd(o + 2, v * d.z);
  unsafeAtomicAdd(o + 3, v * d.w);
}

// ---------------- BN stats: sums[0:C]=sum, sums[C:2C]=sumsq ----------------------
template<int C>
__global__ __launch_bounds__(256) void bn_stats(
    const float* __restrict__ H, float* __restrict__ sums, int Nrows)
{
  constexpr int C4 = C / 4;
  constexpr int RPB = 256 / C4;
  const int c = (threadIdx.x % C4) * 4;
  const int rr = threadIdx.x / C4;
  float4 s = make_float4(0.f, 0.f, 0.f, 0.f);
  float4 q = make_float4(0.f, 0.f, 0.f, 0.f);
  for (int r = blockIdx.x * RPB + rr; r < Nrows; r += gridDim.x * RPB) {
    float4 v = *(const float4*)&H[(size_t)r * C + c];
    s.x += v.x; s.y += v.y; s.z += v.z; s.w += v.w;
    q.x += v.x * v.x; q.y += v.y * v.y; q.z += v.z * v.z; q.w += v.w * v.w;
  }
  unsafeAtomicAdd(&sums[c + 0], s.x);
  unsafeAtomicAdd(&sums[c + 1], s.y);
  unsafeAtomicAdd(&sums[c + 2], s.z);
  unsafeAtomicAdd(&sums[c + 3], s.w);
  unsafeAtomicAdd(&sums[C + c + 0], q.x);
  unsafeAtomicAdd(&sums[C + c + 1], q.y);
  unsafeAtomicAdd(&sums[C + c + 2], q.z);
  unsafeAtomicAdd(&sums[C + c + 3], q.w);
}

// ---------------- BN finalize: scale = gamma*rstd, shift = beta - mean*scale ----
__global__ void bn_finalize(const float* __restrict__ sums,
    const float* __restrict__ gamma, const float* __restrict__ beta,
    float* __restrict__ scsh, int C, float invN)
{
  int c = threadIdx.x;
  if (c >= C) return;
  float mean = sums[c] * invN;
  float var = sums[C + c] * invN - mean * mean;
  float rstd = rsqrtf(var + 1e-5f);
  float sc = gamma[c] * rstd;
  scsh[c] = sc;
  scsh[C + c] = beta[c] - mean * sc;
}

// ---------------- BN2 apply + log_softmax (one 64-lane wave per row) ------------
__global__ __launch_bounds__(256) void bn_lsm(
    const float* __restrict__ H, const float* __restrict__ scsh,
    float* __restrict__ out, int Nrows)
{
  int lane = threadIdx.x & 63;
  int r = blockIdx.x * 4 + (threadIdx.x >> 6);
  if (r >= Nrows) return;
  float y = H[(size_t)r * 64 + lane] * scsh[lane] + scsh[64 + lane];
  float m = y;
#pragma unroll
  for (int off = 32; off >= 1; off >>= 1) m = fmaxf(m, __shfl_xor(m, off));
  float ex = expf(y - m);
  float s = ex;
#pragma unroll
  for (int off = 32; off >= 1; off >>= 1) s += __shfl_xor(s, off);
  out[(size_t)r * 64 + lane] = (y - m) - logf(s);
}

extern "C" void kernel_launch(void* const* d_in, const int* in_sizes, int n_in,
                              void* d_out, int out_size, void* d_ws, size_t ws_size,
                              hipStream_t stream) {
  const float* x      = (const float*)d_in[0];
  const int*   erow   = (const int*)  d_in[1];
  const int*   ecol   = (const int*)  d_in[2];
  const float* eval   = (const float*)d_in[3];
  const float* W1     = (const float*)d_in[4];
  // d_in[5] = b1 : added AFTER spmm, cancels exactly in training-mode BN (shift-invariant)
  const float* gamma1 = (const float*)d_in[6];
  const float* beta1  = (const float*)d_in[7];
  const float* W2     = (const float*)d_in[8];
  // d_in[9] = b2 : cancels in BN2
  const float* gamma2 = (const float*)d_in[10];
  const float* beta2  = (const float*)d_in[11];

  const int N = in_sizes[0] / 512;   // 50000
  const int E = in_sizes[1];         // 800000

  char* ws = (char*)d_ws;
  float* H1    = (float*)(ws + 0);            // 50000*256*4 = 51.2 MB
  float* H1AGG = (float*)(ws + 51200000);     // 51.2 MB
  float* H2    = (float*)(ws + 102400000);    // 12.8 MB
  float* H2AGG = (float*)(ws + 115200000);    // 12.8 MB
  float* ST    = (float*)(ws + 128000000);    // stats
  float* sums1 = ST;          // 512 floats (sum | sumsq)
  float* scsh1 = ST + 512;    // 512 floats (scale | shift)
  float* sums2 = ST + 1024;   // 128 floats
  float* scsh2 = ST + 1152;   // 128 floats

  hipMemsetAsync(H1AGG, 0, (size_t)N * 256 * 4, stream);
  hipMemsetAsync(H2AGG, 0, (size_t)N * 64 * 4, stream);
  hipMemsetAsync(ST, 0, 1280 * 4, stream);

  const dim3 blk(256);

  // layer 1: H1 = x @ W1
  gemm_f32<false><<<dim3((N + BM - 1) / BM, 256 / BN_T), blk, 0, stream>>>(
      x, W1, H1, N, 512, 256, nullptr);
  // H1AGG = A @ H1
  spmm<256><<<(E * 64 + 255) / 256, blk, 0, stream>>>(erow, ecol, eval, H1, H1AGG, E);
  // BN1 stats -> scale/shift
  bn_stats<256><<<256, blk, 0, stream>>>(H1AGG, sums1, N);
  bn_finalize<<<1, 256, 0, stream>>>(sums1, gamma1, beta1, scsh1, 256, 1.0f / N);
  // layer 2: H2 = relu(bn1(H1AGG)) @ W2   (BN+ReLU fused into A load)
  gemm_f32<true><<<dim3((N + BM - 1) / BM, 1), blk, 0, stream>>>(
      H1AGG, W2, H2, N, 256, 64, scsh1);
  // H2AGG = A @ H2
  spmm<64><<<(E * 16 + 255) / 256, blk, 0, stream>>>(erow, ecol, eval, H2, H2AGG, E);
  // BN2 stats -> scale/shift
  bn_stats<64><<<256, blk, 0, stream>>>(H2AGG, sums2, N);
  bn_finalize<<<1, 64, 0, stream>>>(sums2, gamma2, beta2, scsh2, 64, 1.0f / N);
  // BN2 apply + log_softmax
  bn_lsm<<<(N + 3) / 4, blk, 0, stream>>>(H2AGG, scsh2, (float*)d_out, N);
}

// Round 2
// 1188.841 us; speedup vs baseline: 3.4983x; 3.4983x over previous
//
#include <hip/hip_runtime.h>

// ---------------- GEMM: C[M,N] = A[M,K] @ B[K,N], optional fused BN+ReLU on A ----
constexpr int BM = 64, BN_T = 64, BK = 16;

template<bool FUSE_BN>
__global__ __launch_bounds__(256) void gemm_f32(
    const float* __restrict__ A, const float* __restrict__ B,
    float* __restrict__ C, int M, int K, int N,
    const float* __restrict__ scsh)   // [K] scale, [K] shift (only if FUSE_BN)
{
  __shared__ float AsT[BK][BM];   // [k][m]
  __shared__ float Bs[BK][BN_T];  // [k][n]
  const int tid = threadIdx.x;
  const int tx = tid & 15;        // N dir (16)
  const int ty = tid >> 4;        // M dir (16)
  const int m0 = blockIdx.x * BM;
  const int n0 = blockIdx.y * BN_T;
  const int lm  = tid >> 2;            // 0..63  A-tile row
  const int lk4 = (tid & 3) * 4;       // 0,4,8,12 A-tile k chunk
  const int bk  = tid >> 4;            // 0..15  B-tile k row
  const int bn  = (tid & 15) * 4;      // B-tile col chunk

  float acc[4][4] = {};

  for (int k0 = 0; k0 < K; k0 += BK) {
    const int am = m0 + lm;
    float4 av = make_float4(0.f, 0.f, 0.f, 0.f);
    if (am < M) av = *(const float4*)&A[(size_t)am * K + k0 + lk4];
    if (FUSE_BN) {
      float4 sc = *(const float4*)&scsh[k0 + lk4];
      float4 sh = *(const float4*)&scsh[K + k0 + lk4];
      av.x = fmaxf(av.x * sc.x + sh.x, 0.f);
      av.y = fmaxf(av.y * sc.y + sh.y, 0.f);
      av.z = fmaxf(av.z * sc.z + sh.z, 0.f);
      av.w = fmaxf(av.w * sc.w + sh.w, 0.f);
    }
    AsT[lk4 + 0][lm] = av.x;
    AsT[lk4 + 1][lm] = av.y;
    AsT[lk4 + 2][lm] = av.z;
    AsT[lk4 + 3][lm] = av.w;
    *(float4*)&Bs[bk][bn] = *(const float4*)&B[(size_t)(k0 + bk) * N + n0 + bn];
    __syncthreads();
#pragma unroll
    for (int k = 0; k < BK; ++k) {
      float4 a4 = *(const float4*)&AsT[k][ty * 4];
      float4 b4 = *(const float4*)&Bs[k][tx * 4];
      float a[4] = {a4.x, a4.y, a4.z, a4.w};
      float b[4] = {b4.x, b4.y, b4.z, b4.w};
#pragma unroll
      for (int i = 0; i < 4; ++i)
#pragma unroll
        for (int j = 0; j < 4; ++j)
          acc[i][j] = fmaf(a[i], b[j], acc[i][j]);
    }
    __syncthreads();
  }
#pragma unroll
  for (int i = 0; i < 4; ++i) {
    int m = m0 + ty * 4 + i;
    if (m < M)
      *(float4*)&C[(size_t)m * N + n0 + tx * 4] =
          make_float4(acc[i][0], acc[i][1], acc[i][2], acc[i][3]);
  }
}

// ---------------- CSR build: histogram -> scan -> scatter -----------------------
__global__ __launch_bounds__(256) void edge_hist(
    const int* __restrict__ rows, int* __restrict__ cnt, int E)
{
  int e = blockIdx.x * 256 + threadIdx.x;
  if (e < E) atomicAdd(&cnt[rows[e]], 1);
}

// single-block exclusive scan of cnt[0:N] -> rowptr[0:N], cursor[0:N]; rowptr[N]=E
__global__ __launch_bounds__(1024) void scan_rowptr(
    const int* __restrict__ cnt, int* __restrict__ rowptr,
    int* __restrict__ cursor, int Nrows, int E)
{
  __shared__ int lds[1024];
  const int t = threadIdx.x;
  const int CH = (Nrows + 1023) / 1024;
  const int start = t * CH;
  const int end = min(start + CH, Nrows);
  int s = 0;
  for (int i = start; i < end; ++i) s += cnt[i];
  lds[t] = s;
  __syncthreads();
  for (int off = 1; off < 1024; off <<= 1) {
    int u = (t >= off) ? lds[t - off] : 0;
    __syncthreads();
    lds[t] += u;
    __syncthreads();
  }
  int base = (t == 0) ? 0 : lds[t - 1];
  for (int i = start; i < end; ++i) {
    rowptr[i] = base;
    cursor[i] = base;
    base += cnt[i];
  }
  if (t == 0) rowptr[Nrows] = E;
}

__global__ __launch_bounds__(256) void edge_scatter(
    const int* __restrict__ rows, const int* __restrict__ cols,
    const float* __restrict__ vals, int* __restrict__ cursor,
    int* __restrict__ scols, float* __restrict__ svals, int E)
{
  int e = blockIdx.x * 256 + threadIdx.x;
  if (e < E) {
    int r = rows[e];
    int p = atomicAdd(&cursor[r], 1);
    scols[p] = cols[e];
    svals[p] = vals[e];
  }
}

// ---------------- SpMM gather: one wave per output row --------------------------
template<int F>
__global__ __launch_bounds__(256) void spmm_gather(
    const int* __restrict__ rowptr, const int* __restrict__ scols,
    const float* __restrict__ svals, const float* __restrict__ D,
    float* __restrict__ out, int Nrows)
{
  const int lane = threadIdx.x & 63;
  const int r = blockIdx.x * 4 + (threadIdx.x >> 6);
  if (r >= Nrows) return;
  const int s = rowptr[r], e = rowptr[r + 1];
  if (F == 256) {
    float4 acc = make_float4(0.f, 0.f, 0.f, 0.f);
    int j = s;
    for (; j + 1 < e; j += 2) {
      int c0 = scols[j], c1 = scols[j + 1];
      float v0 = svals[j], v1 = svals[j + 1];
      float4 d0 = *(const float4*)&D[(size_t)c0 * 256 + lane * 4];
      float4 d1 = *(const float4*)&D[(size_t)c1 * 256 + lane * 4];
      acc.x = fmaf(v0, d0.x, acc.x); acc.y = fmaf(v0, d0.y, acc.y);
      acc.z = fmaf(v0, d0.z, acc.z); acc.w = fmaf(v0, d0.w, acc.w);
      acc.x = fmaf(v1, d1.x, acc.x); acc.y = fmaf(v1, d1.y, acc.y);
      acc.z = fmaf(v1, d1.z, acc.z); acc.w = fmaf(v1, d1.w, acc.w);
    }
    if (j < e) {
      int c = scols[j]; float v = svals[j];
      float4 d = *(const float4*)&D[(size_t)c * 256 + lane * 4];
      acc.x = fmaf(v, d.x, acc.x); acc.y = fmaf(v, d.y, acc.y);
      acc.z = fmaf(v, d.z, acc.z); acc.w = fmaf(v, d.w, acc.w);
    }
    *(float4*)&out[(size_t)r * 256 + lane * 4] = acc;
  } else {
    float acc = 0.f;
    int j = s;
    for (; j + 1 < e; j += 2) {
      int c0 = scols[j], c1 = scols[j + 1];
      float v0 = svals[j], v1 = svals[j + 1];
      float d0 = D[(size_t)c0 * F + lane];
      float d1 = D[(size_t)c1 * F + lane];
      acc = fmaf(v0, d0, acc);
      acc = fmaf(v1, d1, acc);
    }
    if (j < e) acc = fmaf(svals[j], D[(size_t)scols[j] * F + lane], acc);
    out[(size_t)r * F + lane] = acc;
  }
}

// ---------------- BN stats: sums[0:C]=sum, sums[C:2C]=sumsq ----------------------
template<int C>
__global__ __launch_bounds__(256) void bn_stats(
    const float* __restrict__ H, float* __restrict__ sums, int Nrows)
{
  constexpr int C4 = C / 4;
  constexpr int RPB = 256 / C4;
  const int c = (threadIdx.x % C4) * 4;
  const int rr = threadIdx.x / C4;
  float4 s = make_float4(0.f, 0.f, 0.f, 0.f);
  float4 q = make_float4(0.f, 0.f, 0.f, 0.f);
  for (int r = blockIdx.x * RPB + rr; r < Nrows; r += gridDim.x * RPB) {
    float4 v = *(const float4*)&H[(size_t)r * C + c];
    s.x += v.x; s.y += v.y; s.z += v.z; s.w += v.w;
    q.x += v.x * v.x; q.y += v.y * v.y; q.z += v.z * v.z; q.w += v.w * v.w;
  }
  unsafeAtomicAdd(&sums[c + 0], s.x);
  unsafeAtomicAdd(&sums[c + 1], s.y);
  unsafeAtomicAdd(&sums[c + 2], s.z);
  unsafeAtomicAdd(&sums[c + 3], s.w);
  unsafeAtomicAdd(&sums[C + c + 0], q.x);
  unsafeAtomicAdd(&sums[C + c + 1], q.y);
  unsafeAtomicAdd(&sums[C + c + 2], q.z);
  unsafeAtomicAdd(&sums[C + c + 3], q.w);
}

// ---------------- BN finalize: scale = gamma*rstd, shift = beta - mean*scale ----
__global__ void bn_finalize(const float* __restrict__ sums,
    const float* __restrict__ gamma, const float* __restrict__ beta,
    float* __restrict__ scsh, int C, float invN)
{
  int c = threadIdx.x;
  if (c >= C) return;
  float mean = sums[c] * invN;
  float var = sums[C + c] * invN - mean * mean;
  float rstd = rsqrtf(var + 1e-5f);
  float sc = gamma[c] * rstd;
  scsh[c] = sc;
  scsh[C + c] = beta[c] - mean * sc;
}

// ---------------- BN2 apply + log_softmax (one 64-lane wave per row) ------------
__global__ __launch_bounds__(256) void bn_lsm(
    const float* __restrict__ H, const float* __restrict__ scsh,
    float* __restrict__ out, int Nrows)
{
  int lane = threadIdx.x & 63;
  int r = blockIdx.x * 4 + (threadIdx.x >> 6);
  if (r >= Nrows) return;
  float y = H[(size_t)r * 64 + lane] * scsh[lane] + scsh[64 + lane];
  float m = y;
#pragma unroll
  for (int off = 32; off >= 1; off >>= 1) m = fmaxf(m, __shfl_xor(m, off));
  float ex = expf(y - m);
  float s = ex;
#pragma unroll
  for (int off = 32; off >= 1; off >>= 1) s += __shfl_xor(s, off);
  out[(size_t)r * 64 + lane] = (y - m) - logf(s);
}

extern "C" void kernel_launch(void* const* d_in, const int* in_sizes, int n_in,
                              void* d_out, int out_size, void* d_ws, size_t ws_size,
                              hipStream_t stream) {
  const float* x      = (const float*)d_in[0];
  const int*   erow   = (const int*)  d_in[1];
  const int*   ecol   = (const int*)  d_in[2];
  const float* eval   = (const float*)d_in[3];
  const float* W1     = (const float*)d_in[4];
  // d_in[5] = b1 : added AFTER spmm, cancels exactly in training-mode BN (shift-invariant)
  const float* gamma1 = (const float*)d_in[6];
  const float* beta1  = (const float*)d_in[7];
  const float* W2     = (const float*)d_in[8];
  // d_in[9] = b2 : cancels in BN2
  const float* gamma2 = (const float*)d_in[10];
  const float* beta2  = (const float*)d_in[11];

  const int N = in_sizes[0] / 512;   // 50000
  const int E = in_sizes[1];         // 800000

  char* ws = (char*)d_ws;
  // H1 lives at [0, 51.2MB); after spmm1 it is dead and H2/H2AGG alias it.
  float* H1    = (float*)(ws + 0);              // 51.2 MB
  float* H2    = (float*)(ws + 0);              // 12.8 MB (aliases dead H1)
  float* H2AGG = (float*)(ws + 12800000);       // 12.8 MB (aliases dead H1)
  float* H1AGG = (float*)(ws + 51200000);       // 51.2 MB
  float* ST    = (float*)(ws + 102400000);      // 1280 floats
  float* sums1 = ST;          // 512 floats (sum | sumsq)
  float* scsh1 = ST + 512;    // 512 floats (scale | shift)
  float* sums2 = ST + 1024;   // 128 floats
  float* scsh2 = ST + 1152;   // 128 floats
  int*   rowptr = (int*)(ws + 102405120);       // N+1
  int*   cnt    = (int*)(ws + 102605124);       // N
  int*   cursor = (int*)(ws + 102805124);       // N
  int*   scols  = (int*)(ws + 103005124);       // E
  float* svals  = (float*)(ws + 106205124);     // E   (end ~109.4 MB)

  hipMemsetAsync(cnt, 0, (size_t)N * 4, stream);
  hipMemsetAsync(ST, 0, 1280 * 4, stream);

  const dim3 blk(256);
  const int eblocks = (E + 255) / 256;

  // CSR build (once per call; same graph reused by both spmm layers)
  edge_hist<<<eblocks, blk, 0, stream>>>(erow, cnt, E);
  scan_rowptr<<<1, 1024, 0, stream>>>(cnt, rowptr, cursor, N, E);
  edge_scatter<<<eblocks, blk, 0, stream>>>(erow, ecol, eval, cursor, scols, svals, E);

  // layer 1: H1 = x @ W1
  gemm_f32<false><<<dim3((N + BM - 1) / BM, 256 / BN_T), blk, 0, stream>>>(
      x, W1, H1, N, 512, 256, nullptr);
  // H1AGG = A @ H1 (gather, no atomics)
  spmm_gather<256><<<(N + 3) / 4, blk, 0, stream>>>(rowptr, scols, svals, H1, H1AGG, N);
  // BN1 stats -> scale/shift
  bn_stats<256><<<256, blk, 0, stream>>>(H1AGG, sums1, N);
  bn_finalize<<<1, 256, 0, stream>>>(sums1, gamma1, beta1, scsh1, 256, 1.0f / N);
  // layer 2: H2 = relu(bn1(H1AGG)) @ W2   (BN+ReLU fused into A load)
  gemm_f32<true><<<dim3((N + BM - 1) / BM, 1), blk, 0, stream>>>(
      H1AGG, W2, H2, N, 256, 64, scsh1);
  // H2AGG = A @ H2 (gather)
  spmm_gather<64><<<(N + 3) / 4, blk, 0, stream>>>(rowptr, scols, svals, H2, H2AGG, N);
  // BN2 stats -> scale/shift
  bn_stats<64><<<256, blk, 0, stream>>>(H2AGG, sums2, N);
  bn_finalize<<<1, 64, 0, stream>>>(sums2, gamma2, beta2, scsh2, 64, 1.0f / N);
  // BN2 apply + log_softmax
  bn_lsm<<<(N + 3) / 4, blk, 0, stream>>>(H2AGG, scsh2, (float*)d_out, N);
}

// Round 3
// 760.212 us; speedup vs baseline: 5.4708x; 1.5638x over previous
//
#include <hip/hip_runtime.h>

// ---------------- GEMM: C[M,N] = A[M,K] @ B[K,N], optional fused BN+ReLU on A ----
constexpr int BM = 64, BN_T = 64, BK = 16;

template<bool FUSE_BN>
__global__ __launch_bounds__(256) void gemm_f32(
    const float* __restrict__ A, const float* __restrict__ B,
    float* __restrict__ C, int M, int K, int N,
    const float* __restrict__ scsh)   // [K] scale, [K] shift (only if FUSE_BN)
{
  __shared__ float AsT[BK][BM];   // [k][m]
  __shared__ float Bs[BK][BN_T];  // [k][n]
  const int tid = threadIdx.x;
  const int tx = tid & 15;        // N dir (16)
  const int ty = tid >> 4;        // M dir (16)
  const int m0 = blockIdx.x * BM;
  const int n0 = blockIdx.y * BN_T;
  const int lm  = tid >> 2;            // 0..63  A-tile row
  const int lk4 = (tid & 3) * 4;       // 0,4,8,12 A-tile k chunk
  const int bk  = tid >> 4;            // 0..15  B-tile k row
  const int bn  = (tid & 15) * 4;      // B-tile col chunk

  float acc[4][4] = {};

  for (int k0 = 0; k0 < K; k0 += BK) {
    const int am = m0 + lm;
    float4 av = make_float4(0.f, 0.f, 0.f, 0.f);
    if (am < M) av = *(const float4*)&A[(size_t)am * K + k0 + lk4];
    if (FUSE_BN) {
      float4 sc = *(const float4*)&scsh[k0 + lk4];
      float4 sh = *(const float4*)&scsh[K + k0 + lk4];
      av.x = fmaxf(av.x * sc.x + sh.x, 0.f);
      av.y = fmaxf(av.y * sc.y + sh.y, 0.f);
      av.z = fmaxf(av.z * sc.z + sh.z, 0.f);
      av.w = fmaxf(av.w * sc.w + sh.w, 0.f);
    }
    AsT[lk4 + 0][lm] = av.x;
    AsT[lk4 + 1][lm] = av.y;
    AsT[lk4 + 2][lm] = av.z;
    AsT[lk4 + 3][lm] = av.w;
    *(float4*)&Bs[bk][bn] = *(const float4*)&B[(size_t)(k0 + bk) * N + n0 + bn];
    __syncthreads();
#pragma unroll
    for (int k = 0; k < BK; ++k) {
      float4 a4 = *(const float4*)&AsT[k][ty * 4];
      float4 b4 = *(const float4*)&Bs[k][tx * 4];
      float a[4] = {a4.x, a4.y, a4.z, a4.w};
      float b[4] = {b4.x, b4.y, b4.z, b4.w};
#pragma unroll
      for (int i = 0; i < 4; ++i)
#pragma unroll
        for (int j = 0; j < 4; ++j)
          acc[i][j] = fmaf(a[i], b[j], acc[i][j]);
    }
    __syncthreads();
  }
#pragma unroll
  for (int i = 0; i < 4; ++i) {
    int m = m0 + ty * 4 + i;
    if (m < M)
      *(float4*)&C[(size_t)m * N + n0 + tx * 4] =
          make_float4(acc[i][0], acc[i][1], acc[i][2], acc[i][3]);
  }
}

// ---------------- CSR build: histogram -> scan -> scatter -----------------------
__global__ __launch_bounds__(256) void edge_hist(
    const int* __restrict__ rows, int* __restrict__ cnt, int E)
{
  int e = blockIdx.x * 256 + threadIdx.x;
  if (e < E) atomicAdd(&cnt[rows[e]], 1);
}

// single-block exclusive scan of cnt[0:N] -> rowptr[0:N], cursor[0:N]; rowptr[N]=E
__global__ __launch_bounds__(1024) void scan_rowptr(
    const int* __restrict__ cnt, int* __restrict__ rowptr,
    int* __restrict__ cursor, int Nrows, int E)
{
  __shared__ int lds[1024];
  const int t = threadIdx.x;
  const int CH = (Nrows + 1023) / 1024;
  const int start = t * CH;
  const int end = min(start + CH, Nrows);
  int s = 0;
  for (int i = start; i < end; ++i) s += cnt[i];
  lds[t] = s;
  __syncthreads();
  for (int off = 1; off < 1024; off <<= 1) {
    int u = (t >= off) ? lds[t - off] : 0;
    __syncthreads();
    lds[t] += u;
    __syncthreads();
  }
  int base = (t == 0) ? 0 : lds[t - 1];
  for (int i = start; i < end; ++i) {
    rowptr[i] = base;
    cursor[i] = base;
    base += cnt[i];
  }
  if (t == 0) rowptr[Nrows] = E;
}

__global__ __launch_bounds__(256) void edge_scatter(
    const int* __restrict__ rows, const int* __restrict__ cols,
    const float* __restrict__ vals, int* __restrict__ cursor,
    int* __restrict__ scols, float* __restrict__ svals, int E)
{
  int e = blockIdx.x * 256 + threadIdx.x;
  if (e < E) {
    int r = rows[e];
    int p = atomicAdd(&cursor[r], 1);
    scols[p] = cols[e];
    svals[p] = vals[e];
  }
}

// ---------------- SpMM gather: one wave per output row --------------------------
template<int F>
__global__ __launch_bounds__(256) void spmm_gather(
    const int* __restrict__ rowptr, const int* __restrict__ scols,
    const float* __restrict__ svals, const float* __restrict__ D,
    float* __restrict__ out, int Nrows)
{
  const int lane = threadIdx.x & 63;
  const int r = blockIdx.x * 4 + (threadIdx.x >> 6);
  if (r >= Nrows) return;
  const int s = rowptr[r], e = rowptr[r + 1];
  if (F == 256) {
    float4 acc = make_float4(0.f, 0.f, 0.f, 0.f);
    int j = s;
    for (; j + 1 < e; j += 2) {
      int c0 = scols[j], c1 = scols[j + 1];
      float v0 = svals[j], v1 = svals[j + 1];
      float4 d0 = *(const float4*)&D[(size_t)c0 * 256 + lane * 4];
      float4 d1 = *(const float4*)&D[(size_t)c1 * 256 + lane * 4];
      acc.x = fmaf(v0, d0.x, acc.x); acc.y = fmaf(v0, d0.y, acc.y);
      acc.z = fmaf(v0, d0.z, acc.z); acc.w = fmaf(v0, d0.w, acc.w);
      acc.x = fmaf(v1, d1.x, acc.x); acc.y = fmaf(v1, d1.y, acc.y);
      acc.z = fmaf(v1, d1.z, acc.z); acc.w = fmaf(v1, d1.w, acc.w);
    }
    if (j < e) {
      int c = scols[j]; float v = svals[j];
      float4 d = *(const float4*)&D[(size_t)c * 256 + lane * 4];
      acc.x = fmaf(v, d.x, acc.x); acc.y = fmaf(v, d.y, acc.y);
      acc.z = fmaf(v, d.z, acc.z); acc.w = fmaf(v, d.w, acc.w);
    }
    *(float4*)&out[(size_t)r * 256 + lane * 4] = acc;
  } else {
    float acc = 0.f;
    int j = s;
    for (; j + 1 < e; j += 2) {
      int c0 = scols[j], c1 = scols[j + 1];
      float v0 = svals[j], v1 = svals[j + 1];
      float d0 = D[(size_t)c0 * F + lane];
      float d1 = D[(size_t)c1 * F + lane];
      acc = fmaf(v0, d0, acc);
      acc = fmaf(v1, d1, acc);
    }
    if (j < e) acc = fmaf(svals[j], D[(size_t)scols[j] * F + lane], acc);
    out[(size_t)r * F + lane] = acc;
  }
}

// ---------------- BN stats: per-block partials, NO atomics ----------------------
// partials[blockIdx*2C + 0:C]   = block-partial sum per column
// partials[blockIdx*2C + C:2C]  = block-partial sumsq per column
template<int C>
__global__ __launch_bounds__(256) void bn_stats(
    const float* __restrict__ H, float* __restrict__ partials, int Nrows)
{
  constexpr int C4 = C / 4;
  constexpr int RPB = 256 / C4;
  const int cc = threadIdx.x % C4;
  const int c = cc * 4;
  const int rr = threadIdx.x / C4;
  float4 s = make_float4(0.f, 0.f, 0.f, 0.f);
  float4 q = make_float4(0.f, 0.f, 0.f, 0.f);
  for (int r = blockIdx.x * RPB + rr; r < Nrows; r += gridDim.x * RPB) {
    float4 v = *(const float4*)&H[(size_t)r * C + c];
    s.x += v.x; s.y += v.y; s.z += v.z; s.w += v.w;
    q.x += v.x * v.x; q.y += v.y * v.y; q.z += v.z * v.z; q.w += v.w * v.w;
  }
  __shared__ float lds[256][8];
  float* L = lds[threadIdx.x];
  L[0] = s.x; L[1] = s.y; L[2] = s.z; L[3] = s.w;
  L[4] = q.x; L[5] = q.y; L[6] = q.z; L[7] = q.w;
  __syncthreads();
  if (rr == 0) {
#pragma unroll
    for (int r = 1; r < RPB; ++r) {
      float* M = lds[cc + r * C4];
      s.x += M[0]; s.y += M[1]; s.z += M[2]; s.w += M[3];
      q.x += M[4]; q.y += M[5]; q.z += M[6]; q.w += M[7];
    }
    float* P = &partials[(size_t)blockIdx.x * 2 * C];
    *(float4*)&P[c] = s;
    *(float4*)&P[C + c] = q;
  }
}

// ---------------- BN finalize: reduce partials; scale/shift ---------------------
__global__ void bn_finalize(const float* __restrict__ partials,
    const float* __restrict__ gamma, const float* __restrict__ beta,
    float* __restrict__ scsh, int C, int G, float invN)
{
  int c = threadIdx.x;
  if (c >= C) return;
  float sum = 0.f, sq = 0.f;
  for (int g = 0; g < G; ++g) {
    sum += partials[(size_t)g * 2 * C + c];
    sq  += partials[(size_t)g * 2 * C + C + c];
  }
  float mean = sum * invN;
  float var = sq * invN - mean * mean;
  float rstd = rsqrtf(var + 1e-5f);
  float sc = gamma[c] * rstd;
  scsh[c] = sc;
  scsh[C + c] = beta[c] - mean * sc;
}

// ---------------- BN2 apply + log_softmax (one 64-lane wave per row) ------------
__global__ __launch_bounds__(256) void bn_lsm(
    const float* __restrict__ H, const float* __restrict__ scsh,
    float* __restrict__ out, int Nrows)
{
  int lane = threadIdx.x & 63;
  int r = blockIdx.x * 4 + (threadIdx.x >> 6);
  if (r >= Nrows) return;
  float y = H[(size_t)r * 64 + lane] * scsh[lane] + scsh[64 + lane];
  float m = y;
#pragma unroll
  for (int off = 32; off >= 1; off >>= 1) m = fmaxf(m, __shfl_xor(m, off));
  float ex = expf(y - m);
  float s = ex;
#pragma unroll
  for (int off = 32; off >= 1; off >>= 1) s += __shfl_xor(s, off);
  out[(size_t)r * 64 + lane] = (y - m) - logf(s);
}

extern "C" void kernel_launch(void* const* d_in, const int* in_sizes, int n_in,
                              void* d_out, int out_size, void* d_ws, size_t ws_size,
                              hipStream_t stream) {
  const float* x      = (const float*)d_in[0];
  const int*   erow   = (const int*)  d_in[1];
  const int*   ecol   = (const int*)  d_in[2];
  const float* eval   = (const float*)d_in[3];
  const float* W1     = (const float*)d_in[4];
  // d_in[5] = b1 : added AFTER spmm, cancels exactly in training-mode BN (shift-invariant)
  const float* gamma1 = (const float*)d_in[6];
  const float* beta1  = (const float*)d_in[7];
  const float* W2     = (const float*)d_in[8];
  // d_in[9] = b2 : cancels in BN2
  const float* gamma2 = (const float*)d_in[10];
  const float* beta2  = (const float*)d_in[11];

  const int N = in_sizes[0] / 512;   // 50000
  const int E = in_sizes[1];         // 800000

  char* ws = (char*)d_ws;
  // Region [0, 51.2MB): H1 (gemm1 out, dead after spmm1), then reused as:
  //   partials1 (bn_stats1 out, dead after bn_finalize1)  [0, 512KB)
  //   H2 (gemm2 out)                                       [0, 12.8MB)
  //   H2AGG (spmm2 out)                                    [12.8MB, 25.6MB)
  // Region [51.2MB, 102.4MB): H1AGG (dead after gemm2), reused as partials2.
  float* H1       = (float*)(ws + 0);
  float* partials1= (float*)(ws + 0);           // 256*512 floats = 512 KB
  float* H2       = (float*)(ws + 0);
  float* H2AGG    = (float*)(ws + 12800000);
  float* H1AGG    = (float*)(ws + 51200000);
  float* partials2= (float*)(ws + 51200000);    // 256*128 floats = 128 KB
  float* scsh1    = (float*)(ws + 102400000);   // 512 floats (scale|shift)
  float* scsh2    = (float*)(ws + 102402048);   // 128 floats
  int*   rowptr   = (int*)(ws + 102402560);     // N+1
  int*   cnt      = (int*)(ws + 102602564);     // N
  int*   cursor   = (int*)(ws + 102802564);     // N
  int*   scols    = (int*)(ws + 103002564);     // E
  float* svals    = (float*)(ws + 106202564);   // E  (end ~109.4 MB)

  hipMemsetAsync(cnt, 0, (size_t)N * 4, stream);

  const dim3 blk(256);
  const int eblocks = (E + 255) / 256;

  // CSR build (once per call; same graph reused by both spmm layers)
  edge_hist<<<eblocks, blk, 0, stream>>>(erow, cnt, E);
  scan_rowptr<<<1, 1024, 0, stream>>>(cnt, rowptr, cursor, N, E);
  edge_scatter<<<eblocks, blk, 0, stream>>>(erow, ecol, eval, cursor, scols, svals, E);

  // layer 1: H1 = x @ W1
  gemm_f32<false><<<dim3((N + BM - 1) / BM, 256 / BN_T), blk, 0, stream>>>(
      x, W1, H1, N, 512, 256, nullptr);
  // H1AGG = A @ H1 (gather, no atomics)
  spmm_gather<256><<<(N + 3) / 4, blk, 0, stream>>>(rowptr, scols, svals, H1, H1AGG, N);
  // BN1 stats -> scale/shift (per-block partials, then tiny reduce)
  bn_stats<256><<<256, blk, 0, stream>>>(H1AGG, partials1, N);
  bn_finalize<<<1, 256, 0, stream>>>(partials1, gamma1, beta1, scsh1, 256, 256, 1.0f / N);
  // layer 2: H2 = relu(bn1(H1AGG)) @ W2   (BN+ReLU fused into A load)
  gemm_f32<true><<<dim3((N + BM - 1) / BM, 1), blk, 0, stream>>>(
      H1AGG, W2, H2, N, 256, 64, scsh1);
  // H2AGG = A @ H2 (gather)
  spmm_gather<64><<<(N + 3) / 4, blk, 0, stream>>>(rowptr, scols, svals, H2, H2AGG, N);
  // BN2 stats -> scale/shift
  bn_stats<64><<<256, blk, 0, stream>>>(H2AGG, partials2, N);
  bn_finalize<<<1, 64, 0, stream>>>(partials2, gamma2, beta2, scsh2, 64, 256, 1.0f / N);
  // BN2 apply + log_softmax
  bn_lsm<<<(N + 3) / 4, blk, 0, stream>>>(H2AGG, scsh2, (float*)d_out, N);
}

// Round 4
// 564.612 us; speedup vs baseline: 7.3660x; 1.3464x over previous
//
#include <hip/hip_runtime.h>

typedef __attribute__((ext_vector_type(8))) short short8;   // 8 bf16 (4 VGPRs)
typedef __attribute__((ext_vector_type(4))) float f32x4;
typedef __attribute__((ext_vector_type(8))) unsigned short ushort8;

__device__ __forceinline__ unsigned short f2bf(float f) {
  unsigned int u = __builtin_bit_cast(unsigned int, f);
  u += 0x7fffu + ((u >> 16) & 1u);   // RNE
  return (unsigned short)(u >> 16);
}
__device__ __forceinline__ float bf2f(unsigned short b) {
  return __builtin_bit_cast(float, ((unsigned int)b) << 16);
}
__device__ __forceinline__ void gload_lds16(const void* g, void* l) {
  __builtin_amdgcn_global_load_lds(
      (const __attribute__((address_space(1))) void*)g,
      (__attribute__((address_space(3))) void*)l, 16, 0, 0);
}

// ---------------- cvt: fp32 -> bf16, 8 elems/thread ------------------------------
__global__ __launch_bounds__(256) void cvt_f32_bf16(
    const float* __restrict__ in, unsigned short* __restrict__ out, int n8)
{
  int i = blockIdx.x * 256 + threadIdx.x;
  if (i >= n8) return;
  const float4* p = (const float4*)in;
  float4 lo = p[i * 2], hi = p[i * 2 + 1];
  ushort8 o;
  o[0] = f2bf(lo.x); o[1] = f2bf(lo.y); o[2] = f2bf(lo.z); o[3] = f2bf(lo.w);
  o[4] = f2bf(hi.x); o[5] = f2bf(hi.y); o[6] = f2bf(hi.z); o[7] = f2bf(hi.w);
  *(ushort8*)&out[i * 8] = o;
}

// ---------------- W1 [512][256] fp32 -> W1T [256][512] bf16 ----------------------
__global__ __launch_bounds__(256) void cvt_w1t(
    const float* __restrict__ W1, unsigned short* __restrict__ W1T)
{
  int idx = blockIdx.x * 256 + threadIdx.x;   // 131072 total
  int n = idx >> 9, k = idx & 511;
  W1T[idx] = f2bf(W1[(size_t)k * 256 + n]);   // writes coalesced, reads L2-resident
}

// ---------------- GEMM1: H1_bf16[M,256] = x_bf16[M,512] @ W1 (W1T input) ---------
// 128x128 tile, BK=64, 4 waves 2x2, mfma 16x16x32 bf16, global_load_lds staging,
// T2 XOR swizzle via pre-swizzled global source (linear LDS dest).
__global__ __launch_bounds__(256) void gemm1_mfma(
    const unsigned short* __restrict__ xb,   // [Mpad][512] bf16
    const unsigned short* __restrict__ w1t,  // [256][512] bf16
    unsigned short* __restrict__ H1,         // [M][256] bf16 out
    int M)
{
  __shared__ unsigned short As[128 * 64];  // [row][64k] swizzled, 16 KB
  __shared__ unsigned short Bs[128 * 64];  // [col][64k] swizzled, 16 KB
  const int tid = threadIdx.x;
  const int wid = tid >> 6, lane = tid & 63;
  const int wr = wid >> 1, wc = wid & 1;
  const int m0 = blockIdx.x * 128;
  const int n0 = blockIdx.y * 128;

  // staging: thread t handles chunk-local row=t>>3, phys slot=t&7 (16B slots)
  const int srow = tid >> 3;
  const int ls = ((tid & 7) ^ (srow & 7)) * 8;   // logical k-offset (bf16 elems)
  const unsigned short* gA = &xb[(size_t)(m0 + srow) * 512 + ls];
  const unsigned short* gB = &w1t[(size_t)(n0 + srow) * 512 + ls];
  char* lA = (char*)As + (size_t)wid * 1024;   // + chunk*4096, lane*16 auto
  char* lB = (char*)Bs + (size_t)wid * 1024;

  f32x4 acc[4][4] = {};

  for (int kt = 0; kt < 8; ++kt) {
    const int k0 = kt * 64;
#pragma unroll
    for (int i = 0; i < 4; ++i)
      gload_lds16(gA + (size_t)i * 32 * 512 + k0, lA + i * 4096);
#pragma unroll
    for (int i = 0; i < 4; ++i)
      gload_lds16(gB + (size_t)i * 32 * 512 + k0, lB + i * 4096);
    __syncthreads();   // drains vmcnt before use

#pragma unroll
    for (int kk = 0; kk < 2; ++kk) {
      short8 a[4], b[4];
#pragma unroll
      for (int m = 0; m < 4; ++m) {
        int row = wr * 64 + m * 16 + (lane & 15);
        int phys = (kk * 4 + (lane >> 4)) ^ (row & 7);
        a[m] = *(const short8*)((const char*)As + row * 128 + phys * 16);
      }
#pragma unroll
      for (int n = 0; n < 4; ++n) {
        int col = wc * 64 + n * 16 + (lane & 15);
        int phys = (kk * 4 + (lane >> 4)) ^ (col & 7);
        b[n] = *(const short8*)((const char*)Bs + col * 128 + phys * 16);
      }
#pragma unroll
      for (int m = 0; m < 4; ++m)
#pragma unroll
        for (int n = 0; n < 4; ++n)
          acc[m][n] = __builtin_amdgcn_mfma_f32_16x16x32_bf16(a[m], b[n], acc[m][n], 0, 0, 0);
    }
    __syncthreads();   // protect LDS re-stage
  }

  // epilogue: C/D layout col=lane&15, row=(lane>>4)*4+reg (m89/m91-verified)
  const int colbase = n0 + wc * 64 + (lane & 15);
#pragma unroll
  for (int m = 0; m < 4; ++m) {
    int rowbase = m0 + wr * 64 + m * 16 + (lane >> 4) * 4;
#pragma unroll
    for (int j = 0; j < 4; ++j) {
      int row = rowbase + j;
      if (row < M) {
#pragma unroll
        for (int n = 0; n < 4; ++n)
          H1[(size_t)row * 256 + colbase + n * 16] = f2bf(acc[m][n][j]);
      }
    }
  }
}

// ---------------- GEMM2 (fp32 vector): C = relu(bn(A)) @ B -----------------------
constexpr int BM = 64, BN_T = 64, BK = 16;

__global__ __launch_bounds__(256) void gemm_f32_bn(
    const float* __restrict__ A, const float* __restrict__ B,
    float* __restrict__ C, int M, int K, int N,
    const float* __restrict__ scsh)
{
  __shared__ float AsT[BK][BM];
  __shared__ float Bs[BK][BN_T];
  const int tid = threadIdx.x;
  const int tx = tid & 15;
  const int ty = tid >> 4;
  const int m0 = blockIdx.x * BM;
  const int n0 = blockIdx.y * BN_T;
  const int lm  = tid >> 2;
  const int lk4 = (tid & 3) * 4;
  const int bk  = tid >> 4;
  const int bn  = (tid & 15) * 4;

  float acc[4][4] = {};

  for (int k0 = 0; k0 < K; k0 += BK) {
    const int am = m0 + lm;
    float4 av = make_float4(0.f, 0.f, 0.f, 0.f);
    if (am < M) av = *(const float4*)&A[(size_t)am * K + k0 + lk4];
    float4 sc = *(const float4*)&scsh[k0 + lk4];
    float4 sh = *(const float4*)&scsh[K + k0 + lk4];
    av.x = fmaxf(av.x * sc.x + sh.x, 0.f);
    av.y = fmaxf(av.y * sc.y + sh.y, 0.f);
    av.z = fmaxf(av.z * sc.z + sh.z, 0.f);
    av.w = fmaxf(av.w * sc.w + sh.w, 0.f);
    AsT[lk4 + 0][lm] = av.x;
    AsT[lk4 + 1][lm] = av.y;
    AsT[lk4 + 2][lm] = av.z;
    AsT[lk4 + 3][lm] = av.w;
    *(float4*)&Bs[bk][bn] = *(const float4*)&B[(size_t)(k0 + bk) * N + n0 + bn];
    __syncthreads();
#pragma unroll
    for (int k = 0; k < BK; ++k) {
      float4 a4 = *(const float4*)&AsT[k][ty * 4];
      float4 b4 = *(const float4*)&Bs[k][tx * 4];
      float a[4] = {a4.x, a4.y, a4.z, a4.w};
      float b[4] = {b4.x, b4.y, b4.z, b4.w};
#pragma unroll
      for (int i = 0; i < 4; ++i)
#pragma unroll
        for (int j = 0; j < 4; ++j)
          acc[i][j] = fmaf(a[i], b[j], acc[i][j]);
    }
    __syncthreads();
  }
#pragma unroll
  for (int i = 0; i < 4; ++i) {
    int m = m0 + ty * 4 + i;
    if (m < M)
      *(float4*)&C[(size_t)m * N + n0 + tx * 4] =
          make_float4(acc[i][0], acc[i][1], acc[i][2], acc[i][3]);
  }
}

// ---------------- CSR build: histogram -> scan -> scatter -----------------------
__global__ __launch_bounds__(256) void edge_hist(
    const int* __restrict__ rows, int* __restrict__ cnt, int E)
{
  int e = blockIdx.x * 256 + threadIdx.x;
  if (e < E) atomicAdd(&cnt[rows[e]], 1);
}

__global__ __launch_bounds__(1024) void scan_rowptr(
    const int* __restrict__ cnt, int* __restrict__ rowptr,
    int* __restrict__ cursor, int Nrows, int E)
{
  __shared__ int lds[1024];
  const int t = threadIdx.x;
  const int CH = (Nrows + 1023) / 1024;
  const int start = t * CH;
  const int end = min(start + CH, Nrows);
  int s = 0;
  for (int i = start; i < end; ++i) s += cnt[i];
  lds[t] = s;
  __syncthreads();
  for (int off = 1; off < 1024; off <<= 1) {
    int u = (t >= off) ? lds[t - off] : 0;
    __syncthreads();
    lds[t] += u;
    __syncthreads();
  }
  int base = (t == 0) ? 0 : lds[t - 1];
  for (int i = start; i < end; ++i) {
    rowptr[i] = base;
    cursor[i] = base;
    base += cnt[i];
  }
  if (t == 0) rowptr[Nrows] = E;
}

__global__ __launch_bounds__(256) void edge_scatter(
    const int* __restrict__ rows, const int* __restrict__ cols,
    const float* __restrict__ vals, int* __restrict__ cursor,
    int* __restrict__ scols, float* __restrict__ svals, int E)
{
  int e = blockIdx.x * 256 + threadIdx.x;
  if (e < E) {
    int r = rows[e];
    int p = atomicAdd(&cursor[r], 1);
    scols[p] = cols[e];
    svals[p] = vals[e];
  }
}

// ---------------- SpMM gather (bf16 D, F=256): one wave per row ------------------
__global__ __launch_bounds__(256) void spmm_gather_bf(
    const int* __restrict__ rowptr, const int* __restrict__ scols,
    const float* __restrict__ svals, const unsigned short* __restrict__ D,
    float* __restrict__ out, int Nrows)
{
  const int lane = threadIdx.x & 63;
  const int r = blockIdx.x * 4 + (threadIdx.x >> 6);
  if (r >= Nrows) return;
  const int s = rowptr[r], e = rowptr[r + 1];
  float4 acc = make_float4(0.f, 0.f, 0.f, 0.f);
  int j = s;
  for (; j + 1 < e; j += 2) {
    int c0 = scols[j], c1 = scols[j + 1];
    float v0 = svals[j], v1 = svals[j + 1];
    ushort4 d0 = *(const ushort4*)&D[(size_t)c0 * 256 + lane * 4];
    ushort4 d1 = *(const ushort4*)&D[(size_t)c1 * 256 + lane * 4];
    acc.x = fmaf(v0, bf2f(d0.x), acc.x); acc.y = fmaf(v0, bf2f(d0.y), acc.y);
    acc.z = fmaf(v0, bf2f(d0.z), acc.z); acc.w = fmaf(v0, bf2f(d0.w), acc.w);
    acc.x = fmaf(v1, bf2f(d1.x), acc.x); acc.y = fmaf(v1, bf2f(d1.y), acc.y);
    acc.z = fmaf(v1, bf2f(d1.z), acc.z); acc.w = fmaf(v1, bf2f(d1.w), acc.w);
  }
  if (j < e) {
    int c = scols[j]; float v = svals[j];
    ushort4 d = *(const ushort4*)&D[(size_t)c * 256 + lane * 4];
    acc.x = fmaf(v, bf2f(d.x), acc.x); acc.y = fmaf(v, bf2f(d.y), acc.y);
    acc.z = fmaf(v, bf2f(d.z), acc.z); acc.w = fmaf(v, bf2f(d.w), acc.w);
  }
  *(float4*)&out[(size_t)r * 256 + lane * 4] = acc;
}

// ---------------- SpMM gather (fp32 D, F=64): one wave per row -------------------
__global__ __launch_bounds__(256) void spmm_gather_f32_64(
    const int* __restrict__ rowptr, const int* __restrict__ scols,
    const float* __restrict__ svals, const float* __restrict__ D,
    float* __restrict__ out, int Nrows)
{
  const int lane = threadIdx.x & 63;
  const int r = blockIdx.x * 4 + (threadIdx.x >> 6);
  if (r >= Nrows) return;
  const int s = rowptr[r], e = rowptr[r + 1];
  float acc = 0.f;
  int j = s;
  for (; j + 1 < e; j += 2) {
    int c0 = scols[j], c1 = scols[j + 1];
    float v0 = svals[j], v1 = svals[j + 1];
    acc = fmaf(v0, D[(size_t)c0 * 64 + lane], acc);
    acc = fmaf(v1, D[(size_t)c1 * 64 + lane], acc);
  }
  if (j < e) acc = fmaf(svals[j], D[(size_t)scols[j] * 64 + lane], acc);
  out[(size_t)r * 64 + lane] = acc;
}

// ---------------- BN stats: per-block partials, NO atomics ----------------------
template<int C>
__global__ __launch_bounds__(256) void bn_stats(
    const float* __restrict__ H, float* __restrict__ partials, int Nrows)
{
  constexpr int C4 = C / 4;
  constexpr int RPB = 256 / C4;
  const int cc = threadIdx.x % C4;
  const int c = cc * 4;
  const int rr = threadIdx.x / C4;
  float4 s = make_float4(0.f, 0.f, 0.f, 0.f);
  float4 q = make_float4(0.f, 0.f, 0.f, 0.f);
  for (int r = blockIdx.x * RPB + rr; r < Nrows; r += gridDim.x * RPB) {
    float4 v = *(const float4*)&H[(size_t)r * C + c];
    s.x += v.x; s.y += v.y; s.z += v.z; s.w += v.w;
    q.x += v.x * v.x; q.y += v.y * v.y; q.z += v.z * v.z; q.w += v.w * v.w;
  }
  __shared__ float lds[256][8];
  float* L = lds[threadIdx.x];
  L[0] = s.x; L[1] = s.y; L[2] = s.z; L[3] = s.w;
  L[4] = q.x; L[5] = q.y; L[6] = q.z; L[7] = q.w;
  __syncthreads();
  if (rr == 0) {
#pragma unroll
    for (int r = 1; r < RPB; ++r) {
      float* Mm = lds[cc + r * C4];
      s.x += Mm[0]; s.y += Mm[1]; s.z += Mm[2]; s.w += Mm[3];
      q.x += Mm[4]; q.y += Mm[5]; q.z += Mm[6]; q.w += Mm[7];
    }
    float* P = &partials[(size_t)blockIdx.x * 2 * C];
    *(float4*)&P[c] = s;
    *(float4*)&P[C + c] = q;
  }
}

// ---------------- BN finalize -----------------------------------------------------
__global__ void bn_finalize(const float* __restrict__ partials,
    const float* __restrict__ gamma, const float* __restrict__ beta,
    float* __restrict__ scsh, int C, int G, float invN)
{
  int c = threadIdx.x;
  if (c >= C) return;
  float sum = 0.f, sq = 0.f;
  for (int g = 0; g < G; ++g) {
    sum += partials[(size_t)g * 2 * C + c];
    sq  += partials[(size_t)g * 2 * C + C + c];
  }
  float mean = sum * invN;
  float var = sq * invN - mean * mean;
  float rstd = rsqrtf(var + 1e-5f);
  float sc = gamma[c] * rstd;
  scsh[c] = sc;
  scsh[C + c] = beta[c] - mean * sc;
}

// ---------------- BN2 apply + log_softmax ----------------------------------------
__global__ __launch_bounds__(256) void bn_lsm(
    const float* __restrict__ H, const float* __restrict__ scsh,
    float* __restrict__ out, int Nrows)
{
  int lane = threadIdx.x & 63;
  int r = blockIdx.x * 4 + (threadIdx.x >> 6);
  if (r >= Nrows) return;
  float y = H[(size_t)r * 64 + lane] * scsh[lane] + scsh[64 + lane];
  float m = y;
#pragma unroll
  for (int off = 32; off >= 1; off >>= 1) m = fmaxf(m, __shfl_xor(m, off));
  float ex = expf(y - m);
  float s = ex;
#pragma unroll
  for (int off = 32; off >= 1; off >>= 1) s += __shfl_xor(s, off);
  out[(size_t)r * 64 + lane] = (y - m) - logf(s);
}

extern "C" void kernel_launch(void* const* d_in, const int* in_sizes, int n_in,
                              void* d_out, int out_size, void* d_ws, size_t ws_size,
                              hipStream_t stream) {
  const float* x      = (const float*)d_in[0];
  const int*   erow   = (const int*)  d_in[1];
  const int*   ecol   = (const int*)  d_in[2];
  const float* eval   = (const float*)d_in[3];
  const float* W1     = (const float*)d_in[4];
  // d_in[5] = b1 : cancels exactly in training-mode BN (shift-invariant)
  const float* gamma1 = (const float*)d_in[6];
  const float* beta1  = (const float*)d_in[7];
  const float* W2     = (const float*)d_in[8];
  // d_in[9] = b2 : cancels in BN2
  const float* gamma2 = (const float*)d_in[10];
  const float* beta2  = (const float*)d_in[11];

  const int N = in_sizes[0] / 512;   // 50000
  const int E = in_sizes[1];         // 800000

  char* ws = (char*)d_ws;
  // [0, 25.6M):       H1 bf16 (dead after spmm1) -> partials1 -> H2(12.8M)+H2AGG(@12.8M)
  // [25.6M, 76.85M):  x_bf16 (+pad; dead after gemm1) -> H1AGG (dead after gemm2) -> partials2
  // [76.85M, ~84.1M): W1T, scsh, CSR arrays
  unsigned short* H1b   = (unsigned short*)(ws + 0);
  float* partials1      = (float*)(ws + 0);
  float* H2             = (float*)(ws + 0);
  float* H2AGG          = (float*)(ws + 12800000);
  unsigned short* xb    = (unsigned short*)(ws + 25600000);
  float* H1AGG          = (float*)(ws + 25600000);
  float* partials2      = (float*)(ws + 25600000);
  unsigned short* w1t   = (unsigned short*)(ws + 76865536);
  float* scsh1          = (float*)(ws + 77127680);
  float* scsh2          = (float*)(ws + 77129728);
  int*   rowptr         = (int*)(ws + 77130240);
  int*   cnt            = (int*)(ws + 77330244);
  int*   cursor         = (int*)(ws + 77530244);
  int*   scols          = (int*)(ws + 77730244);
  float* svals          = (float*)(ws + 80930244);

  hipMemsetAsync(cnt, 0, (size_t)N * 4, stream);

  const dim3 blk(256);
  const int eblocks = (E + 255) / 256;

  // CSR build
  edge_hist<<<eblocks, blk, 0, stream>>>(erow, cnt, E);
  scan_rowptr<<<1, 1024, 0, stream>>>(cnt, rowptr, cursor, N, E);
  edge_scatter<<<eblocks, blk, 0, stream>>>(erow, ecol, eval, cursor, scols, svals, E);

  // bf16 conversions
  cvt_f32_bf16<<<(N * 512 / 8 + 255) / 256, blk, 0, stream>>>(x, xb, N * 512 / 8);
  cvt_w1t<<<512 * 256 / 256, blk, 0, stream>>>(W1, w1t);

  // layer 1: H1 = x @ W1 (bf16 MFMA, bf16 out)
  gemm1_mfma<<<dim3((N + 127) / 128, 2), blk, 0, stream>>>(xb, w1t, H1b, N);
  // H1AGG = A @ H1 (gather from bf16)
  spmm_gather_bf<<<(N + 3) / 4, blk, 0, stream>>>(rowptr, scols, svals, H1b, H1AGG, N);
  // BN1
  bn_stats<256><<<256, blk, 0, stream>>>(H1AGG, partials1, N);
  bn_finalize<<<1, 256, 0, stream>>>(partials1, gamma1, beta1, scsh1, 256, 256, 1.0f / N);
  // layer 2: H2 = relu(bn1(H1AGG)) @ W2
  gemm_f32_bn<<<dim3((N + BM - 1) / BM, 1), blk, 0, stream>>>(
      H1AGG, W2, H2, N, 256, 64, scsh1);
  // H2AGG = A @ H2
  spmm_gather_f32_64<<<(N + 3) / 4, blk, 0, stream>>>(rowptr, scols, svals, H2, H2AGG, N);
  // BN2
  bn_stats<64><<<256, blk, 0, stream>>>(H2AGG, partials2, N);
  bn_finalize<<<1, 64, 0, stream>>>(partials2, gamma2, beta2, scsh2, 64, 256, 1.0f / N);
  // BN2 apply + log_softmax
  bn_lsm<<<(N + 3) / 4, blk, 0, stream>>>(H2AGG, scsh2, (float*)d_out, N);
}

// Round 5
// 464.873 us; speedup vs baseline: 8.9464x; 1.2146x over previous
//
#include <hip/hip_runtime.h>

typedef __attribute__((ext_vector_type(8))) short short8;   // 8 bf16 (4 VGPRs)
typedef __attribute__((ext_vector_type(4))) float f32x4;
typedef __attribute__((ext_vector_type(8))) unsigned short ushort8;

__device__ __forceinline__ unsigned short f2bf(float f) {
  unsigned int u = __builtin_bit_cast(unsigned int, f);
  u += 0x7fffu + ((u >> 16) & 1u);   // RNE
  return (unsigned short)(u >> 16);
}
__device__ __forceinline__ float bf2f(unsigned short b) {
  return __builtin_bit_cast(float, ((unsigned int)b) << 16);
}
__device__ __forceinline__ void gload_lds16(const void* g, void* l) {
  __builtin_amdgcn_global_load_lds(
      (const __attribute__((address_space(1))) void*)g,
      (__attribute__((address_space(3))) void*)l, 16, 0, 0);
}

// ---------------- cvt: fp32 -> bf16, 8 elems/thread ------------------------------
__global__ __launch_bounds__(256) void cvt_f32_bf16(
    const float* __restrict__ in, unsigned short* __restrict__ out, int n8)
{
  int i = blockIdx.x * 256 + threadIdx.x;
  if (i >= n8) return;
  const float4* p = (const float4*)in;
  float4 lo = p[i * 2], hi = p[i * 2 + 1];
  ushort8 o;
  o[0] = f2bf(lo.x); o[1] = f2bf(lo.y); o[2] = f2bf(lo.z); o[3] = f2bf(lo.w);
  o[4] = f2bf(hi.x); o[5] = f2bf(hi.y); o[6] = f2bf(hi.z); o[7] = f2bf(hi.w);
  *(ushort8*)&out[i * 8] = o;
}

// ---------------- W1 [512][256] fp32 -> W1T [256][512] bf16 ----------------------
__global__ __launch_bounds__(256) void cvt_w1t(
    const float* __restrict__ W1, unsigned short* __restrict__ W1T)
{
  int idx = blockIdx.x * 256 + threadIdx.x;   // 131072 total
  int n = idx >> 9, k = idx & 511;
  W1T[idx] = f2bf(W1[(size_t)k * 256 + n]);   // writes coalesced, reads L2-resident
}

// ---------------- GEMM1: H1_bf16[M,256] = x_bf16[M,512] @ W1 (W1T input) ---------
__global__ __launch_bounds__(256) void gemm1_mfma(
    const unsigned short* __restrict__ xb,   // [Mpad][512] bf16
    const unsigned short* __restrict__ w1t,  // [256][512] bf16
    unsigned short* __restrict__ H1,         // [M][256] bf16 out
    int M)
{
  __shared__ unsigned short As[128 * 64];  // [row][64k] swizzled, 16 KB
  __shared__ unsigned short Bs[128 * 64];  // [col][64k] swizzled, 16 KB
  const int tid = threadIdx.x;
  const int wid = tid >> 6, lane = tid & 63;
  const int wr = wid >> 1, wc = wid & 1;
  const int m0 = blockIdx.x * 128;
  const int n0 = blockIdx.y * 128;

  const int srow = tid >> 3;
  const int ls = ((tid & 7) ^ (srow & 7)) * 8;   // pre-swizzled global k-offset
  const unsigned short* gA = &xb[(size_t)(m0 + srow) * 512 + ls];
  const unsigned short* gB = &w1t[(size_t)(n0 + srow) * 512 + ls];
  char* lA = (char*)As + (size_t)wid * 1024;
  char* lB = (char*)Bs + (size_t)wid * 1024;

  f32x4 acc[4][4] = {};

  for (int kt = 0; kt < 8; ++kt) {
    const int k0 = kt * 64;
#pragma unroll
    for (int i = 0; i < 4; ++i)
      gload_lds16(gA + (size_t)i * 32 * 512 + k0, lA + i * 4096);
#pragma unroll
    for (int i = 0; i < 4; ++i)
      gload_lds16(gB + (size_t)i * 32 * 512 + k0, lB + i * 4096);
    __syncthreads();

#pragma unroll
    for (int kk = 0; kk < 2; ++kk) {
      short8 a[4], b[4];
#pragma unroll
      for (int m = 0; m < 4; ++m) {
        int row = wr * 64 + m * 16 + (lane & 15);
        int phys = (kk * 4 + (lane >> 4)) ^ (row & 7);
        a[m] = *(const short8*)((const char*)As + row * 128 + phys * 16);
      }
#pragma unroll
      for (int n = 0; n < 4; ++n) {
        int col = wc * 64 + n * 16 + (lane & 15);
        int phys = (kk * 4 + (lane >> 4)) ^ (col & 7);
        b[n] = *(const short8*)((const char*)Bs + col * 128 + phys * 16);
      }
#pragma unroll
      for (int m = 0; m < 4; ++m)
#pragma unroll
        for (int n = 0; n < 4; ++n)
          acc[m][n] = __builtin_amdgcn_mfma_f32_16x16x32_bf16(a[m], b[n], acc[m][n], 0, 0, 0);
    }
    __syncthreads();
  }

  const int colbase = n0 + wc * 64 + (lane & 15);
#pragma unroll
  for (int m = 0; m < 4; ++m) {
    int rowbase = m0 + wr * 64 + m * 16 + (lane >> 4) * 4;
#pragma unroll
    for (int j = 0; j < 4; ++j) {
      int row = rowbase + j;
      if (row < M) {
#pragma unroll
        for (int n = 0; n < 4; ++n)
          H1[(size_t)row * 256 + colbase + n * 16] = f2bf(acc[m][n][j]);
      }
    }
  }
}

// ---------------- GEMM2 (fp32 vector): C = relu(bn(A)) @ B -----------------------
constexpr int BM = 64, BN_T = 64, BK = 16;

__global__ __launch_bounds__(256) void gemm_f32_bn(
    const float* __restrict__ A, const float* __restrict__ B,
    float* __restrict__ C, int M, int K, int N,
    const float* __restrict__ scsh)
{
  __shared__ float AsT[BK][BM];
  __shared__ float Bs[BK][BN_T];
  const int tid = threadIdx.x;
  const int tx = tid & 15;
  const int ty = tid >> 4;
  const int m0 = blockIdx.x * BM;
  const int n0 = blockIdx.y * BN_T;
  const int lm  = tid >> 2;
  const int lk4 = (tid & 3) * 4;
  const int bk  = tid >> 4;
  const int bn  = (tid & 15) * 4;

  float acc[4][4] = {};

  for (int k0 = 0; k0 < K; k0 += BK) {
    const int am = m0 + lm;
    float4 av = make_float4(0.f, 0.f, 0.f, 0.f);
    if (am < M) av = *(const float4*)&A[(size_t)am * K + k0 + lk4];
    float4 sc = *(const float4*)&scsh[k0 + lk4];
    float4 sh = *(const float4*)&scsh[K + k0 + lk4];
    av.x = fmaxf(av.x * sc.x + sh.x, 0.f);
    av.y = fmaxf(av.y * sc.y + sh.y, 0.f);
    av.z = fmaxf(av.z * sc.z + sh.z, 0.f);
    av.w = fmaxf(av.w * sc.w + sh.w, 0.f);
    AsT[lk4 + 0][lm] = av.x;
    AsT[lk4 + 1][lm] = av.y;
    AsT[lk4 + 2][lm] = av.z;
    AsT[lk4 + 3][lm] = av.w;
    *(float4*)&Bs[bk][bn] = *(const float4*)&B[(size_t)(k0 + bk) * N + n0 + bn];
    __syncthreads();
#pragma unroll
    for (int k = 0; k < BK; ++k) {
      float4 a4 = *(const float4*)&AsT[k][ty * 4];
      float4 b4 = *(const float4*)&Bs[k][tx * 4];
      float a[4] = {a4.x, a4.y, a4.z, a4.w};
      float b[4] = {b4.x, b4.y, b4.z, b4.w};
#pragma unroll
      for (int i = 0; i < 4; ++i)
#pragma unroll
        for (int j = 0; j < 4; ++j)
          acc[i][j] = fmaf(a[i], b[j], acc[i][j]);
    }
    __syncthreads();
  }
#pragma unroll
  for (int i = 0; i < 4; ++i) {
    int m = m0 + ty * 4 + i;
    if (m < M)
      *(float4*)&C[(size_t)m * N + n0 + tx * 4] =
          make_float4(acc[i][0], acc[i][1], acc[i][2], acc[i][3]);
  }
}

// ---------------- CSR build: histogram -> 3-phase scan -> scatter ----------------
__global__ __launch_bounds__(256) void edge_hist(
    const int* __restrict__ rows, int* __restrict__ cnt, int E)
{
  int e = blockIdx.x * 256 + threadIdx.x;
  if (e < E) atomicAdd(&cnt[rows[e]], 1);
}

// phase A: per-block (256 rows) partial sums
__global__ __launch_bounds__(256) void scan_blocksum(
    const int* __restrict__ cnt, int* __restrict__ bsum, int Nrows)
{
  int i = blockIdx.x * 256 + threadIdx.x;
  int v = (i < Nrows) ? cnt[i] : 0;
#pragma unroll
  for (int off = 1; off < 64; off <<= 1) v += __shfl_xor(v, off);
  __shared__ int wsum[4];
  if ((threadIdx.x & 63) == 0) wsum[threadIdx.x >> 6] = v;
  __syncthreads();
  if (threadIdx.x == 0)
    bsum[blockIdx.x] = wsum[0] + wsum[1] + wsum[2] + wsum[3];
}

// phase B: single tiny block scans <=256 block sums -> exclusive offsets
__global__ __launch_bounds__(256) void scan_boff(
    const int* __restrict__ bsum, int* __restrict__ boff, int NB)
{
  __shared__ int lds[256];
  int t = threadIdx.x;
  int v = (t < NB) ? bsum[t] : 0;
  lds[t] = v;
  __syncthreads();
  for (int off = 1; off < 256; off <<= 1) {
    int u = (t >= off) ? lds[t - off] : 0;
    __syncthreads();
    lds[t] += u;
    __syncthreads();
  }
  boff[t] = (t == 0) ? 0 : lds[t - 1];
}

// phase C: block-local exclusive scan + offset -> rowptr/cursor
__global__ __launch_bounds__(256) void scan_write(
    const int* __restrict__ cnt, const int* __restrict__ boff,
    int* __restrict__ rowptr, int* __restrict__ cursor, int Nrows, int E)
{
  __shared__ int lds[256];
  int t = threadIdx.x;
  int i = blockIdx.x * 256 + t;
  int v = (i < Nrows) ? cnt[i] : 0;
  lds[t] = v;
  __syncthreads();
  for (int off = 1; off < 256; off <<= 1) {
    int u = (t >= off) ? lds[t - off] : 0;
    __syncthreads();
    lds[t] += u;
    __syncthreads();
  }
  int excl = boff[blockIdx.x] + lds[t] - v;
  if (i < Nrows) { rowptr[i] = excl; cursor[i] = excl; }
  if (i == Nrows) rowptr[i] = E;
}

__global__ __launch_bounds__(256) void edge_scatter(
    const int* __restrict__ rows, const int* __restrict__ cols,
    const float* __restrict__ vals, int* __restrict__ cursor,
    int* __restrict__ scols, float* __restrict__ svals, int E)
{
  int e = blockIdx.x * 256 + threadIdx.x;
  if (e < E) {
    int r = rows[e];
    int p = atomicAdd(&cursor[r], 1);
    scols[p] = cols[e];
    svals[p] = vals[e];
  }
}

// ---------------- SpMM gather (bf16 D, F=256): one wave per row ------------------
__global__ __launch_bounds__(256) void spmm_gather_bf(
    const int* __restrict__ rowptr, const int* __restrict__ scols,
    const float* __restrict__ svals, const unsigned short* __restrict__ D,
    float* __restrict__ out, int Nrows)
{
  const int lane = threadIdx.x & 63;
  const int r = blockIdx.x * 4 + (threadIdx.x >> 6);
  if (r >= Nrows) return;
  const int s = rowptr[r], e = rowptr[r + 1];
  float4 acc = make_float4(0.f, 0.f, 0.f, 0.f);
  int j = s;
  for (; j + 1 < e; j += 2) {
    int c0 = scols[j], c1 = scols[j + 1];
    float v0 = svals[j], v1 = svals[j + 1];
    ushort4 d0 = *(const ushort4*)&D[(size_t)c0 * 256 + lane * 4];
    ushort4 d1 = *(const ushort4*)&D[(size_t)c1 * 256 + lane * 4];
    acc.x = fmaf(v0, bf2f(d0.x), acc.x); acc.y = fmaf(v0, bf2f(d0.y), acc.y);
    acc.z = fmaf(v0, bf2f(d0.z), acc.z); acc.w = fmaf(v0, bf2f(d0.w), acc.w);
    acc.x = fmaf(v1, bf2f(d1.x), acc.x); acc.y = fmaf(v1, bf2f(d1.y), acc.y);
    acc.z = fmaf(v1, bf2f(d1.z), acc.z); acc.w = fmaf(v1, bf2f(d1.w), acc.w);
  }
  if (j < e) {
    int c = scols[j]; float v = svals[j];
    ushort4 d = *(const ushort4*)&D[(size_t)c * 256 + lane * 4];
    acc.x = fmaf(v, bf2f(d.x), acc.x); acc.y = fmaf(v, bf2f(d.y), acc.y);
    acc.z = fmaf(v, bf2f(d.z), acc.z); acc.w = fmaf(v, bf2f(d.w), acc.w);
  }
  *(float4*)&out[(size_t)r * 256 + lane * 4] = acc;
}

// ---------------- SpMM gather (fp32 D, F=64): one wave per row -------------------
__global__ __launch_bounds__(256) void spmm_gather_f32_64(
    const int* __restrict__ rowptr, const int* __restrict__ scols,
    const float* __restrict__ svals, const float* __restrict__ D,
    float* __restrict__ out, int Nrows)
{
  const int lane = threadIdx.x & 63;
  const int r = blockIdx.x * 4 + (threadIdx.x >> 6);
  if (r >= Nrows) return;
  const int s = rowptr[r], e = rowptr[r + 1];
  float acc = 0.f;
  int j = s;
  for (; j + 1 < e; j += 2) {
    int c0 = scols[j], c1 = scols[j + 1];
    float v0 = svals[j], v1 = svals[j + 1];
    acc = fmaf(v0, D[(size_t)c0 * 64 + lane], acc);
    acc = fmaf(v1, D[(size_t)c1 * 64 + lane], acc);
  }
  if (j < e) acc = fmaf(svals[j], D[(size_t)scols[j] * 64 + lane], acc);
  out[(size_t)r * 64 + lane] = acc;
}

// ---------------- BN stats: per-block partials, NO atomics ----------------------
template<int C>
__global__ __launch_bounds__(256) void bn_stats(
    const float* __restrict__ H, float* __restrict__ partials, int Nrows)
{
  constexpr int C4 = C / 4;
  constexpr int RPB = 256 / C4;
  const int cc = threadIdx.x % C4;
  const int c = cc * 4;
  const int rr = threadIdx.x / C4;
  float4 s = make_float4(0.f, 0.f, 0.f, 0.f);
  float4 q = make_float4(0.f, 0.f, 0.f, 0.f);
  for (int r = blockIdx.x * RPB + rr; r < Nrows; r += gridDim.x * RPB) {
    float4 v = *(const float4*)&H[(size_t)r * C + c];
    s.x += v.x; s.y += v.y; s.z += v.z; s.w += v.w;
    q.x += v.x * v.x; q.y += v.y * v.y; q.z += v.z * v.z; q.w += v.w * v.w;
  }
  __shared__ float lds[256][8];
  float* L = lds[threadIdx.x];
  L[0] = s.x; L[1] = s.y; L[2] = s.z; L[3] = s.w;
  L[4] = q.x; L[5] = q.y; L[6] = q.z; L[7] = q.w;
  __syncthreads();
  if (rr == 0) {
#pragma unroll
    for (int r = 1; r < RPB; ++r) {
      float* Mm = lds[cc + r * C4];
      s.x += Mm[0]; s.y += Mm[1]; s.z += Mm[2]; s.w += Mm[3];
      q.x += Mm[4]; q.y += Mm[5]; q.z += Mm[6]; q.w += Mm[7];
    }
    float* P = &partials[(size_t)blockIdx.x * 2 * C];
    *(float4*)&P[c] = s;
    *(float4*)&P[C + c] = q;
  }
}

// ---------------- BN finalize -----------------------------------------------------
__global__ void bn_finalize(const float* __restrict__ partials,
    const float* __restrict__ gamma, const float* __restrict__ beta,
    float* __restrict__ scsh, int C, int G, float invN)
{
  int c = threadIdx.x;
  if (c >= C) return;
  float sum = 0.f, sq = 0.f;
  for (int g = 0; g < G; ++g) {
    sum += partials[(size_t)g * 2 * C + c];
    sq  += partials[(size_t)g * 2 * C + C + c];
  }
  float mean = sum * invN;
  float var = sq * invN - mean * mean;
  float rstd = rsqrtf(var + 1e-5f);
  float sc = gamma[c] * rstd;
  scsh[c] = sc;
  scsh[C + c] = beta[c] - mean * sc;
}

// ---------------- BN2 apply + log_softmax ----------------------------------------
__global__ __launch_bounds__(256) void bn_lsm(
    const float* __restrict__ H, const float* __restrict__ scsh,
    float* __restrict__ out, int Nrows)
{
  int lane = threadIdx.x & 63;
  int r = blockIdx.x * 4 + (threadIdx.x >> 6);
  if (r >= Nrows) return;
  float y = H[(size_t)r * 64 + lane] * scsh[lane] + scsh[64 + lane];
  float m = y;
#pragma unroll
  for (int off = 32; off >= 1; off >>= 1) m = fmaxf(m, __shfl_xor(m, off));
  float ex = expf(y - m);
  float s = ex;
#pragma unroll
  for (int off = 32; off >= 1; off >>= 1) s += __shfl_xor(s, off);
  out[(size_t)r * 64 + lane] = (y - m) - logf(s);
}

extern "C" void kernel_launch(void* const* d_in, const int* in_sizes, int n_in,
                              void* d_out, int out_size, void* d_ws, size_t ws_size,
                              hipStream_t stream) {
  const float* x      = (const float*)d_in[0];
  const int*   erow   = (const int*)  d_in[1];
  const int*   ecol   = (const int*)  d_in[2];
  const float* eval   = (const float*)d_in[3];
  const float* W1     = (const float*)d_in[4];
  // d_in[5] = b1 : cancels exactly in training-mode BN (shift-invariant)
  const float* gamma1 = (const float*)d_in[6];
  const float* beta1  = (const float*)d_in[7];
  const float* W2     = (const float*)d_in[8];
  // d_in[9] = b2 : cancels in BN2
  const float* gamma2 = (const float*)d_in[10];
  const float* beta2  = (const float*)d_in[11];

  const int N = in_sizes[0] / 512;   // 50000
  const int E = in_sizes[1];         // 800000

  char* ws = (char*)d_ws;
  unsigned short* H1b   = (unsigned short*)(ws + 0);
  float* partials1      = (float*)(ws + 0);
  float* H2             = (float*)(ws + 0);
  float* H2AGG          = (float*)(ws + 12800000);
  unsigned short* xb    = (unsigned short*)(ws + 25600000);
  float* H1AGG          = (float*)(ws + 25600000);
  float* partials2      = (float*)(ws + 25600000);
  unsigned short* w1t   = (unsigned short*)(ws + 76865536);
  float* scsh1          = (float*)(ws + 77127680);
  float* scsh2          = (float*)(ws + 77129728);
  int*   rowptr         = (int*)(ws + 77130240);
  int*   cnt            = (int*)(ws + 77330244);
  int*   cursor         = (int*)(ws + 77530244);
  int*   scols          = (int*)(ws + 77730244);
  float* svals          = (float*)(ws + 80930244);
  int*   bsum           = (int*)(ws + 84130244);   // <=256 ints
  int*   boff           = (int*)(ws + 84131268);   // 256 ints

  hipMemsetAsync(cnt, 0, (size_t)N * 4, stream);

  const dim3 blk(256);
  const int eblocks = (E + 255) / 256;
  const int NB = (N + 255) / 256;   // 196 <= 256

  // CSR build
  edge_hist<<<eblocks, blk, 0, stream>>>(erow, cnt, E);
  scan_blocksum<<<NB, blk, 0, stream>>>(cnt, bsum, N);
  scan_boff<<<1, blk, 0, stream>>>(bsum, boff, NB);
  scan_write<<<NB + 1, blk, 0, stream>>>(cnt, boff, rowptr, cursor, N, E);
  edge_scatter<<<eblocks, blk, 0, stream>>>(erow, ecol, eval, cursor, scols, svals, E);

  // bf16 conversions
  cvt_f32_bf16<<<(N * 512 / 8 + 255) / 256, blk, 0, stream>>>(x, xb, N * 512 / 8);
  cvt_w1t<<<512 * 256 / 256, blk, 0, stream>>>(W1, w1t);

  // layer 1: H1 = x @ W1 (bf16 MFMA, bf16 out)
  gemm1_mfma<<<dim3((N + 127) / 128, 2), blk, 0, stream>>>(xb, w1t, H1b, N);
  // H1AGG = A @ H1 (gather from bf16)
  spmm_gather_bf<<<(N + 3) / 4, blk, 0, stream>>>(rowptr, scols, svals, H1b, H1AGG, N);
  // BN1
  bn_stats<256><<<256, blk, 0, stream>>>(H1AGG, partials1, N);
  bn_finalize<<<1, 256, 0, stream>>>(partials1, gamma1, beta1, scsh1, 256, 256, 1.0f / N);
  // layer 2: H2 = relu(bn1(H1AGG)) @ W2
  gemm_f32_bn<<<dim3((N + BM - 1) / BM, 1), blk, 0, stream>>>(
      H1AGG, W2, H2, N, 256, 64, scsh1);
  // H2AGG = A @ H2
  spmm_gather_f32_64<<<(N + 3) / 4, blk, 0, stream>>>(rowptr, scols, svals, H2, H2AGG, N);
  // BN2
  bn_stats<64><<<256, blk, 0, stream>>>(H2AGG, partials2, N);
  bn_finalize<<<1, 64, 0, stream>>>(partials2, gamma2, beta2, scsh2, 64, 256, 1.0f / N);
  // BN2 apply + log_softmax
  bn_lsm<<<(N + 3) / 4, blk, 0, stream>>>(H2AGG, scsh2, (float*)d_out, N);
}

// Round 6
// 345.069 us; speedup vs baseline: 12.0525x; 1.3472x over previous
//
#include <hip/hip_runtime.h>

typedef __attribute__((ext_vector_type(8))) short short8;   // 8 bf16 (4 VGPRs)
typedef __attribute__((ext_vector_type(4))) float f32x4;
typedef __attribute__((ext_vector_type(8))) unsigned short ushort8;

__device__ __forceinline__ unsigned short f2bf(float f) {
  unsigned int u = __builtin_bit_cast(unsigned int, f);
  u += 0x7fffu + ((u >> 16) & 1u);   // RNE
  return (unsigned short)(u >> 16);
}
__device__ __forceinline__ float bf2f(unsigned short b) {
  return __builtin_bit_cast(float, ((unsigned int)b) << 16);
}
__device__ __forceinline__ void gload_lds16(const void* g, void* l) {
  __builtin_amdgcn_global_load_lds(
      (const __attribute__((address_space(1))) void*)g,
      (__attribute__((address_space(3))) void*)l, 16, 0, 0);
}

// ---------------- cvt: fp32 -> bf16, 8 elems/thread ------------------------------
__global__ __launch_bounds__(256) void cvt_f32_bf16(
    const float* __restrict__ in, unsigned short* __restrict__ out, int n8)
{
  int i = blockIdx.x * 256 + threadIdx.x;
  if (i >= n8) return;
  const float4* p = (const float4*)in;
  float4 lo = p[i * 2], hi = p[i * 2 + 1];
  ushort8 o;
  o[0] = f2bf(lo.x); o[1] = f2bf(lo.y); o[2] = f2bf(lo.z); o[3] = f2bf(lo.w);
  o[4] = f2bf(hi.x); o[5] = f2bf(hi.y); o[6] = f2bf(hi.z); o[7] = f2bf(hi.w);
  *(ushort8*)&out[i * 8] = o;
}

// ---------------- W1 [512][256] fp32 -> W1T [256][512] bf16 ----------------------
__global__ __launch_bounds__(256) void cvt_w1t(
    const float* __restrict__ W1, unsigned short* __restrict__ W1T)
{
  int idx = blockIdx.x * 256 + threadIdx.x;   // 131072 total
  int n = idx >> 9, k = idx & 511;
  W1T[idx] = f2bf(W1[(size_t)k * 256 + n]);   // writes coalesced, reads L2-resident
}

// ---------------- GEMM1: H1_bf16[M,256] = x_bf16[M,512] @ W1 (W1T input) ---------
__global__ __launch_bounds__(256) void gemm1_mfma(
    const unsigned short* __restrict__ xb,   // [Mpad][512] bf16
    const unsigned short* __restrict__ w1t,  // [256][512] bf16
    unsigned short* __restrict__ H1,         // [M][256] bf16 out
    int M)
{
  __shared__ unsigned short As[128 * 64];  // [row][64k] swizzled, 16 KB
  __shared__ unsigned short Bs[128 * 64];  // [col][64k] swizzled, 16 KB
  const int tid = threadIdx.x;
  const int wid = tid >> 6, lane = tid & 63;
  const int wr = wid >> 1, wc = wid & 1;
  const int m0 = blockIdx.x * 128;
  const int n0 = blockIdx.y * 128;

  const int srow = tid >> 3;
  const int ls = ((tid & 7) ^ (srow & 7)) * 8;   // pre-swizzled global k-offset
  const unsigned short* gA = &xb[(size_t)(m0 + srow) * 512 + ls];
  const unsigned short* gB = &w1t[(size_t)(n0 + srow) * 512 + ls];
  char* lA = (char*)As + (size_t)wid * 1024;
  char* lB = (char*)Bs + (size_t)wid * 1024;

  f32x4 acc[4][4] = {};

  for (int kt = 0; kt < 8; ++kt) {
    const int k0 = kt * 64;
#pragma unroll
    for (int i = 0; i < 4; ++i)
      gload_lds16(gA + (size_t)i * 32 * 512 + k0, lA + i * 4096);
#pragma unroll
    for (int i = 0; i < 4; ++i)
      gload_lds16(gB + (size_t)i * 32 * 512 + k0, lB + i * 4096);
    __syncthreads();

#pragma unroll
    for (int kk = 0; kk < 2; ++kk) {
      short8 a[4], b[4];
#pragma unroll
      for (int m = 0; m < 4; ++m) {
        int row = wr * 64 + m * 16 + (lane & 15);
        int phys = (kk * 4 + (lane >> 4)) ^ (row & 7);
        a[m] = *(const short8*)((const char*)As + row * 128 + phys * 16);
      }
#pragma unroll
      for (int n = 0; n < 4; ++n) {
        int col = wc * 64 + n * 16 + (lane & 15);
        int phys = (kk * 4 + (lane >> 4)) ^ (col & 7);
        b[n] = *(const short8*)((const char*)Bs + col * 128 + phys * 16);
      }
#pragma unroll
      for (int m = 0; m < 4; ++m)
#pragma unroll
        for (int n = 0; n < 4; ++n)
          acc[m][n] = __builtin_amdgcn_mfma_f32_16x16x32_bf16(a[m], b[n], acc[m][n], 0, 0, 0);
    }
    __syncthreads();
  }

  const int colbase = n0 + wc * 64 + (lane & 15);
#pragma unroll
  for (int m = 0; m < 4; ++m) {
    int rowbase = m0 + wr * 64 + m * 16 + (lane >> 4) * 4;
#pragma unroll
    for (int j = 0; j < 4; ++j) {
      int row = rowbase + j;
      if (row < M) {
#pragma unroll
        for (int n = 0; n < 4; ++n)
          H1[(size_t)row * 256 + colbase + n * 16] = f2bf(acc[m][n][j]);
      }
    }
  }
}

// ---------------- GEMM2 (fp32 vector): C = relu(bn(A)) @ B -----------------------
constexpr int BM = 64, BN_T = 64, BK = 16;

__global__ __launch_bounds__(256) void gemm_f32_bn(
    const float* __restrict__ A, const float* __restrict__ B,
    float* __restrict__ C, int M, int K, int N,
    const float* __restrict__ scsh)
{
  __shared__ float AsT[BK][BM];
  __shared__ float Bs[BK][BN_T];
  const int tid = threadIdx.x;
  const int tx = tid & 15;
  const int ty = tid >> 4;
  const int m0 = blockIdx.x * BM;
  const int n0 = blockIdx.y * BN_T;
  const int lm  = tid >> 2;
  const int lk4 = (tid & 3) * 4;
  const int bk  = tid >> 4;
  const int bn  = (tid & 15) * 4;

  float acc[4][4] = {};

  for (int k0 = 0; k0 < K; k0 += BK) {
    const int am = m0 + lm;
    float4 av = make_float4(0.f, 0.f, 0.f, 0.f);
    if (am < M) av = *(const float4*)&A[(size_t)am * K + k0 + lk4];
    float4 sc = *(const float4*)&scsh[k0 + lk4];
    float4 sh = *(const float4*)&scsh[K + k0 + lk4];
    av.x = fmaxf(av.x * sc.x + sh.x, 0.f);
    av.y = fmaxf(av.y * sc.y + sh.y, 0.f);
    av.z = fmaxf(av.z * sc.z + sh.z, 0.f);
    av.w = fmaxf(av.w * sc.w + sh.w, 0.f);
    AsT[lk4 + 0][lm] = av.x;
    AsT[lk4 + 1][lm] = av.y;
    AsT[lk4 + 2][lm] = av.z;
    AsT[lk4 + 3][lm] = av.w;
    *(float4*)&Bs[bk][bn] = *(const float4*)&B[(size_t)(k0 + bk) * N + n0 + bn];
    __syncthreads();
#pragma unroll
    for (int k = 0; k < BK; ++k) {
      float4 a4 = *(const float4*)&AsT[k][ty * 4];
      float4 b4 = *(const float4*)&Bs[k][tx * 4];
      float a[4] = {a4.x, a4.y, a4.z, a4.w};
      float b[4] = {b4.x, b4.y, b4.z, b4.w};
#pragma unroll
      for (int i = 0; i < 4; ++i)
#pragma unroll
        for (int j = 0; j < 4; ++j)
          acc[i][j] = fmaf(a[i], b[j], acc[i][j]);
    }
    __syncthreads();
  }
#pragma unroll
  for (int i = 0; i < 4; ++i) {
    int m = m0 + ty * 4 + i;
    if (m < M)
      *(float4*)&C[(size_t)m * N + n0 + tx * 4] =
          make_float4(acc[i][0], acc[i][1], acc[i][2], acc[i][3]);
  }
}

// ---------------- CSR build: histogram -> 3-phase scan -> scatter ----------------
__global__ __launch_bounds__(256) void edge_hist(
    const int* __restrict__ rows, int* __restrict__ cnt, int E)
{
  int e = blockIdx.x * 256 + threadIdx.x;
  if (e < E) atomicAdd(&cnt[rows[e]], 1);
}

__global__ __launch_bounds__(256) void scan_blocksum(
    const int* __restrict__ cnt, int* __restrict__ bsum, int Nrows)
{
  int i = blockIdx.x * 256 + threadIdx.x;
  int v = (i < Nrows) ? cnt[i] : 0;
#pragma unroll
  for (int off = 1; off < 64; off <<= 1) v += __shfl_xor(v, off);
  __shared__ int wsum[4];
  if ((threadIdx.x & 63) == 0) wsum[threadIdx.x >> 6] = v;
  __syncthreads();
  if (threadIdx.x == 0)
    bsum[blockIdx.x] = wsum[0] + wsum[1] + wsum[2] + wsum[3];
}

__global__ __launch_bounds__(256) void scan_boff(
    const int* __restrict__ bsum, int* __restrict__ boff, int NB)
{
  __shared__ int lds[256];
  int t = threadIdx.x;
  int v = (t < NB) ? bsum[t] : 0;
  lds[t] = v;
  __syncthreads();
  for (int off = 1; off < 256; off <<= 1) {
    int u = (t >= off) ? lds[t - off] : 0;
    __syncthreads();
    lds[t] += u;
    __syncthreads();
  }
  boff[t] = (t == 0) ? 0 : lds[t - 1];
}

__global__ __launch_bounds__(256) void scan_write(
    const int* __restrict__ cnt, const int* __restrict__ boff,
    int* __restrict__ rowptr, int* __restrict__ cursor, int Nrows, int E)
{
  __shared__ int lds[256];
  int t = threadIdx.x;
  int i = blockIdx.x * 256 + t;
  int v = (i < Nrows) ? cnt[i] : 0;
  lds[t] = v;
  __syncthreads();
  for (int off = 1; off < 256; off <<= 1) {
    int u = (t >= off) ? lds[t - off] : 0;
    __syncthreads();
    lds[t] += u;
    __syncthreads();
  }
  int excl = boff[blockIdx.x] + lds[t] - v;
  if (i < Nrows) { rowptr[i] = excl; cursor[i] = excl; }
  if (i == Nrows) rowptr[i] = E;
}

__global__ __launch_bounds__(256) void edge_scatter(
    const int* __restrict__ rows, const int* __restrict__ cols,
    const float* __restrict__ vals, int* __restrict__ cursor,
    int* __restrict__ scols, float* __restrict__ svals, int E)
{
  int e = blockIdx.x * 256 + threadIdx.x;
  if (e < E) {
    int r = rows[e];
    int p = atomicAdd(&cursor[r], 1);
    scols[p] = cols[e];
    svals[p] = vals[e];
  }
}

// ---------------- SpMM gather (bf16 D, F=256): one wave per row ------------------
__global__ __launch_bounds__(256) void spmm_gather_bf(
    const int* __restrict__ rowptr, const int* __restrict__ scols,
    const float* __restrict__ svals, const unsigned short* __restrict__ D,
    float* __restrict__ out, int Nrows)
{
  const int lane = threadIdx.x & 63;
  const int r = blockIdx.x * 4 + (threadIdx.x >> 6);
  if (r >= Nrows) return;
  const int s = rowptr[r], e = rowptr[r + 1];
  float4 acc = make_float4(0.f, 0.f, 0.f, 0.f);
  int j = s;
  for (; j + 1 < e; j += 2) {
    int c0 = scols[j], c1 = scols[j + 1];
    float v0 = svals[j], v1 = svals[j + 1];
    ushort4 d0 = *(const ushort4*)&D[(size_t)c0 * 256 + lane * 4];
    ushort4 d1 = *(const ushort4*)&D[(size_t)c1 * 256 + lane * 4];
    acc.x = fmaf(v0, bf2f(d0.x), acc.x); acc.y = fmaf(v0, bf2f(d0.y), acc.y);
    acc.z = fmaf(v0, bf2f(d0.z), acc.z); acc.w = fmaf(v0, bf2f(d0.w), acc.w);
    acc.x = fmaf(v1, bf2f(d1.x), acc.x); acc.y = fmaf(v1, bf2f(d1.y), acc.y);
    acc.z = fmaf(v1, bf2f(d1.z), acc.z); acc.w = fmaf(v1, bf2f(d1.w), acc.w);
  }
  if (j < e) {
    int c = scols[j]; float v = svals[j];
    ushort4 d = *(const ushort4*)&D[(size_t)c * 256 + lane * 4];
    acc.x = fmaf(v, bf2f(d.x), acc.x); acc.y = fmaf(v, bf2f(d.y), acc.y);
    acc.z = fmaf(v, bf2f(d.z), acc.z); acc.w = fmaf(v, bf2f(d.w), acc.w);
  }
  *(float4*)&out[(size_t)r * 256 + lane * 4] = acc;
}

// ---------------- SpMM gather (fp32 D, F=64): one wave per row -------------------
__global__ __launch_bounds__(256) void spmm_gather_f32_64(
    const int* __restrict__ rowptr, const int* __restrict__ scols,
    const float* __restrict__ svals, const float* __restrict__ D,
    float* __restrict__ out, int Nrows)
{
  const int lane = threadIdx.x & 63;
  const int r = blockIdx.x * 4 + (threadIdx.x >> 6);
  if (r >= Nrows) return;
  const int s = rowptr[r], e = rowptr[r + 1];
  float acc = 0.f;
  int j = s;
  for (; j + 1 < e; j += 2) {
    int c0 = scols[j], c1 = scols[j + 1];
    float v0 = svals[j], v1 = svals[j + 1];
    acc = fmaf(v0, D[(size_t)c0 * 64 + lane], acc);
    acc = fmaf(v1, D[(size_t)c1 * 64 + lane], acc);
  }
  if (j < e) acc = fmaf(svals[j], D[(size_t)scols[j] * 64 + lane], acc);
  out[(size_t)r * 64 + lane] = acc;
}

// ---------------- BN stats: per-block partials, NO atomics ----------------------
template<int C>
__global__ __launch_bounds__(256) void bn_stats(
    const float* __restrict__ H, float* __restrict__ partials, int Nrows)
{
  constexpr int C4 = C / 4;
  constexpr int RPB = 256 / C4;
  const int cc = threadIdx.x % C4;
  const int c = cc * 4;
  const int rr = threadIdx.x / C4;
  float4 s = make_float4(0.f, 0.f, 0.f, 0.f);
  float4 q = make_float4(0.f, 0.f, 0.f, 0.f);
  for (int r = blockIdx.x * RPB + rr; r < Nrows; r += gridDim.x * RPB) {
    float4 v = *(const float4*)&H[(size_t)r * C + c];
    s.x += v.x; s.y += v.y; s.z += v.z; s.w += v.w;
    q.x += v.x * v.x; q.y += v.y * v.y; q.z += v.z * v.z; q.w += v.w * v.w;
  }
  __shared__ float lds[256][8];
  float* L = lds[threadIdx.x];
  L[0] = s.x; L[1] = s.y; L[2] = s.z; L[3] = s.w;
  L[4] = q.x; L[5] = q.y; L[6] = q.z; L[7] = q.w;
  __syncthreads();
  if (rr == 0) {
#pragma unroll
    for (int r = 1; r < RPB; ++r) {
      float* Mm = lds[cc + r * C4];
      s.x += Mm[0]; s.y += Mm[1]; s.z += Mm[2]; s.w += Mm[3];
      q.x += Mm[4]; q.y += Mm[5]; q.z += Mm[6]; q.w += Mm[7];
    }
    float* P = &partials[(size_t)blockIdx.x * 2 * C];
    *(float4*)&P[c] = s;
    *(float4*)&P[C + c] = q;
  }
}

// ---------------- BN finalize (parallel): one block per channel ------------------
template<int C>
__global__ __launch_bounds__(256) void bn_finalize_par(
    const float* __restrict__ partials,
    const float* __restrict__ gamma, const float* __restrict__ beta,
    float* __restrict__ scsh, int G, float invN)
{
  const int c = blockIdx.x;
  const int t = threadIdx.x;
  float sum = 0.f, sq = 0.f;
  for (int g = t; g < G; g += 256) {
    sum += partials[(size_t)g * 2 * C + c];
    sq  += partials[(size_t)g * 2 * C + C + c];
  }
#pragma unroll
  for (int off = 1; off < 64; off <<= 1) {
    sum += __shfl_xor(sum, off);
    sq  += __shfl_xor(sq, off);
  }
  __shared__ float ws[4][2];
  if ((t & 63) == 0) { ws[t >> 6][0] = sum; ws[t >> 6][1] = sq; }
  __syncthreads();
  if (t == 0) {
    sum = ws[0][0] + ws[1][0] + ws[2][0] + ws[3][0];
    sq  = ws[0][1] + ws[1][1] + ws[2][1] + ws[3][1];
    float mean = sum * invN;
    float var = sq * invN - mean * mean;
    float rstd = rsqrtf(var + 1e-5f);
    float sc = gamma[c] * rstd;
    scsh[c] = sc;
    scsh[C + c] = beta[c] - mean * sc;
  }
}

// ---------------- BN2 apply + log_softmax ----------------------------------------
__global__ __launch_bounds__(256) void bn_lsm(
    const float* __restrict__ H, const float* __restrict__ scsh,
    float* __restrict__ out, int Nrows)
{
  int lane = threadIdx.x & 63;
  int r = blockIdx.x * 4 + (threadIdx.x >> 6);
  if (r >= Nrows) return;
  float y = H[(size_t)r * 64 + lane] * scsh[lane] + scsh[64 + lane];
  float m = y;
#pragma unroll
  for (int off = 32; off >= 1; off >>= 1) m = fmaxf(m, __shfl_xor(m, off));
  float ex = expf(y - m);
  float s = ex;
#pragma unroll
  for (int off = 32; off >= 1; off >>= 1) s += __shfl_xor(s, off);
  out[(size_t)r * 64 + lane] = (y - m) - logf(s);
}

extern "C" void kernel_launch(void* const* d_in, const int* in_sizes, int n_in,
                              void* d_out, int out_size, void* d_ws, size_t ws_size,
                              hipStream_t stream) {
  const float* x      = (const float*)d_in[0];
  const int*   erow   = (const int*)  d_in[1];
  const int*   ecol   = (const int*)  d_in[2];
  const float* eval   = (const float*)d_in[3];
  const float* W1     = (const float*)d_in[4];
  // d_in[5] = b1 : cancels exactly in training-mode BN (shift-invariant)
  const float* gamma1 = (const float*)d_in[6];
  const float* beta1  = (const float*)d_in[7];
  const float* W2     = (const float*)d_in[8];
  // d_in[9] = b2 : cancels in BN2
  const float* gamma2 = (const float*)d_in[10];
  const float* beta2  = (const float*)d_in[11];

  const int N = in_sizes[0] / 512;   // 50000
  const int E = in_sizes[1];         // 800000

  char* ws = (char*)d_ws;
  unsigned short* H1b   = (unsigned short*)(ws + 0);
  float* partials1      = (float*)(ws + 0);
  float* H2             = (float*)(ws + 0);
  float* H2AGG          = (float*)(ws + 12800000);
  unsigned short* xb    = (unsigned short*)(ws + 25600000);
  float* H1AGG          = (float*)(ws + 25600000);
  float* partials2      = (float*)(ws + 25600000);
  unsigned short* w1t   = (unsigned short*)(ws + 76865536);
  float* scsh1          = (float*)(ws + 77127680);
  float* scsh2          = (float*)(ws + 77129728);
  int*   rowptr         = (int*)(ws + 77130240);
  int*   cnt            = (int*)(ws + 77330244);
  int*   cursor         = (int*)(ws + 77530244);
  int*   scols          = (int*)(ws + 77730244);
  float* svals          = (float*)(ws + 80930244);
  int*   bsum           = (int*)(ws + 84130244);   // <=256 ints
  int*   boff           = (int*)(ws + 84131268);   // 256 ints

  hipMemsetAsync(cnt, 0, (size_t)N * 4, stream);

  const dim3 blk(256);
  const int eblocks = (E + 255) / 256;
  const int NB = (N + 255) / 256;   // 196 <= 256

  // CSR build
  edge_hist<<<eblocks, blk, 0, stream>>>(erow, cnt, E);
  scan_blocksum<<<NB, blk, 0, stream>>>(cnt, bsum, N);
  scan_boff<<<1, blk, 0, stream>>>(bsum, boff, NB);
  scan_write<<<NB + 1, blk, 0, stream>>>(cnt, boff, rowptr, cursor, N, E);
  edge_scatter<<<eblocks, blk, 0, stream>>>(erow, ecol, eval, cursor, scols, svals, E);

  // bf16 conversions
  cvt_f32_bf16<<<(N * 512 / 8 + 255) / 256, blk, 0, stream>>>(x, xb, N * 512 / 8);
  cvt_w1t<<<512 * 256 / 256, blk, 0, stream>>>(W1, w1t);

  // layer 1: H1 = x @ W1 (bf16 MFMA, bf16 out)
  gemm1_mfma<<<dim3((N + 127) / 128, 2), blk, 0, stream>>>(xb, w1t, H1b, N);
  // H1AGG = A @ H1 (gather from bf16)
  spmm_gather_bf<<<(N + 3) / 4, blk, 0, stream>>>(rowptr, scols, svals, H1b, H1AGG, N);
  // BN1
  bn_stats<256><<<256, blk, 0, stream>>>(H1AGG, partials1, N);
  bn_finalize_par<256><<<256, blk, 0, stream>>>(partials1, gamma1, beta1, scsh1, 256, 1.0f / N);
  // layer 2: H2 = relu(bn1(H1AGG)) @ W2
  gemm_f32_bn<<<dim3((N + BM - 1) / BM, 1), blk, 0, stream>>>(
      H1AGG, W2, H2, N, 256, 64, scsh1);
  // H2AGG = A @ H2
  spmm_gather_f32_64<<<(N + 3) / 4, blk, 0, stream>>>(rowptr, scols, svals, H2, H2AGG, N);
  // BN2
  bn_stats<64><<<256, blk, 0, stream>>>(H2AGG, partials2, N);
  bn_finalize_par<64><<<64, blk, 0, stream>>>(partials2, gamma2, beta2, scsh2, 256, 1.0f / N);
  // BN2 apply + log_softmax
  bn_lsm<<<(N + 3) / 4, blk, 0, stream>>>(H2AGG, scsh2, (float*)d_out, N);
}

// Round 7
// 318.711 us; speedup vs baseline: 13.0493x; 1.0827x over previous
//
#include <hip/hip_runtime.h>

typedef __attribute__((ext_vector_type(8))) short short8;   // 8 bf16 (4 VGPRs)
typedef __attribute__((ext_vector_type(4))) float f32x4;
typedef __attribute__((ext_vector_type(8))) unsigned short ushort8;

__device__ __forceinline__ unsigned short f2bf(float f) {
  unsigned int u = __builtin_bit_cast(unsigned int, f);
  u += 0x7fffu + ((u >> 16) & 1u);   // RNE
  return (unsigned short)(u >> 16);
}
__device__ __forceinline__ float bf2f(unsigned short b) {
  return __builtin_bit_cast(float, ((unsigned int)b) << 16);
}
__device__ __forceinline__ void gload_lds16(const void* g, void* l) {
  __builtin_amdgcn_global_load_lds(
      (const __attribute__((address_space(1))) void*)g,
      (__attribute__((address_space(3))) void*)l, 16, 0, 0);
}

// ---------------- W1 [512][256] fp32 -> W1T [256][512] bf16 ----------------------
__global__ __launch_bounds__(256) void cvt_w1t(
    const float* __restrict__ W1, unsigned short* __restrict__ W1T)
{
  int idx = blockIdx.x * 256 + threadIdx.x;   // 131072 total
  int n = idx >> 9, k = idx & 511;
  W1T[idx] = f2bf(W1[(size_t)k * 256 + n]);
}

// ---------------- W2 [256][64] fp32 -> W2T [64][256] bf16 ------------------------
__global__ __launch_bounds__(256) void cvt_w2t(
    const float* __restrict__ W2, unsigned short* __restrict__ W2T)
{
  int idx = blockIdx.x * 256 + threadIdx.x;   // 16384 total
  int n = idx >> 8, k = idx & 255;
  W2T[idx] = f2bf(W2[(size_t)k * 64 + n]);
}

// ---------------- GEMM1: H1_bf16[M,256] = x_f32[M,512] @ W1 (cast fused) ---------
// 128x256 tile (x read once), BK=64, 4 waves 2x2 (wave: 64 rows x 128 cols).
// A: fp32 global -> cvt -> swizzled ds_write. B: global_load_lds, pre-swz source.
__global__ __launch_bounds__(256) void gemm1_mfma(
    const float* __restrict__ x,             // [M][512] fp32
    const unsigned short* __restrict__ w1t,  // [256][512] bf16
    unsigned short* __restrict__ H1,         // [M][256] bf16 out
    int M)
{
  __shared__ unsigned short As[128 * 64];  // 16 KB, [row][64k] swizzled
  __shared__ unsigned short Bs[256 * 64];  // 32 KB, [col][64k] swizzled
  const int tid = threadIdx.x;
  const int wid = tid >> 6, lane = tid & 63;
  const int wr = wid >> 1, wc = wid & 1;
  const int m0 = blockIdx.x * 128;

  const int srow = tid >> 3;                       // 0..31 (B staging)
  const int ls = ((tid & 7) ^ (srow & 7)) * 8;     // pre-swizzled k-offset
  const unsigned short* gB = &w1t[(size_t)srow * 512 + ls];
  char* lB = (char*)Bs + (size_t)wid * 1024;

  f32x4 acc[4][8] = {};

  for (int kt = 0; kt < 8; ++kt) {
    const int k0 = kt * 64;
    // B: 8 x 32 rows via global_load_lds (issued first, async)
#pragma unroll
    for (int i = 0; i < 8; ++i)
      gload_lds16(gB + (size_t)i * 32 * 512 + k0, lB + (size_t)i * 4096);
    // A: reg-staged fp32 -> bf16, swizzled ds_write (4 chunks/thread)
#pragma unroll
    for (int i = 0; i < 4; ++i) {
      int chunk = tid + 256 * i;
      int r = chunk >> 3, c = chunk & 7;
      int grow = m0 + r;
      float v[8] = {0.f, 0.f, 0.f, 0.f, 0.f, 0.f, 0.f, 0.f};
      if (grow < M) {
        float4 lo = *(const float4*)&x[(size_t)grow * 512 + k0 + c * 8];
        float4 hi = *(const float4*)&x[(size_t)grow * 512 + k0 + c * 8 + 4];
        v[0] = lo.x; v[1] = lo.y; v[2] = lo.z; v[3] = lo.w;
        v[4] = hi.x; v[5] = hi.y; v[6] = hi.z; v[7] = hi.w;
      }
      ushort8 o;
#pragma unroll
      for (int j = 0; j < 8; ++j) o[j] = f2bf(v[j]);
      *(ushort8*)((char*)As + r * 128 + ((c ^ (r & 7)) * 16)) = o;
    }
    __syncthreads();

#pragma unroll
    for (int kk = 0; kk < 2; ++kk) {
      short8 a[4], b[8];
#pragma unroll
      for (int m = 0; m < 4; ++m) {
        int row = wr * 64 + m * 16 + (lane & 15);
        int phys = (kk * 4 + (lane >> 4)) ^ (row & 7);
        a[m] = *(const short8*)((const char*)As + row * 128 + phys * 16);
      }
#pragma unroll
      for (int n = 0; n < 8; ++n) {
        int col = wc * 128 + n * 16 + (lane & 15);
        int phys = (kk * 4 + (lane >> 4)) ^ (col & 7);
        b[n] = *(const short8*)((const char*)Bs + col * 128 + phys * 16);
      }
#pragma unroll
      for (int m = 0; m < 4; ++m)
#pragma unroll
        for (int n = 0; n < 8; ++n)
          acc[m][n] = __builtin_amdgcn_mfma_f32_16x16x32_bf16(a[m], b[n], acc[m][n], 0, 0, 0);
    }
    __syncthreads();
  }

  const int colbase = wc * 128 + (lane & 15);
#pragma unroll
  for (int m = 0; m < 4; ++m) {
    int rowbase = m0 + wr * 64 + m * 16 + (lane >> 4) * 4;
#pragma unroll
    for (int j = 0; j < 4; ++j) {
      int row = rowbase + j;
      if (row < M) {
#pragma unroll
        for (int n = 0; n < 8; ++n)
          H1[(size_t)row * 256 + colbase + n * 16] = f2bf(acc[m][n][j]);
      }
    }
  }
}

// ---------------- GEMM2: H2_bf16[M,64] = relu(bn1(H1AGG_bf16)) @ W2 (MFMA) -------
// 128x64 tile, BK=64, 4 waves 2x2 (wave: 64 rows x 32 cols). BN fused in A-stage.
__global__ __launch_bounds__(256) void gemm2_mfma(
    const unsigned short* __restrict__ A,    // H1AGG bf16 [Mpad][256]
    const unsigned short* __restrict__ w2t,  // [64][256] bf16
    const float* __restrict__ scsh,          // [256] scale | [256] shift
    unsigned short* __restrict__ H2,         // [M][64] bf16 out
    int M)
{
  __shared__ unsigned short As[128 * 64];  // 16 KB
  __shared__ unsigned short Bs[64 * 64];   // 8 KB
  const int tid = threadIdx.x;
  const int wid = tid >> 6, lane = tid & 63;
  const int wr = wid >> 1, wc = wid & 1;
  const int m0 = blockIdx.x * 128;

  const int srow = tid >> 3;
  const int ls = ((tid & 7) ^ (srow & 7)) * 8;
  const unsigned short* gB = &w2t[(size_t)srow * 256 + ls];
  char* lB = (char*)Bs + (size_t)wid * 1024;

  f32x4 acc[4][2] = {};

  for (int kt = 0; kt < 4; ++kt) {
    const int k0 = kt * 64;
#pragma unroll
    for (int i = 0; i < 2; ++i)
      gload_lds16(gB + (size_t)i * 32 * 256 + k0, lB + (size_t)i * 4096);
    // A: bf16 load -> BN+ReLU in fp32 -> bf16 -> swizzled ds_write
#pragma unroll
    for (int i = 0; i < 4; ++i) {
      int chunk = tid + 256 * i;
      int r = chunk >> 3, c = chunk & 7;
      int gk = k0 + c * 8;
      ushort8 u = *(const ushort8*)&A[(size_t)(m0 + r) * 256 + gk];
      float4 sc0 = *(const float4*)&scsh[gk];
      float4 sc1 = *(const float4*)&scsh[gk + 4];
      float4 sh0 = *(const float4*)&scsh[256 + gk];
      float4 sh1 = *(const float4*)&scsh[256 + gk + 4];
      ushort8 o;
      o[0] = f2bf(fmaxf(bf2f(u[0]) * sc0.x + sh0.x, 0.f));
      o[1] = f2bf(fmaxf(bf2f(u[1]) * sc0.y + sh0.y, 0.f));
      o[2] = f2bf(fmaxf(bf2f(u[2]) * sc0.z + sh0.z, 0.f));
      o[3] = f2bf(fmaxf(bf2f(u[3]) * sc0.w + sh0.w, 0.f));
      o[4] = f2bf(fmaxf(bf2f(u[4]) * sc1.x + sh1.x, 0.f));
      o[5] = f2bf(fmaxf(bf2f(u[5]) * sc1.y + sh1.y, 0.f));
      o[6] = f2bf(fmaxf(bf2f(u[6]) * sc1.z + sh1.z, 0.f));
      o[7] = f2bf(fmaxf(bf2f(u[7]) * sc1.w + sh1.w, 0.f));
      *(ushort8*)((char*)As + r * 128 + ((c ^ (r & 7)) * 16)) = o;
    }
    __syncthreads();

#pragma unroll
    for (int kk = 0; kk < 2; ++kk) {
      short8 a[4], b[2];
#pragma unroll
      for (int m = 0; m < 4; ++m) {
        int row = wr * 64 + m * 16 + (lane & 15);
        int phys = (kk * 4 + (lane >> 4)) ^ (row & 7);
        a[m] = *(const short8*)((const char*)As + row * 128 + phys * 16);
      }
#pragma unroll
      for (int n = 0; n < 2; ++n) {
        int col = wc * 32 + n * 16 + (lane & 15);
        int phys = (kk * 4 + (lane >> 4)) ^ (col & 7);
        b[n] = *(const short8*)((const char*)Bs + col * 128 + phys * 16);
      }
#pragma unroll
      for (int m = 0; m < 4; ++m)
#pragma unroll
        for (int n = 0; n < 2; ++n)
          acc[m][n] = __builtin_amdgcn_mfma_f32_16x16x32_bf16(a[m], b[n], acc[m][n], 0, 0, 0);
    }
    __syncthreads();
  }

  const int colbase = wc * 32 + (lane & 15);
#pragma unroll
  for (int m = 0; m < 4; ++m) {
    int rowbase = m0 + wr * 64 + m * 16 + (lane >> 4) * 4;
#pragma unroll
    for (int j = 0; j < 4; ++j) {
      int row = rowbase + j;
      if (row < M) {
#pragma unroll
        for (int n = 0; n < 2; ++n)
          H2[(size_t)row * 64 + colbase + n * 16] = f2bf(acc[m][n][j]);
      }
    }
  }
}

// ---------------- CSR build: histogram -> 3-phase scan -> scatter ----------------
__global__ __launch_bounds__(256) void edge_hist(
    const int* __restrict__ rows, int* __restrict__ cnt, int E)
{
  int e = blockIdx.x * 256 + threadIdx.x;
  if (e < E) atomicAdd(&cnt[rows[e]], 1);
}

__global__ __launch_bounds__(256) void scan_blocksum(
    const int* __restrict__ cnt, int* __restrict__ bsum, int Nrows)
{
  int i = blockIdx.x * 256 + threadIdx.x;
  int v = (i < Nrows) ? cnt[i] : 0;
#pragma unroll
  for (int off = 1; off < 64; off <<= 1) v += __shfl_xor(v, off);
  __shared__ int wsum[4];
  if ((threadIdx.x & 63) == 0) wsum[threadIdx.x >> 6] = v;
  __syncthreads();
  if (threadIdx.x == 0)
    bsum[blockIdx.x] = wsum[0] + wsum[1] + wsum[2] + wsum[3];
}

__global__ __launch_bounds__(256) void scan_boff(
    const int* __restrict__ bsum, int* __restrict__ boff, int NB)
{
  __shared__ int lds[256];
  int t = threadIdx.x;
  int v = (t < NB) ? bsum[t] : 0;
  lds[t] = v;
  __syncthreads();
  for (int off = 1; off < 256; off <<= 1) {
    int u = (t >= off) ? lds[t - off] : 0;
    __syncthreads();
    lds[t] += u;
    __syncthreads();
  }
  boff[t] = (t == 0) ? 0 : lds[t - 1];
}

__global__ __launch_bounds__(256) void scan_write(
    const int* __restrict__ cnt, const int* __restrict__ boff,
    int* __restrict__ rowptr, int* __restrict__ cursor, int Nrows, int E)
{
  __shared__ int lds[256];
  int t = threadIdx.x;
  int i = blockIdx.x * 256 + t;
  int v = (i < Nrows) ? cnt[i] : 0;
  lds[t] = v;
  __syncthreads();
  for (int off = 1; off < 256; off <<= 1) {
    int u = (t >= off) ? lds[t - off] : 0;
    __syncthreads();
    lds[t] += u;
    __syncthreads();
  }
  int excl = boff[blockIdx.x] + lds[t] - v;
  if (i < Nrows) { rowptr[i] = excl; cursor[i] = excl; }
  if (i == Nrows) rowptr[i] = E;
}

__global__ __launch_bounds__(256) void edge_scatter(
    const int* __restrict__ rows, const int* __restrict__ cols,
    const float* __restrict__ vals, int* __restrict__ cursor,
    int* __restrict__ scols, float* __restrict__ svals, int E)
{
  int e = blockIdx.x * 256 + threadIdx.x;
  if (e < E) {
    int r = rows[e];
    int p = atomicAdd(&cursor[r], 1);
    scols[p] = cols[e];
    svals[p] = vals[e];
  }
}

// ---------------- SpMM gather (bf16 D, F=256) -> bf16 out ------------------------
__global__ __launch_bounds__(256) void spmm_gather_bf(
    const int* __restrict__ rowptr, const int* __restrict__ scols,
    const float* __restrict__ svals, const unsigned short* __restrict__ D,
    unsigned short* __restrict__ out, int Nrows)
{
  const int lane = threadIdx.x & 63;
  const int r = blockIdx.x * 4 + (threadIdx.x >> 6);
  if (r >= Nrows) return;
  const int s = rowptr[r], e = rowptr[r + 1];
  float4 acc = make_float4(0.f, 0.f, 0.f, 0.f);
  int j = s;
  for (; j + 1 < e; j += 2) {
    int c0 = scols[j], c1 = scols[j + 1];
    float v0 = svals[j], v1 = svals[j + 1];
    ushort4 d0 = *(const ushort4*)&D[(size_t)c0 * 256 + lane * 4];
    ushort4 d1 = *(const ushort4*)&D[(size_t)c1 * 256 + lane * 4];
    acc.x = fmaf(v0, bf2f(d0.x), acc.x); acc.y = fmaf(v0, bf2f(d0.y), acc.y);
    acc.z = fmaf(v0, bf2f(d0.z), acc.z); acc.w = fmaf(v0, bf2f(d0.w), acc.w);
    acc.x = fmaf(v1, bf2f(d1.x), acc.x); acc.y = fmaf(v1, bf2f(d1.y), acc.y);
    acc.z = fmaf(v1, bf2f(d1.z), acc.z); acc.w = fmaf(v1, bf2f(d1.w), acc.w);
  }
  if (j < e) {
    int c = scols[j]; float v = svals[j];
    ushort4 d = *(const ushort4*)&D[(size_t)c * 256 + lane * 4];
    acc.x = fmaf(v, bf2f(d.x), acc.x); acc.y = fmaf(v, bf2f(d.y), acc.y);
    acc.z = fmaf(v, bf2f(d.z), acc.z); acc.w = fmaf(v, bf2f(d.w), acc.w);
  }
  ushort4 ov;
  ov.x = f2bf(acc.x); ov.y = f2bf(acc.y); ov.z = f2bf(acc.z); ov.w = f2bf(acc.w);
  *(ushort4*)&out[(size_t)r * 256 + lane * 4] = ov;
}

// ---------------- SpMM gather (bf16 D, F=64) -> fp32 out -------------------------
__global__ __launch_bounds__(256) void spmm_gather_bf64(
    const int* __restrict__ rowptr, const int* __restrict__ scols,
    const float* __restrict__ svals, const unsigned short* __restrict__ D,
    float* __restrict__ out, int Nrows)
{
  const int lane = threadIdx.x & 63;
  const int r = blockIdx.x * 4 + (threadIdx.x >> 6);
  if (r >= Nrows) return;
  const int s = rowptr[r], e = rowptr[r + 1];
  float acc = 0.f;
  int j = s;
  for (; j + 1 < e; j += 2) {
    int c0 = scols[j], c1 = scols[j + 1];
    float v0 = svals[j], v1 = svals[j + 1];
    acc = fmaf(v0, bf2f(D[(size_t)c0 * 64 + lane]), acc);
    acc = fmaf(v1, bf2f(D[(size_t)c1 * 64 + lane]), acc);
  }
  if (j < e) acc = fmaf(svals[j], bf2f(D[(size_t)scols[j] * 64 + lane]), acc);
  out[(size_t)r * 64 + lane] = acc;
}

// ---------------- BN1 stats from bf16 H (C=256), per-block partials --------------
__global__ __launch_bounds__(256) void bn_stats_bf256(
    const unsigned short* __restrict__ H, float* __restrict__ partials, int Nrows)
{
  const int cc = threadIdx.x & 31;    // col chunk (8 cols)
  const int c = cc * 8;
  const int rr = threadIdx.x >> 5;    // 0..7
  float s[8] = {}, q[8] = {};
  for (int r = blockIdx.x * 8 + rr; r < Nrows; r += gridDim.x * 8) {
    ushort8 u = *(const ushort8*)&H[(size_t)r * 256 + c];
#pragma unroll
    for (int j = 0; j < 8; ++j) {
      float f = bf2f(u[j]);
      s[j] += f; q[j] += f * f;
    }
  }
  __shared__ float lds[256][16];
  float* L = lds[threadIdx.x];
#pragma unroll
  for (int j = 0; j < 8; ++j) { L[j] = s[j]; L[8 + j] = q[j]; }
  __syncthreads();
  if (rr == 0) {
#pragma unroll
    for (int r2 = 1; r2 < 8; ++r2) {
      float* Mm = lds[cc + r2 * 32];
#pragma unroll
      for (int j = 0; j < 8; ++j) { s[j] += Mm[j]; q[j] += Mm[8 + j]; }
    }
    float* P = &partials[(size_t)blockIdx.x * 512];
#pragma unroll
    for (int j = 0; j < 8; ++j) { P[c + j] = s[j]; P[256 + c + j] = q[j]; }
  }
}

// ---------------- BN stats fp32 (C=64), per-block partials -----------------------
__global__ __launch_bounds__(256) void bn_stats64(
    const float* __restrict__ H, float* __restrict__ partials, int Nrows)
{
  const int cc = threadIdx.x % 16;
  const int c = cc * 4;
  const int rr = threadIdx.x / 16;   // 0..15
  float4 s = make_float4(0.f, 0.f, 0.f, 0.f);
  float4 q = make_float4(0.f, 0.f, 0.f, 0.f);
  for (int r = blockIdx.x * 16 + rr; r < Nrows; r += gridDim.x * 16) {
    float4 v = *(const float4*)&H[(size_t)r * 64 + c];
    s.x += v.x; s.y += v.y; s.z += v.z; s.w += v.w;
    q.x += v.x * v.x; q.y += v.y * v.y; q.z += v.z * v.z; q.w += v.w * v.w;
  }
  __shared__ float lds[256][8];
  float* L = lds[threadIdx.x];
  L[0] = s.x; L[1] = s.y; L[2] = s.z; L[3] = s.w;
  L[4] = q.x; L[5] = q.y; L[6] = q.z; L[7] = q.w;
  __syncthreads();
  if (rr == 0) {
#pragma unroll
    for (int r2 = 1; r2 < 16; ++r2) {
      float* Mm = lds[cc + r2 * 16];
      s.x += Mm[0]; s.y += Mm[1]; s.z += Mm[2]; s.w += Mm[3];
      q.x += Mm[4]; q.y += Mm[5]; q.z += Mm[6]; q.w += Mm[7];
    }
    float* P = &partials[(size_t)blockIdx.x * 128];
    *(float4*)&P[c] = s;
    *(float4*)&P[64 + c] = q;
  }
}

// ---------------- BN finalize (parallel): one block per channel ------------------
template<int C>
__global__ __launch_bounds__(256) void bn_finalize_par(
    const float* __restrict__ partials,
    const float* __restrict__ gamma, const float* __restrict__ beta,
    float* __restrict__ scsh, int G, float invN)
{
  const int c = blockIdx.x;
  const int t = threadIdx.x;
  float sum = 0.f, sq = 0.f;
  for (int g = t; g < G; g += 256) {
    sum += partials[(size_t)g * 2 * C + c];
    sq  += partials[(size_t)g * 2 * C + C + c];
  }
#pragma unroll
  for (int off = 1; off < 64; off <<= 1) {
    sum += __shfl_xor(sum, off);
    sq  += __shfl_xor(sq, off);
  }
  __shared__ float ws[4][2];
  if ((t & 63) == 0) { ws[t >> 6][0] = sum; ws[t >> 6][1] = sq; }
  __syncthreads();
  if (t == 0) {
    sum = ws[0][0] + ws[1][0] + ws[2][0] + ws[3][0];
    sq  = ws[0][1] + ws[1][1] + ws[2][1] + ws[3][1];
    float mean = sum * invN;
    float var = sq * invN - mean * mean;
    float rstd = rsqrtf(var + 1e-5f);
    float sc = gamma[c] * rstd;
    scsh[c] = sc;
    scsh[C + c] = beta[c] - mean * sc;
  }
}

// ---------------- BN2 apply + log_softmax ----------------------------------------
__global__ __launch_bounds__(256) void bn_lsm(
    const float* __restrict__ H, const float* __restrict__ scsh,
    float* __restrict__ out, int Nrows)
{
  int lane = threadIdx.x & 63;
  int r = blockIdx.x * 4 + (threadIdx.x >> 6);
  if (r >= Nrows) return;
  float y = H[(size_t)r * 64 + lane] * scsh[lane] + scsh[64 + lane];
  float m = y;
#pragma unroll
  for (int off = 32; off >= 1; off >>= 1) m = fmaxf(m, __shfl_xor(m, off));
  float ex = expf(y - m);
  float s = ex;
#pragma unroll
  for (int off = 32; off >= 1; off >>= 1) s += __shfl_xor(s, off);
  out[(size_t)r * 64 + lane] = (y - m) - logf(s);
}

extern "C" void kernel_launch(void* const* d_in, const int* in_sizes, int n_in,
                              void* d_out, int out_size, void* d_ws, size_t ws_size,
                              hipStream_t stream) {
  const float* x      = (const float*)d_in[0];
  const int*   erow   = (const int*)  d_in[1];
  const int*   ecol   = (const int*)  d_in[2];
  const float* eval   = (const float*)d_in[3];
  const float* W1     = (const float*)d_in[4];
  // d_in[5] = b1 : cancels exactly in training-mode BN (shift-invariant)
  const float* gamma1 = (const float*)d_in[6];
  const float* beta1  = (const float*)d_in[7];
  const float* W2     = (const float*)d_in[8];
  // d_in[9] = b2 : cancels in BN2
  const float* gamma2 = (const float*)d_in[10];
  const float* beta2  = (const float*)d_in[11];

  const int N = in_sizes[0] / 512;   // 50000
  const int E = in_sizes[1];         // 800000

  char* ws = (char*)d_ws;
  // [0, 25.6M): H1 bf16 (dead after spmm1) -> partials1(512K) -> H2b[0,6.4M) + H2AGG[12.8M,25.6M)
  // [51.2M, 76.86M): H1AGG bf16 (+pad rows to 50048; dead after gemm2) -> partials2(128K)
  unsigned short* H1b   = (unsigned short*)(ws + 0);
  float* partials1      = (float*)(ws + 0);
  unsigned short* H2b   = (unsigned short*)(ws + 0);
  float* H2AGG          = (float*)(ws + 12800000);
  unsigned short* H1AGGb= (unsigned short*)(ws + 51200000);
  float* partials2      = (float*)(ws + 51200000);
  unsigned short* w1t   = (unsigned short*)(ws + 76865536);   // 256 KB
  float* scsh1          = (float*)(ws + 77127680);            // 512 f
  float* scsh2          = (float*)(ws + 77129728);            // 128 f
  int*   rowptr         = (int*)(ws + 77130240);
  int*   cnt            = (int*)(ws + 77330244);
  int*   cursor         = (int*)(ws + 77530244);
  int*   scols          = (int*)(ws + 77730244);
  float* svals          = (float*)(ws + 80930244);
  int*   bsum           = (int*)(ws + 84130244);
  int*   boff           = (int*)(ws + 84131268);
  unsigned short* w2t   = (unsigned short*)(ws + 84132352);   // 32 KB

  hipMemsetAsync(cnt, 0, (size_t)N * 4, stream);

  const dim3 blk(256);
  const int eblocks = (E + 255) / 256;
  const int NB = (N + 255) / 256;   // 196 <= 256

  // CSR build
  edge_hist<<<eblocks, blk, 0, stream>>>(erow, cnt, E);
  scan_blocksum<<<NB, blk, 0, stream>>>(cnt, bsum, N);
  scan_boff<<<1, blk, 0, stream>>>(bsum, boff, NB);
  scan_write<<<NB + 1, blk, 0, stream>>>(cnt, boff, rowptr, cursor, N, E);
  edge_scatter<<<eblocks, blk, 0, stream>>>(erow, ecol, eval, cursor, scols, svals, E);

  // weight conversions (tiny)
  cvt_w1t<<<512, blk, 0, stream>>>(W1, w1t);
  cvt_w2t<<<64, blk, 0, stream>>>(W2, w2t);

  // layer 1: H1 = x @ W1 (fp32 in, cast fused, bf16 out)
  gemm1_mfma<<<(N + 127) / 128, blk, 0, stream>>>(x, w1t, H1b, N);
  // H1AGG = A @ H1 (gather, bf16 out)
  spmm_gather_bf<<<(N + 3) / 4, blk, 0, stream>>>(rowptr, scols, svals, H1b, H1AGGb, N);
  // BN1
  bn_stats_bf256<<<256, blk, 0, stream>>>(H1AGGb, partials1, N);
  bn_finalize_par<256><<<256, blk, 0, stream>>>(partials1, gamma1, beta1, scsh1, 256, 1.0f / N);
  // layer 2: H2 = relu(bn1(H1AGG)) @ W2 (MFMA, BN fused in A-stage, bf16 out)
  gemm2_mfma<<<(N + 127) / 128, blk, 0, stream>>>(H1AGGb, w2t, scsh1, H2b, N);
  // H2AGG = A @ H2 (gather from bf16, fp32 out)
  spmm_gather_bf64<<<(N + 3) / 4, blk, 0, stream>>>(rowptr, scols, svals, H2b, H2AGG, N);
  // BN2
  bn_stats64<<<256, blk, 0, stream>>>(H2AGG, partials2, N);
  bn_finalize_par<64><<<64, blk, 0, stream>>>(partials2, gamma2, beta2, scsh2, 256, 1.0f / N);
  // BN2 apply + log_softmax
  bn_lsm<<<(N + 3) / 4, blk, 0, stream>>>(H2AGG, scsh2, (float*)d_out, N);
}

// Round 8
// 303.878 us; speedup vs baseline: 13.6863x; 1.0488x over previous
//
#include <hip/hip_runtime.h>

typedef __attribute__((ext_vector_type(8))) short short8;   // 8 bf16 (4 VGPRs)
typedef __attribute__((ext_vector_type(4))) float f32x4;
typedef __attribute__((ext_vector_type(8))) unsigned short ushort8;

__device__ __forceinline__ unsigned short f2bf(float f) {
  unsigned int u = __builtin_bit_cast(unsigned int, f);
  u += 0x7fffu + ((u >> 16) & 1u);   // RNE
  return (unsigned short)(u >> 16);
}
__device__ __forceinline__ float bf2f(unsigned short b) {
  return __builtin_bit_cast(float, ((unsigned int)b) << 16);
}
__device__ __forceinline__ void gload_lds16(const void* g, void* l) {
  __builtin_amdgcn_global_load_lds(
      (const __attribute__((address_space(1))) void*)g,
      (__attribute__((address_space(3))) void*)l, 16, 0, 0);
}

// ---------------- W1 [512][256] fp32 -> W1T [256][512] bf16 ----------------------
__global__ __launch_bounds__(256) void cvt_w1t(
    const float* __restrict__ W1, unsigned short* __restrict__ W1T)
{
  int idx = blockIdx.x * 256 + threadIdx.x;   // 131072 total
  int n = idx >> 9, k = idx & 511;
  W1T[idx] = f2bf(W1[(size_t)k * 256 + n]);
}

// ---------------- W2 [256][64] fp32 -> W2T [64][256] bf16 ------------------------
__global__ __launch_bounds__(256) void cvt_w2t(
    const float* __restrict__ W2, unsigned short* __restrict__ W2T)
{
  int idx = blockIdx.x * 256 + threadIdx.x;   // 16384 total
  int n = idx >> 8, k = idx & 255;
  W2T[idx] = f2bf(W2[(size_t)k * 64 + n]);
}

// ---------------- GEMM1: H1_bf16[M,256] = x_f32[M,512] @ W1 (cast fused) ---------
// 64x256 tile (x read once, 782 blocks), BK=64, 4 waves 1x4 (wave: 64r x 64c).
// A: fp32 global -> cvt -> swizzled ds_write. B: global_load_lds, pre-swz source.
__global__ __launch_bounds__(256) void gemm1_mfma(
    const float* __restrict__ x,             // [M][512] fp32
    const unsigned short* __restrict__ w1t,  // [256][512] bf16
    unsigned short* __restrict__ H1,         // [M][256] bf16 out
    int M)
{
  __shared__ unsigned short As[64 * 64];   // 8 KB, [row][64k] swizzled
  __shared__ unsigned short Bs[256 * 64];  // 32 KB, [col][64k] swizzled
  const int tid = threadIdx.x;
  const int wid = tid >> 6, lane = tid & 63;
  const int wc = wid;                      // wave col-quadrant (0..3)
  const int m0 = blockIdx.x * 64;

  const int srow = tid >> 3;                       // 0..31 (B staging)
  const int ls = ((tid & 7) ^ (srow & 7)) * 8;     // pre-swizzled k-offset
  const unsigned short* gB = &w1t[(size_t)srow * 512 + ls];
  char* lB = (char*)Bs + (size_t)wid * 1024;

  f32x4 acc[4][4] = {};

  for (int kt = 0; kt < 8; ++kt) {
    const int k0 = kt * 64;
    // B: 8 x 32 rows via global_load_lds (issued first, async)
#pragma unroll
    for (int i = 0; i < 8; ++i)
      gload_lds16(gB + (size_t)i * 32 * 512 + k0, lB + (size_t)i * 4096);
    // A: reg-staged fp32 -> bf16, swizzled ds_write (2 chunks/thread, 64 rows)
#pragma unroll
    for (int i = 0; i < 2; ++i) {
      int chunk = tid + 256 * i;
      int r = chunk >> 3, c = chunk & 7;
      int grow = m0 + r;
      float v[8] = {0.f, 0.f, 0.f, 0.f, 0.f, 0.f, 0.f, 0.f};
      if (grow < M) {
        float4 lo = *(const float4*)&x[(size_t)grow * 512 + k0 + c * 8];
        float4 hi = *(const float4*)&x[(size_t)grow * 512 + k0 + c * 8 + 4];
        v[0] = lo.x; v[1] = lo.y; v[2] = lo.z; v[3] = lo.w;
        v[4] = hi.x; v[5] = hi.y; v[6] = hi.z; v[7] = hi.w;
      }
      ushort8 o;
#pragma unroll
      for (int j = 0; j < 8; ++j) o[j] = f2bf(v[j]);
      *(ushort8*)((char*)As + r * 128 + ((c ^ (r & 7)) * 16)) = o;
    }
    __syncthreads();

#pragma unroll
    for (int kk = 0; kk < 2; ++kk) {
      short8 a[4], b[4];
#pragma unroll
      for (int m = 0; m < 4; ++m) {
        int row = m * 16 + (lane & 15);
        int phys = (kk * 4 + (lane >> 4)) ^ (row & 7);
        a[m] = *(const short8*)((const char*)As + row * 128 + phys * 16);
      }
#pragma unroll
      for (int n = 0; n < 4; ++n) {
        int col = wc * 64 + n * 16 + (lane & 15);
        int phys = (kk * 4 + (lane >> 4)) ^ (col & 7);
        b[n] = *(const short8*)((const char*)Bs + col * 128 + phys * 16);
      }
#pragma unroll
      for (int m = 0; m < 4; ++m)
#pragma unroll
        for (int n = 0; n < 4; ++n)
          acc[m][n] = __builtin_amdgcn_mfma_f32_16x16x32_bf16(a[m], b[n], acc[m][n], 0, 0, 0);
    }
    __syncthreads();
  }

  const int colbase = wc * 64 + (lane & 15);
#pragma unroll
  for (int m = 0; m < 4; ++m) {
    int rowbase = m0 + m * 16 + (lane >> 4) * 4;
#pragma unroll
    for (int j = 0; j < 4; ++j) {
      int row = rowbase + j;
      if (row < M) {
#pragma unroll
        for (int n = 0; n < 4; ++n)
          H1[(size_t)row * 256 + colbase + n * 16] = f2bf(acc[m][n][j]);
      }
    }
  }
}

// ---------------- GEMM2: H2_bf16[M,64] = relu(bn1(H1AGG_bf16)) @ W2 (MFMA) -------
// 128x64 tile, BK=64, 4 waves 2x2 (wave: 64 rows x 32 cols). BN fused in A-stage.
__global__ __launch_bounds__(256) void gemm2_mfma(
    const unsigned short* __restrict__ A,    // H1AGG bf16 [Mpad][256]
    const unsigned short* __restrict__ w2t,  // [64][256] bf16
    const float* __restrict__ scsh,          // [256] scale | [256] shift
    unsigned short* __restrict__ H2,         // [M][64] bf16 out
    int M)
{
  __shared__ unsigned short As[128 * 64];  // 16 KB
  __shared__ unsigned short Bs[64 * 64];   // 8 KB
  const int tid = threadIdx.x;
  const int wid = tid >> 6, lane = tid & 63;
  const int wr = wid >> 1, wc = wid & 1;
  const int m0 = blockIdx.x * 128;

  const int srow = tid >> 3;
  const int ls = ((tid & 7) ^ (srow & 7)) * 8;
  const unsigned short* gB = &w2t[(size_t)srow * 256 + ls];
  char* lB = (char*)Bs + (size_t)wid * 1024;

  f32x4 acc[4][2] = {};

  for (int kt = 0; kt < 4; ++kt) {
    const int k0 = kt * 64;
#pragma unroll
    for (int i = 0; i < 2; ++i)
      gload_lds16(gB + (size_t)i * 32 * 256 + k0, lB + (size_t)i * 4096);
    // A: bf16 load -> BN+ReLU in fp32 -> bf16 -> swizzled ds_write
#pragma unroll
    for (int i = 0; i < 4; ++i) {
      int chunk = tid + 256 * i;
      int r = chunk >> 3, c = chunk & 7;
      int gk = k0 + c * 8;
      ushort8 u = *(const ushort8*)&A[(size_t)(m0 + r) * 256 + gk];
      float4 sc0 = *(const float4*)&scsh[gk];
      float4 sc1 = *(const float4*)&scsh[gk + 4];
      float4 sh0 = *(const float4*)&scsh[256 + gk];
      float4 sh1 = *(const float4*)&scsh[256 + gk + 4];
      ushort8 o;
      o[0] = f2bf(fmaxf(bf2f(u[0]) * sc0.x + sh0.x, 0.f));
      o[1] = f2bf(fmaxf(bf2f(u[1]) * sc0.y + sh0.y, 0.f));
      o[2] = f2bf(fmaxf(bf2f(u[2]) * sc0.z + sh0.z, 0.f));
      o[3] = f2bf(fmaxf(bf2f(u[3]) * sc0.w + sh0.w, 0.f));
      o[4] = f2bf(fmaxf(bf2f(u[4]) * sc1.x + sh1.x, 0.f));
      o[5] = f2bf(fmaxf(bf2f(u[5]) * sc1.y + sh1.y, 0.f));
      o[6] = f2bf(fmaxf(bf2f(u[6]) * sc1.z + sh1.z, 0.f));
      o[7] = f2bf(fmaxf(bf2f(u[7]) * sc1.w + sh1.w, 0.f));
      *(ushort8*)((char*)As + r * 128 + ((c ^ (r & 7)) * 16)) = o;
    }
    __syncthreads();

#pragma unroll
    for (int kk = 0; kk < 2; ++kk) {
      short8 a[4], b[2];
#pragma unroll
      for (int m = 0; m < 4; ++m) {
        int row = wr * 64 + m * 16 + (lane & 15);
        int phys = (kk * 4 + (lane >> 4)) ^ (row & 7);
        a[m] = *(const short8*)((const char*)As + row * 128 + phys * 16);
      }
#pragma unroll
      for (int n = 0; n < 2; ++n) {
        int col = wc * 32 + n * 16 + (lane & 15);
        int phys = (kk * 4 + (lane >> 4)) ^ (col & 7);
        b[n] = *(const short8*)((const char*)Bs + col * 128 + phys * 16);
      }
#pragma unroll
      for (int m = 0; m < 4; ++m)
#pragma unroll
        for (int n = 0; n < 2; ++n)
          acc[m][n] = __builtin_amdgcn_mfma_f32_16x16x32_bf16(a[m], b[n], acc[m][n], 0, 0, 0);
    }
    __syncthreads();
  }

  const int colbase = wc * 32 + (lane & 15);
#pragma unroll
  for (int m = 0; m < 4; ++m) {
    int rowbase = m0 + wr * 64 + m * 16 + (lane >> 4) * 4;
#pragma unroll
    for (int j = 0; j < 4; ++j) {
      int row = rowbase + j;
      if (row < M) {
#pragma unroll
        for (int n = 0; n < 2; ++n)
          H2[(size_t)row * 64 + colbase + n * 16] = f2bf(acc[m][n][j]);
      }
    }
  }
}

// ---------------- CSR build: histogram -> 3-phase scan -> scatter ----------------
__global__ __launch_bounds__(256) void edge_hist(
    const int* __restrict__ rows, int* __restrict__ cnt, int E)
{
  int e = blockIdx.x * 256 + threadIdx.x;
  if (e < E) atomicAdd(&cnt[rows[e]], 1);
}

__global__ __launch_bounds__(256) void scan_blocksum(
    const int* __restrict__ cnt, int* __restrict__ bsum, int Nrows)
{
  int i = blockIdx.x * 256 + threadIdx.x;
  int v = (i < Nrows) ? cnt[i] : 0;
#pragma unroll
  for (int off = 1; off < 64; off <<= 1) v += __shfl_xor(v, off);
  __shared__ int wsum[4];
  if ((threadIdx.x & 63) == 0) wsum[threadIdx.x >> 6] = v;
  __syncthreads();
  if (threadIdx.x == 0)
    bsum[blockIdx.x] = wsum[0] + wsum[1] + wsum[2] + wsum[3];
}

__global__ __launch_bounds__(256) void scan_boff(
    const int* __restrict__ bsum, int* __restrict__ boff, int NB)
{
  __shared__ int lds[256];
  int t = threadIdx.x;
  int v = (t < NB) ? bsum[t] : 0;
  lds[t] = v;
  __syncthreads();
  for (int off = 1; off < 256; off <<= 1) {
    int u = (t >= off) ? lds[t - off] : 0;
    __syncthreads();
    lds[t] += u;
    __syncthreads();
  }
  boff[t] = (t == 0) ? 0 : lds[t - 1];
}

__global__ __launch_bounds__(256) void scan_write(
    const int* __restrict__ cnt, const int* __restrict__ boff,
    int* __restrict__ rowptr, int* __restrict__ cursor, int Nrows, int E)
{
  __shared__ int lds[256];
  int t = threadIdx.x;
  int i = blockIdx.x * 256 + t;
  int v = (i < Nrows) ? cnt[i] : 0;
  lds[t] = v;
  __syncthreads();
  for (int off = 1; off < 256; off <<= 1) {
    int u = (t >= off) ? lds[t - off] : 0;
    __syncthreads();
    lds[t] += u;
    __syncthreads();
  }
  int excl = boff[blockIdx.x] + lds[t] - v;
  if (i < Nrows) { rowptr[i] = excl; cursor[i] = excl; }
  if (i == Nrows) rowptr[i] = E;
}

__global__ __launch_bounds__(256) void edge_scatter(
    const int* __restrict__ rows, const int* __restrict__ cols,
    const float* __restrict__ vals, int* __restrict__ cursor,
    int* __restrict__ scols, float* __restrict__ svals, int E)
{
  int e = blockIdx.x * 256 + threadIdx.x;
  if (e < E) {
    int r = rows[e];
    int p = atomicAdd(&cursor[r], 1);
    scols[p] = cols[e];
    svals[p] = vals[e];
  }
}

// ---------------- SpMM gather (bf16 D, F=256) -> bf16 out ------------------------
__global__ __launch_bounds__(256) void spmm_gather_bf(
    const int* __restrict__ rowptr, const int* __restrict__ scols,
    const float* __restrict__ svals, const unsigned short* __restrict__ D,
    unsigned short* __restrict__ out, int Nrows)
{
  const int lane = threadIdx.x & 63;
  const int r = blockIdx.x * 4 + (threadIdx.x >> 6);
  if (r >= Nrows) return;
  const int s = rowptr[r], e = rowptr[r + 1];
  float4 acc = make_float4(0.f, 0.f, 0.f, 0.f);
  int j = s;
  for (; j + 1 < e; j += 2) {
    int c0 = scols[j], c1 = scols[j + 1];
    float v0 = svals[j], v1 = svals[j + 1];
    ushort4 d0 = *(const ushort4*)&D[(size_t)c0 * 256 + lane * 4];
    ushort4 d1 = *(const ushort4*)&D[(size_t)c1 * 256 + lane * 4];
    acc.x = fmaf(v0, bf2f(d0.x), acc.x); acc.y = fmaf(v0, bf2f(d0.y), acc.y);
    acc.z = fmaf(v0, bf2f(d0.z), acc.z); acc.w = fmaf(v0, bf2f(d0.w), acc.w);
    acc.x = fmaf(v1, bf2f(d1.x), acc.x); acc.y = fmaf(v1, bf2f(d1.y), acc.y);
    acc.z = fmaf(v1, bf2f(d1.z), acc.z); acc.w = fmaf(v1, bf2f(d1.w), acc.w);
  }
  if (j < e) {
    int c = scols[j]; float v = svals[j];
    ushort4 d = *(const ushort4*)&D[(size_t)c * 256 + lane * 4];
    acc.x = fmaf(v, bf2f(d.x), acc.x); acc.y = fmaf(v, bf2f(d.y), acc.y);
    acc.z = fmaf(v, bf2f(d.z), acc.z); acc.w = fmaf(v, bf2f(d.w), acc.w);
  }
  ushort4 ov;
  ov.x = f2bf(acc.x); ov.y = f2bf(acc.y); ov.z = f2bf(acc.z); ov.w = f2bf(acc.w);
  *(ushort4*)&out[(size_t)r * 256 + lane * 4] = ov;
}

// ---------------- SpMM gather (bf16 D, F=64) -> fp32 out -------------------------
__global__ __launch_bounds__(256) void spmm_gather_bf64(
    const int* __restrict__ rowptr, const int* __restrict__ scols,
    const float* __restrict__ svals, const unsigned short* __restrict__ D,
    float* __restrict__ out, int Nrows)
{
  const int lane = threadIdx.x & 63;
  const int r = blockIdx.x * 4 + (threadIdx.x >> 6);
  if (r >= Nrows) return;
  const int s = rowptr[r], e = rowptr[r + 1];
  float acc = 0.f;
  int j = s;
  for (; j + 1 < e; j += 2) {
    int c0 = scols[j], c1 = scols[j + 1];
    float v0 = svals[j], v1 = svals[j + 1];
    acc = fmaf(v0, bf2f(D[(size_t)c0 * 64 + lane]), acc);
    acc = fmaf(v1, bf2f(D[(size_t)c1 * 64 + lane]), acc);
  }
  if (j < e) acc = fmaf(svals[j], bf2f(D[(size_t)scols[j] * 64 + lane]), acc);
  out[(size_t)r * 64 + lane] = acc;
}

// ---------------- BN1 stats from bf16 H (C=256), per-block partials --------------
__global__ __launch_bounds__(256) void bn_stats_bf256(
    const unsigned short* __restrict__ H, float* __restrict__ partials, int Nrows)
{
  const int cc = threadIdx.x & 31;    // col chunk (8 cols)
  const int c = cc * 8;
  const int rr = threadIdx.x >> 5;    // 0..7
  float s[8] = {}, q[8] = {};
  for (int r = blockIdx.x * 8 + rr; r < Nrows; r += gridDim.x * 8) {
    ushort8 u = *(const ushort8*)&H[(size_t)r * 256 + c];
#pragma unroll
    for (int j = 0; j < 8; ++j) {
      float f = bf2f(u[j]);
      s[j] += f; q[j] += f * f;
    }
  }
  __shared__ float lds[256][16];
  float* L = lds[threadIdx.x];
#pragma unroll
  for (int j = 0; j < 8; ++j) { L[j] = s[j]; L[8 + j] = q[j]; }
  __syncthreads();
  if (rr == 0) {
#pragma unroll
    for (int r2 = 1; r2 < 8; ++r2) {
      float* Mm = lds[cc + r2 * 32];
#pragma unroll
      for (int j = 0; j < 8; ++j) { s[j] += Mm[j]; q[j] += Mm[8 + j]; }
    }
    float* P = &partials[(size_t)blockIdx.x * 512];
#pragma unroll
    for (int j = 0; j < 8; ++j) { P[c + j] = s[j]; P[256 + c + j] = q[j]; }
  }
}

// ---------------- BN stats fp32 (C=64), per-block partials -----------------------
__global__ __launch_bounds__(256) void bn_stats64(
    const float* __restrict__ H, float* __restrict__ partials, int Nrows)
{
  const int cc = threadIdx.x % 16;
  const int c = cc * 4;
  const int rr = threadIdx.x / 16;   // 0..15
  float4 s = make_float4(0.f, 0.f, 0.f, 0.f);
  float4 q = make_float4(0.f, 0.f, 0.f, 0.f);
  for (int r = blockIdx.x * 16 + rr; r < Nrows; r += gridDim.x * 16) {
    float4 v = *(const float4*)&H[(size_t)r * 64 + c];
    s.x += v.x; s.y += v.y; s.z += v.z; s.w += v.w;
    q.x += v.x * v.x; q.y += v.y * v.y; q.z += v.z * v.z; q.w += v.w * v.w;
  }
  __shared__ float lds[256][8];
  float* L = lds[threadIdx.x];
  L[0] = s.x; L[1] = s.y; L[2] = s.z; L[3] = s.w;
  L[4] = q.x; L[5] = q.y; L[6] = q.z; L[7] = q.w;
  __syncthreads();
  if (rr == 0) {
#pragma unroll
    for (int r2 = 1; r2 < 16; ++r2) {
      float* Mm = lds[cc + r2 * 16];
      s.x += Mm[0]; s.y += Mm[1]; s.z += Mm[2]; s.w += Mm[3];
      q.x += Mm[4]; q.y += Mm[5]; q.z += Mm[6]; q.w += Mm[7];
    }
    float* P = &partials[(size_t)blockIdx.x * 128];
    *(float4*)&P[c] = s;
    *(float4*)&P[64 + c] = q;
  }
}

// ---------------- BN finalize (parallel): one block per channel ------------------
template<int C>
__global__ __launch_bounds__(256) void bn_finalize_par(
    const float* __restrict__ partials,
    const float* __restrict__ gamma, const float* __restrict__ beta,
    float* __restrict__ scsh, int G, float invN)
{
  const int c = blockIdx.x;
  const int t = threadIdx.x;
  float sum = 0.f, sq = 0.f;
  for (int g = t; g < G; g += 256) {
    sum += partials[(size_t)g * 2 * C + c];
    sq  += partials[(size_t)g * 2 * C + C + c];
  }
#pragma unroll
  for (int off = 1; off < 64; off <<= 1) {
    sum += __shfl_xor(sum, off);
    sq  += __shfl_xor(sq, off);
  }
  __shared__ float ws[4][2];
  if ((t & 63) == 0) { ws[t >> 6][0] = sum; ws[t >> 6][1] = sq; }
  __syncthreads();
  if (t == 0) {
    sum = ws[0][0] + ws[1][0] + ws[2][0] + ws[3][0];
    sq  = ws[0][1] + ws[1][1] + ws[2][1] + ws[3][1];
    float mean = sum * invN;
    float var = sq * invN - mean * mean;
    float rstd = rsqrtf(var + 1e-5f);
    float sc = gamma[c] * rstd;
    scsh[c] = sc;
    scsh[C + c] = beta[c] - mean * sc;
  }
}

// ---------------- BN2 apply + log_softmax ----------------------------------------
__global__ __launch_bounds__(256) void bn_lsm(
    const float* __restrict__ H, const float* __restrict__ scsh,
    float* __restrict__ out, int Nrows)
{
  int lane = threadIdx.x & 63;
  int r = blockIdx.x * 4 + (threadIdx.x >> 6);
  if (r >= Nrows) return;
  float y = H[(size_t)r * 64 + lane] * scsh[lane] + scsh[64 + lane];
  float m = y;
#pragma unroll
  for (int off = 32; off >= 1; off >>= 1) m = fmaxf(m, __shfl_xor(m, off));
  float ex = expf(y - m);
  float s = ex;
#pragma unroll
  for (int off = 32; off >= 1; off >>= 1) s += __shfl_xor(s, off);
  out[(size_t)r * 64 + lane] = (y - m) - logf(s);
}

extern "C" void kernel_launch(void* const* d_in, const int* in_sizes, int n_in,
                              void* d_out, int out_size, void* d_ws, size_t ws_size,
                              hipStream_t stream) {
  const float* x      = (const float*)d_in[0];
  const int*   erow   = (const int*)  d_in[1];
  const int*   ecol   = (const int*)  d_in[2];
  const float* eval   = (const float*)d_in[3];
  const float* W1     = (const float*)d_in[4];
  // d_in[5] = b1 : cancels exactly in training-mode BN (shift-invariant)
  const float* gamma1 = (const float*)d_in[6];
  const float* beta1  = (const float*)d_in[7];
  const float* W2     = (const float*)d_in[8];
  // d_in[9] = b2 : cancels in BN2
  const float* gamma2 = (const float*)d_in[10];
  const float* beta2  = (const float*)d_in[11];

  const int N = in_sizes[0] / 512;   // 50000
  const int E = in_sizes[1];         // 800000

  char* ws = (char*)d_ws;
  unsigned short* H1b   = (unsigned short*)(ws + 0);
  float* partials1      = (float*)(ws + 0);
  unsigned short* H2b   = (unsigned short*)(ws + 0);
  float* H2AGG          = (float*)(ws + 12800000);
  unsigned short* H1AGGb= (unsigned short*)(ws + 51200000);
  float* partials2      = (float*)(ws + 51200000);
  unsigned short* w1t   = (unsigned short*)(ws + 76865536);   // 256 KB
  float* scsh1          = (float*)(ws + 77127680);            // 512 f
  float* scsh2          = (float*)(ws + 77129728);            // 128 f
  int*   rowptr         = (int*)(ws + 77130240);
  int*   cnt            = (int*)(ws + 77330244);
  int*   cursor         = (int*)(ws + 77530244);
  int*   scols          = (int*)(ws + 77730244);
  float* svals          = (float*)(ws + 80930244);
  int*   bsum           = (int*)(ws + 84130244);
  int*   boff           = (int*)(ws + 84131268);
  unsigned short* w2t   = (unsigned short*)(ws + 84132352);   // 32 KB

  hipMemsetAsync(cnt, 0, (size_t)N * 4, stream);

  const dim3 blk(256);
  const int eblocks = (E + 255) / 256;
  const int NB = (N + 255) / 256;   // 196 <= 256

  // CSR build
  edge_hist<<<eblocks, blk, 0, stream>>>(erow, cnt, E);
  scan_blocksum<<<NB, blk, 0, stream>>>(cnt, bsum, N);
  scan_boff<<<1, blk, 0, stream>>>(bsum, boff, NB);
  scan_write<<<NB + 1, blk, 0, stream>>>(cnt, boff, rowptr, cursor, N, E);
  edge_scatter<<<eblocks, blk, 0, stream>>>(erow, ecol, eval, cursor, scols, svals, E);

  // weight conversions (tiny)
  cvt_w1t<<<512, blk, 0, stream>>>(W1, w1t);
  cvt_w2t<<<64, blk, 0, stream>>>(W2, w2t);

  // layer 1: H1 = x @ W1 (fp32 in, cast fused, bf16 out) — 64-row tiles, 782 blocks
  gemm1_mfma<<<(N + 63) / 64, blk, 0, stream>>>(x, w1t, H1b, N);
  // H1AGG = A @ H1 (gather, bf16 out)
  spmm_gather_bf<<<(N + 3) / 4, blk, 0, stream>>>(rowptr, scols, svals, H1b, H1AGGb, N);
  // BN1
  bn_stats_bf256<<<256, blk, 0, stream>>>(H1AGGb, partials1, N);
  bn_finalize_par<256><<<256, blk, 0, stream>>>(partials1, gamma1, beta1, scsh1, 256, 1.0f / N);
  // layer 2: H2 = relu(bn1(H1AGG)) @ W2 (MFMA, BN fused in A-stage, bf16 out)
  gemm2_mfma<<<(N + 127) / 128, blk, 0, stream>>>(H1AGGb, w2t, scsh1, H2b, N);
  // H2AGG = A @ H2 (gather from bf16, fp32 out)
  spmm_gather_bf64<<<(N + 3) / 4, blk, 0, stream>>>(rowptr, scols, svals, H2b, H2AGG, N);
  // BN2
  bn_stats64<<<256, blk, 0, stream>>>(H2AGG, partials2, N);
  bn_finalize_par<64><<<64, blk, 0, stream>>>(partials2, gamma2, beta2, scsh2, 256, 1.0f / N);
  // BN2 apply + log_softmax
  bn_lsm<<<(N + 3) / 4, blk, 0, stream>>>(H2AGG, scsh2, (float*)d_out, N);
}

// Round 9
// 274.798 us; speedup vs baseline: 15.1345x; 1.1058x over previous
//
#include <hip/hip_runtime.h>

typedef __attribute__((ext_vector_type(8))) short short8;   // 8 bf16 (4 VGPRs)
typedef __attribute__((ext_vector_type(4))) float f32x4;
typedef __attribute__((ext_vector_type(8))) unsigned short ushort8;

__device__ __forceinline__ unsigned short f2bf(float f) {
  unsigned int u = __builtin_bit_cast(unsigned int, f);
  u += 0x7fffu + ((u >> 16) & 1u);   // RNE
  return (unsigned short)(u >> 16);
}
__device__ __forceinline__ float bf2f(unsigned short b) {
  return __builtin_bit_cast(float, ((unsigned int)b) << 16);
}
__device__ __forceinline__ void gload_lds16(const void* g, void* l) {
  __builtin_amdgcn_global_load_lds(
      (const __attribute__((address_space(1))) void*)g,
      (__attribute__((address_space(3))) void*)l, 16, 0, 0);
}

// ---------------- W1 [512][256] fp32 -> W1T [256][512] bf16 ----------------------
__global__ __launch_bounds__(256) void cvt_w1t(
    const float* __restrict__ W1, unsigned short* __restrict__ W1T)
{
  int idx = blockIdx.x * 256 + threadIdx.x;   // 131072 total
  int n = idx >> 9, k = idx & 511;
  W1T[idx] = f2bf(W1[(size_t)k * 256 + n]);
}

// ---------------- W2 [256][64] fp32 -> W2T [64][256] bf16 ------------------------
__global__ __launch_bounds__(256) void cvt_w2t(
    const float* __restrict__ W2, unsigned short* __restrict__ W2T)
{
  int idx = blockIdx.x * 256 + threadIdx.x;   // 16384 total
  int n = idx >> 8, k = idx & 255;
  W2T[idx] = f2bf(W2[(size_t)k * 64 + n]);
}

// ---------------- GEMM1: H1_bf16[M,256] = x_f32[M,512] @ W1 (cast fused) ---------
// 64x256 tile, BK=64, double-buffered LDS, 2-phase pipeline (T3-minimum):
// per K-step: issue next A loads + next B gload_lds -> compute cur -> write A nxt
// -> ONE barrier. 80 KB LDS (2 blocks/CU); staging hides under MFMA.
__global__ __launch_bounds__(256) void gemm1_mfma(
    const float* __restrict__ x,             // [M][512] fp32
    const unsigned short* __restrict__ w1t,  // [256][512] bf16
    unsigned short* __restrict__ H1,         // [M][256] bf16 out
    int M)
{
  __shared__ unsigned short As[2][64 * 64];   // 2 x 8 KB, [row][64k] swizzled
  __shared__ unsigned short Bs[2][256 * 64];  // 2 x 32 KB, [col][64k] swizzled
  const int tid = threadIdx.x;
  const int wid = tid >> 6, lane = tid & 63;
  const int wc = wid;                      // wave col-quadrant (0..3)
  const int m0 = blockIdx.x * 64;

  const int srow = tid >> 3;                       // 0..31 (B staging)
  const int ls = ((tid & 7) ^ (srow & 7)) * 8;     // pre-swizzled k-offset
  const unsigned short* gB = &w1t[(size_t)srow * 512 + ls];

  // A staging: 2 chunks/thread (rows ar0, ar0+32; 8-elem group ac)
  const int ar0 = tid >> 3;            // 0..31
  const int ar1 = ar0 + 32;            // 32..63
  const int ac  = tid & 7;
  const int arow0 = m0 + ar0;
  const int arow1 = m0 + ar1;

  float4 a0lo, a0hi, a1lo, a1hi;

  auto loadA = [&](int k0) {
    a0lo = make_float4(0.f, 0.f, 0.f, 0.f); a0hi = a0lo; a1lo = a0lo; a1hi = a0lo;
    if (arow0 < M) {
      a0lo = *(const float4*)&x[(size_t)arow0 * 512 + k0 + ac * 8];
      a0hi = *(const float4*)&x[(size_t)arow0 * 512 + k0 + ac * 8 + 4];
    }
    if (arow1 < M) {
      a1lo = *(const float4*)&x[(size_t)arow1 * 512 + k0 + ac * 8];
      a1hi = *(const float4*)&x[(size_t)arow1 * 512 + k0 + ac * 8 + 4];
    }
  };
  auto writeA = [&](int buf) {
    float v0[8] = {a0lo.x, a0lo.y, a0lo.z, a0lo.w, a0hi.x, a0hi.y, a0hi.z, a0hi.w};
    float v1[8] = {a1lo.x, a1lo.y, a1lo.z, a1lo.w, a1hi.x, a1hi.y, a1hi.z, a1hi.w};
    ushort8 o0, o1;
#pragma unroll
    for (int j = 0; j < 8; ++j) { o0[j] = f2bf(v0[j]); o1[j] = f2bf(v1[j]); }
    *(ushort8*)((char*)As[buf] + ar0 * 128 + ((ac ^ (ar0 & 7)) * 16)) = o0;
    *(ushort8*)((char*)As[buf] + ar1 * 128 + ((ac ^ (ar1 & 7)) * 16)) = o1;
  };
  auto stageB = [&](int k0, int buf) {
    char* lB = (char*)Bs[buf] + (size_t)wid * 1024;
#pragma unroll
    for (int i = 0; i < 8; ++i)
      gload_lds16(gB + (size_t)i * 32 * 512 + k0, lB + (size_t)i * 4096);
  };

  f32x4 acc[4][4] = {};

  // prologue: stage kt=0 into buf 0
  loadA(0);
  stageB(0, 0);
  writeA(0);
  __syncthreads();   // drains vmcnt(0)+lgkmcnt(0)

  for (int kt = 0; kt < 8; ++kt) {
    const int cur = kt & 1, nxt = cur ^ 1;
    if (kt < 7) {
      loadA((kt + 1) * 64);        // issue A global loads (regs)
      stageB((kt + 1) * 64, nxt);  // issue B direct-to-LDS (async)
    }
    // compute from buf cur
#pragma unroll
    for (int kk = 0; kk < 2; ++kk) {
      short8 a[4], b[4];
#pragma unroll
      for (int m = 0; m < 4; ++m) {
        int row = m * 16 + (lane & 15);
        int phys = (kk * 4 + (lane >> 4)) ^ (row & 7);
        a[m] = *(const short8*)((const char*)As[cur] + row * 128 + phys * 16);
      }
#pragma unroll
      for (int n = 0; n < 4; ++n) {
        int col = wc * 64 + n * 16 + (lane & 15);
        int phys = (kk * 4 + (lane >> 4)) ^ (col & 7);
        b[n] = *(const short8*)((const char*)Bs[cur] + col * 128 + phys * 16);
      }
#pragma unroll
      for (int m = 0; m < 4; ++m)
#pragma unroll
        for (int n = 0; n < 4; ++n)
          acc[m][n] = __builtin_amdgcn_mfma_f32_16x16x32_bf16(a[m], b[n], acc[m][n], 0, 0, 0);
    }
    if (kt < 7) writeA(nxt);   // compiler waits on A loads here (B stays in flight)
    __syncthreads();           // one barrier per K-step
  }

  const int colbase = wc * 64 + (lane & 15);
#pragma unroll
  for (int m = 0; m < 4; ++m) {
    int rowbase = m0 + m * 16 + (lane >> 4) * 4;
#pragma unroll
    for (int j = 0; j < 4; ++j) {
      int row = rowbase + j;
      if (row < M) {
#pragma unroll
        for (int n = 0; n < 4; ++n)
          H1[(size_t)row * 256 + colbase + n * 16] = f2bf(acc[m][n][j]);
      }
    }
  }
}

// ---------------- GEMM2: H2_bf16[M,64] = relu(bn1(H1AGG_bf16)) @ W2 (MFMA) -------
__global__ __launch_bounds__(256) void gemm2_mfma(
    const unsigned short* __restrict__ A,    // H1AGG bf16 [Mpad][256]
    const unsigned short* __restrict__ w2t,  // [64][256] bf16
    const float* __restrict__ scsh,          // [256] scale | [256] shift
    unsigned short* __restrict__ H2,         // [M][64] bf16 out
    int M)
{
  __shared__ unsigned short As[128 * 64];  // 16 KB
  __shared__ unsigned short Bs[64 * 64];   // 8 KB
  const int tid = threadIdx.x;
  const int wid = tid >> 6, lane = tid & 63;
  const int wr = wid >> 1, wc = wid & 1;
  const int m0 = blockIdx.x * 128;

  const int srow = tid >> 3;
  const int ls = ((tid & 7) ^ (srow & 7)) * 8;
  const unsigned short* gB = &w2t[(size_t)srow * 256 + ls];
  char* lB = (char*)Bs + (size_t)wid * 1024;

  f32x4 acc[4][2] = {};

  for (int kt = 0; kt < 4; ++kt) {
    const int k0 = kt * 64;
#pragma unroll
    for (int i = 0; i < 2; ++i)
      gload_lds16(gB + (size_t)i * 32 * 256 + k0, lB + (size_t)i * 4096);
#pragma unroll
    for (int i = 0; i < 4; ++i) {
      int chunk = tid + 256 * i;
      int r = chunk >> 3, c = chunk & 7;
      int gk = k0 + c * 8;
      ushort8 u = *(const ushort8*)&A[(size_t)(m0 + r) * 256 + gk];
      float4 sc0 = *(const float4*)&scsh[gk];
      float4 sc1 = *(const float4*)&scsh[gk + 4];
      float4 sh0 = *(const float4*)&scsh[256 + gk];
      float4 sh1 = *(const float4*)&scsh[256 + gk + 4];
      ushort8 o;
      o[0] = f2bf(fmaxf(bf2f(u[0]) * sc0.x + sh0.x, 0.f));
      o[1] = f2bf(fmaxf(bf2f(u[1]) * sc0.y + sh0.y, 0.f));
      o[2] = f2bf(fmaxf(bf2f(u[2]) * sc0.z + sh0.z, 0.f));
      o[3] = f2bf(fmaxf(bf2f(u[3]) * sc0.w + sh0.w, 0.f));
      o[4] = f2bf(fmaxf(bf2f(u[4]) * sc1.x + sh1.x, 0.f));
      o[5] = f2bf(fmaxf(bf2f(u[5]) * sc1.y + sh1.y, 0.f));
      o[6] = f2bf(fmaxf(bf2f(u[6]) * sc1.z + sh1.z, 0.f));
      o[7] = f2bf(fmaxf(bf2f(u[7]) * sc1.w + sh1.w, 0.f));
      *(ushort8*)((char*)As + r * 128 + ((c ^ (r & 7)) * 16)) = o;
    }
    __syncthreads();

#pragma unroll
    for (int kk = 0; kk < 2; ++kk) {
      short8 a[4], b[2];
#pragma unroll
      for (int m = 0; m < 4; ++m) {
        int row = wr * 64 + m * 16 + (lane & 15);
        int phys = (kk * 4 + (lane >> 4)) ^ (row & 7);
        a[m] = *(const short8*)((const char*)As + row * 128 + phys * 16);
      }
#pragma unroll
      for (int n = 0; n < 2; ++n) {
        int col = wc * 32 + n * 16 + (lane & 15);
        int phys = (kk * 4 + (lane >> 4)) ^ (col & 7);
        b[n] = *(const short8*)((const char*)Bs + col * 128 + phys * 16);
      }
#pragma unroll
      for (int m = 0; m < 4; ++m)
#pragma unroll
        for (int n = 0; n < 2; ++n)
          acc[m][n] = __builtin_amdgcn_mfma_f32_16x16x32_bf16(a[m], b[n], acc[m][n], 0, 0, 0);
    }
    __syncthreads();
  }

  const int colbase = wc * 32 + (lane & 15);
#pragma unroll
  for (int m = 0; m < 4; ++m) {
    int rowbase = m0 + wr * 64 + m * 16 + (lane >> 4) * 4;
#pragma unroll
    for (int j = 0; j < 4; ++j) {
      int row = rowbase + j;
      if (row < M) {
#pragma unroll
        for (int n = 0; n < 2; ++n)
          H2[(size_t)row * 64 + colbase + n * 16] = f2bf(acc[m][n][j]);
      }
    }
  }
}

// ---------------- CSR build: histogram -> 3-phase scan -> scatter ----------------
__global__ __launch_bounds__(256) void edge_hist(
    const int* __restrict__ rows, int* __restrict__ cnt, int E)
{
  int e = blockIdx.x * 256 + threadIdx.x;
  if (e < E) atomicAdd(&cnt[rows[e]], 1);
}

__global__ __launch_bounds__(256) void scan_blocksum(
    const int* __restrict__ cnt, int* __restrict__ bsum, int Nrows)
{
  int i = blockIdx.x * 256 + threadIdx.x;
  int v = (i < Nrows) ? cnt[i] : 0;
#pragma unroll
  for (int off = 1; off < 64; off <<= 1) v += __shfl_xor(v, off);
  __shared__ int wsum[4];
  if ((threadIdx.x & 63) == 0) wsum[threadIdx.x >> 6] = v;
  __syncthreads();
  if (threadIdx.x == 0)
    bsum[blockIdx.x] = wsum[0] + wsum[1] + wsum[2] + wsum[3];
}

__global__ __launch_bounds__(256) void scan_boff(
    const int* __restrict__ bsum, int* __restrict__ boff, int NB)
{
  __shared__ int lds[256];
  int t = threadIdx.x;
  int v = (t < NB) ? bsum[t] : 0;
  lds[t] = v;
  __syncthreads();
  for (int off = 1; off < 256; off <<= 1) {
    int u = (t >= off) ? lds[t - off] : 0;
    __syncthreads();
    lds[t] += u;
    __syncthreads();
  }
  boff[t] = (t == 0) ? 0 : lds[t - 1];
}

__global__ __launch_bounds__(256) void scan_write(
    const int* __restrict__ cnt, const int* __restrict__ boff,
    int* __restrict__ rowptr, int* __restrict__ cursor, int Nrows, int E)
{
  __shared__ int lds[256];
  int t = threadIdx.x;
  int i = blockIdx.x * 256 + t;
  int v = (i < Nrows) ? cnt[i] : 0;
  lds[t] = v;
  __syncthreads();
  for (int off = 1; off < 256; off <<= 1) {
    int u = (t >= off) ? lds[t - off] : 0;
    __syncthreads();
    lds[t] += u;
    __syncthreads();
  }
  int excl = boff[blockIdx.x] + lds[t] - v;
  if (i < Nrows) { rowptr[i] = excl; cursor[i] = excl; }
  if (i == Nrows) rowptr[i] = E;
}

// packed (col, val_bits) -> one 8B scattered write per edge (halves line count)
__global__ __launch_bounds__(256) void edge_scatter(
    const int* __restrict__ rows, const int* __restrict__ cols,
    const float* __restrict__ vals, int* __restrict__ cursor,
    int2* __restrict__ spack, int E)
{
  int e = blockIdx.x * 256 + threadIdx.x;
  if (e < E) {
    int r = rows[e];
    int p = atomicAdd(&cursor[r], 1);
    spack[p] = make_int2(cols[e], __float_as_int(vals[e]));
  }
}

// ---------------- SpMM gather (bf16 D, F=256) -> bf16 out, 4-unrolled ------------
__global__ __launch_bounds__(256) void spmm_gather_bf(
    const int* __restrict__ rowptr, const int2* __restrict__ sp,
    const unsigned short* __restrict__ D,
    unsigned short* __restrict__ out, int Nrows)
{
  const int lane = threadIdx.x & 63;
  const int r = blockIdx.x * 4 + (threadIdx.x >> 6);
  if (r >= Nrows) return;
  const int s = rowptr[r], e = rowptr[r + 1];
  float4 acc0 = make_float4(0.f, 0.f, 0.f, 0.f);
  float4 acc1 = make_float4(0.f, 0.f, 0.f, 0.f);
  int j = s;
  for (; j + 3 < e; j += 4) {
    int2 p0 = sp[j], p1 = sp[j + 1], p2 = sp[j + 2], p3 = sp[j + 3];
    ushort4 d0 = *(const ushort4*)&D[(size_t)p0.x * 256 + lane * 4];
    ushort4 d1 = *(const ushort4*)&D[(size_t)p1.x * 256 + lane * 4];
    ushort4 d2 = *(const ushort4*)&D[(size_t)p2.x * 256 + lane * 4];
    ushort4 d3 = *(const ushort4*)&D[(size_t)p3.x * 256 + lane * 4];
    float v0 = __int_as_float(p0.y), v1 = __int_as_float(p1.y);
    float v2 = __int_as_float(p2.y), v3 = __int_as_float(p3.y);
    acc0.x = fmaf(v0, bf2f(d0.x), acc0.x); acc0.y = fmaf(v0, bf2f(d0.y), acc0.y);
    acc0.z = fmaf(v0, bf2f(d0.z), acc0.z); acc0.w = fmaf(v0, bf2f(d0.w), acc0.w);
    acc1.x = fmaf(v1, bf2f(d1.x), acc1.x); acc1.y = fmaf(v1, bf2f(d1.y), acc1.y);
    acc1.z = fmaf(v1, bf2f(d1.z), acc1.z); acc1.w = fmaf(v1, bf2f(d1.w), acc1.w);
    acc0.x = fmaf(v2, bf2f(d2.x), acc0.x); acc0.y = fmaf(v2, bf2f(d2.y), acc0.y);
    acc0.z = fmaf(v2, bf2f(d2.z), acc0.z); acc0.w = fmaf(v2, bf2f(d2.w), acc0.w);
    acc1.x = fmaf(v3, bf2f(d3.x), acc1.x); acc1.y = fmaf(v3, bf2f(d3.y), acc1.y);
    acc1.z = fmaf(v3, bf2f(d3.z), acc1.z); acc1.w = fmaf(v3, bf2f(d3.w), acc1.w);
  }
  for (; j < e; ++j) {
    int2 p = sp[j];
    float v = __int_as_float(p.y);
    ushort4 d = *(const ushort4*)&D[(size_t)p.x * 256 + lane * 4];
    acc0.x = fmaf(v, bf2f(d.x), acc0.x); acc0.y = fmaf(v, bf2f(d.y), acc0.y);
    acc0.z = fmaf(v, bf2f(d.z), acc0.z); acc0.w = fmaf(v, bf2f(d.w), acc0.w);
  }
  ushort4 ov;
  ov.x = f2bf(acc0.x + acc1.x); ov.y = f2bf(acc0.y + acc1.y);
  ov.z = f2bf(acc0.z + acc1.z); ov.w = f2bf(acc0.w + acc1.w);
  *(ushort4*)&out[(size_t)r * 256 + lane * 4] = ov;
}

// ---------------- SpMM gather (bf16 D, F=64) -> fp32 out, 4-unrolled -------------
__global__ __launch_bounds__(256) void spmm_gather_bf64(
    const int* __restrict__ rowptr, const int2* __restrict__ sp,
    const unsigned short* __restrict__ D,
    float* __restrict__ out, int Nrows)
{
  const int lane = threadIdx.x & 63;
  const int r = blockIdx.x * 4 + (threadIdx.x >> 6);
  if (r >= Nrows) return;
  const int s = rowptr[r], e = rowptr[r + 1];
  float acc0 = 0.f, acc1 = 0.f;
  int j = s;
  for (; j + 3 < e; j += 4) {
    int2 p0 = sp[j], p1 = sp[j + 1], p2 = sp[j + 2], p3 = sp[j + 3];
    float d0 = bf2f(D[(size_t)p0.x * 64 + lane]);
    float d1 = bf2f(D[(size_t)p1.x * 64 + lane]);
    float d2 = bf2f(D[(size_t)p2.x * 64 + lane]);
    float d3 = bf2f(D[(size_t)p3.x * 64 + lane]);
    acc0 = fmaf(__int_as_float(p0.y), d0, acc0);
    acc1 = fmaf(__int_as_float(p1.y), d1, acc1);
    acc0 = fmaf(__int_as_float(p2.y), d2, acc0);
    acc1 = fmaf(__int_as_float(p3.y), d3, acc1);
  }
  for (; j < e; ++j) {
    int2 p = sp[j];
    acc0 = fmaf(__int_as_float(p.y), bf2f(D[(size_t)p.x * 64 + lane]), acc0);
  }
  out[(size_t)r * 64 + lane] = acc0 + acc1;
}

// ---------------- BN1 stats from bf16 H (C=256), per-block partials --------------
__global__ __launch_bounds__(256) void bn_stats_bf256(
    const unsigned short* __restrict__ H, float* __restrict__ partials, int Nrows)
{
  const int cc = threadIdx.x & 31;    // col chunk (8 cols)
  const int c = cc * 8;
  const int rr = threadIdx.x >> 5;    // 0..7
  float s[8] = {}, q[8] = {};
  for (int r = blockIdx.x * 8 + rr; r < Nrows; r += gridDim.x * 8) {
    ushort8 u = *(const ushort8*)&H[(size_t)r * 256 + c];
#pragma unroll
    for (int j = 0; j < 8; ++j) {
      float f = bf2f(u[j]);
      s[j] += f; q[j] += f * f;
    }
  }
  __shared__ float lds[256][16];
  float* L = lds[threadIdx.x];
#pragma unroll
  for (int j = 0; j < 8; ++j) { L[j] = s[j]; L[8 + j] = q[j]; }
  __syncthreads();
  if (rr == 0) {
#pragma unroll
    for (int r2 = 1; r2 < 8; ++r2) {
      float* Mm = lds[cc + r2 * 32];
#pragma unroll
      for (int j = 0; j < 8; ++j) { s[j] += Mm[j]; q[j] += Mm[8 + j]; }
    }
    float* P = &partials[(size_t)blockIdx.x * 512];
#pragma unroll
    for (int j = 0; j < 8; ++j) { P[c + j] = s[j]; P[256 + c + j] = q[j]; }
  }
}

// ---------------- BN stats fp32 (C=64), per-block partials -----------------------
__global__ __launch_bounds__(256) void bn_stats64(
    const float* __restrict__ H, float* __restrict__ partials, int Nrows)
{
  const int cc = threadIdx.x % 16;
  const int c = cc * 4;
  const int rr = threadIdx.x / 16;   // 0..15
  float4 s = make_float4(0.f, 0.f, 0.f, 0.f);
  float4 q = make_float4(0.f, 0.f, 0.f, 0.f);
  for (int r = blockIdx.x * 16 + rr; r < Nrows; r += gridDim.x * 16) {
    float4 v = *(const float4*)&H[(size_t)r * 64 + c];
    s.x += v.x; s.y += v.y; s.z += v.z; s.w += v.w;
    q.x += v.x * v.x; q.y += v.y * v.y; q.z += v.z * v.z; q.w += v.w * v.w;
  }
  __shared__ float lds[256][8];
  float* L = lds[threadIdx.x];
  L[0] = s.x; L[1] = s.y; L[2] = s.z; L[3] = s.w;
  L[4] = q.x; L[5] = q.y; L[6] = q.z; L[7] = q.w;
  __syncthreads();
  if (rr == 0) {
#pragma unroll
    for (int r2 = 1; r2 < 16; ++r2) {
      float* Mm = lds[cc + r2 * 16];
      s.x += Mm[0]; s.y += Mm[1]; s.z += Mm[2]; s.w += Mm[3];
      q.x += Mm[4]; q.y += Mm[5]; q.z += Mm[6]; q.w += Mm[7];
    }
    float* P = &partials[(size_t)blockIdx.x * 128];
    *(float4*)&P[c] = s;
    *(float4*)&P[64 + c] = q;
  }
}

// ---------------- BN finalize (parallel): one block per channel ------------------
template<int C>
__global__ __launch_bounds__(256) void bn_finalize_par(
    const float* __restrict__ partials,
    const float* __restrict__ gamma, const float* __restrict__ beta,
    float* __restrict__ scsh, int G, float invN)
{
  const int c = blockIdx.x;
  const int t = threadIdx.x;
  float sum = 0.f, sq = 0.f;
  for (int g = t; g < G; g += 256) {
    sum += partials[(size_t)g * 2 * C + c];
    sq  += partials[(size_t)g * 2 * C + C + c];
  }
#pragma unroll
  for (int off = 1; off < 64; off <<= 1) {
    sum += __shfl_xor(sum, off);
    sq  += __shfl_xor(sq, off);
  }
  __shared__ float ws[4][2];
  if ((t & 63) == 0) { ws[t >> 6][0] = sum; ws[t >> 6][1] = sq; }
  __syncthreads();
  if (t == 0) {
    sum = ws[0][0] + ws[1][0] + ws[2][0] + ws[3][0];
    sq  = ws[0][1] + ws[1][1] + ws[2][1] + ws[3][1];
    float mean = sum * invN;
    float var = sq * invN - mean * mean;
    float rstd = rsqrtf(var + 1e-5f);
    float sc = gamma[c] * rstd;
    scsh[c] = sc;
    scsh[C + c] = beta[c] - mean * sc;
  }
}

// ---------------- BN2 apply + log_softmax ----------------------------------------
__global__ __launch_bounds__(256) void bn_lsm(
    const float* __restrict__ H, const float* __restrict__ scsh,
    float* __restrict__ out, int Nrows)
{
  int lane = threadIdx.x & 63;
  int r = blockIdx.x * 4 + (threadIdx.x >> 6);
  if (r >= Nrows) return;
  float y = H[(size_t)r * 64 + lane] * scsh[lane] + scsh[64 + lane];
  float m = y;
#pragma unroll
  for (int off = 32; off >= 1; off >>= 1) m = fmaxf(m, __shfl_xor(m, off));
  float ex = expf(y - m);
  float s = ex;
#pragma unroll
  for (int off = 32; off >= 1; off >>= 1) s += __shfl_xor(s, off);
  out[(size_t)r * 64 + lane] = (y - m) - logf(s);
}

extern "C" void kernel_launch(void* const* d_in, const int* in_sizes, int n_in,
                              void* d_out, int out_size, void* d_ws, size_t ws_size,
                              hipStream_t stream) {
  const float* x      = (const float*)d_in[0];
  const int*   erow   = (const int*)  d_in[1];
  const int*   ecol   = (const int*)  d_in[2];
  const float* eval   = (const float*)d_in[3];
  const float* W1     = (const float*)d_in[4];
  // d_in[5] = b1 : cancels exactly in training-mode BN (shift-invariant)
  const float* gamma1 = (const float*)d_in[6];
  const float* beta1  = (const float*)d_in[7];
  const float* W2     = (const float*)d_in[8];
  // d_in[9] = b2 : cancels in BN2
  const float* gamma2 = (const float*)d_in[10];
  const float* beta2  = (const float*)d_in[11];

  const int N = in_sizes[0] / 512;   // 50000
  const int E = in_sizes[1];         // 800000

  char* ws = (char*)d_ws;
  unsigned short* H1b   = (unsigned short*)(ws + 0);
  float* partials1      = (float*)(ws + 0);
  unsigned short* H2b   = (unsigned short*)(ws + 0);
  float* H2AGG          = (float*)(ws + 12800000);
  unsigned short* H1AGGb= (unsigned short*)(ws + 51200000);
  float* partials2      = (float*)(ws + 51200000);
  unsigned short* w1t   = (unsigned short*)(ws + 76865536);   // 256 KB
  float* scsh1          = (float*)(ws + 77127680);            // 512 f
  float* scsh2          = (float*)(ws + 77129728);            // 128 f
  int*   rowptr         = (int*)(ws + 77130240);
  int*   cnt            = (int*)(ws + 77330244);
  int*   cursor         = (int*)(ws + 77530244);
  int2*  spack          = (int2*)(ws + 77730248);             // E * 8 B (8-aligned)
  int*   bsum           = (int*)(ws + 84130248);
  int*   boff           = (int*)(ws + 84131272);
  unsigned short* w2t   = (unsigned short*)(ws + 84132352);   // 32 KB

  hipMemsetAsync(cnt, 0, (size_t)N * 4, stream);

  const dim3 blk(256);
  const int eblocks = (E + 255) / 256;
  const int NB = (N + 255) / 256;   // 196 <= 256

  // CSR build
  edge_hist<<<eblocks, blk, 0, stream>>>(erow, cnt, E);
  scan_blocksum<<<NB, blk, 0, stream>>>(cnt, bsum, N);
  scan_boff<<<1, blk, 0, stream>>>(bsum, boff, NB);
  scan_write<<<NB + 1, blk, 0, stream>>>(cnt, boff, rowptr, cursor, N, E);
  edge_scatter<<<eblocks, blk, 0, stream>>>(erow, ecol, eval, cursor, spack, E);

  // weight conversions (tiny)
  cvt_w1t<<<512, blk, 0, stream>>>(W1, w1t);
  cvt_w2t<<<64, blk, 0, stream>>>(W2, w2t);

  // layer 1: H1 = x @ W1 (fp32 in, cast fused, bf16 out) — double-buffered pipeline
  gemm1_mfma<<<(N + 63) / 64, blk, 0, stream>>>(x, w1t, H1b, N);
  // H1AGG = A @ H1 (gather, bf16 out)
  spmm_gather_bf<<<(N + 3) / 4, blk, 0, stream>>>(rowptr, spack, H1b, H1AGGb, N);
  // BN1
  bn_stats_bf256<<<256, blk, 0, stream>>>(H1AGGb, partials1, N);
  bn_finalize_par<256><<<256, blk, 0, stream>>>(partials1, gamma1, beta1, scsh1, 256, 1.0f / N);
  // layer 2: H2 = relu(bn1(H1AGG)) @ W2 (MFMA, BN fused in A-stage, bf16 out)
  gemm2_mfma<<<(N + 127) / 128, blk, 0, stream>>>(H1AGGb, w2t, scsh1, H2b, N);
  // H2AGG = A @ H2 (gather from bf16, fp32 out)
  spmm_gather_bf64<<<(N + 3) / 4, blk, 0, stream>>>(rowptr, spack, H2b, H2AGG, N);
  // BN2
  bn_stats64<<<256, blk, 0, stream>>>(H2AGG, partials2, N);
  bn_finalize_par<64><<<64, blk, 0, stream>>>(partials2, gamma2, beta2, scsh2, 256, 1.0f / N);
  // BN2 apply + log_softmax
  bn_lsm<<<(N + 3) / 4, blk, 0, stream>>>(H2AGG, scsh2, (float*)d_out, N);
}

// Round 10
// 273.846 us; speedup vs baseline: 15.1872x; 1.0035x over previous
//
#include <hip/hip_runtime.h>

typedef __attribute__((ext_vector_type(8))) short short8;   // 8 bf16 (4 VGPRs)
typedef __attribute__((ext_vector_type(4))) float f32x4;
typedef __attribute__((ext_vector_type(8))) unsigned short ushort8;

__device__ __forceinline__ unsigned short f2bf(float f) {
  unsigned int u = __builtin_bit_cast(unsigned int, f);
  u += 0x7fffu + ((u >> 16) & 1u);   // RNE
  return (unsigned short)(u >> 16);
}
__device__ __forceinline__ float bf2f(unsigned short b) {
  return __builtin_bit_cast(float, ((unsigned int)b) << 16);
}
__device__ __forceinline__ void gload_lds16(const void* g, void* l) {
  __builtin_amdgcn_global_load_lds(
      (const __attribute__((address_space(1))) void*)g,
      (__attribute__((address_space(3))) void*)l, 16, 0, 0);
}

// ---------------- W1/W2 -> transposed bf16 (one kernel) --------------------------
__global__ __launch_bounds__(256) void cvt_weights(
    const float* __restrict__ W1, const float* __restrict__ W2,
    unsigned short* __restrict__ w1t, unsigned short* __restrict__ w2t)
{
  int idx = blockIdx.x * 256 + threadIdx.x;
  if (idx < 131072) {                    // W1 [512][256] -> w1t [256][512]
    int n = idx >> 9, k = idx & 511;
    w1t[idx] = f2bf(W1[(size_t)k * 256 + n]);
  } else if (idx < 131072 + 16384) {     // W2 [256][64] -> w2t [64][256]
    int i = idx - 131072;
    int n = i >> 8, k = i & 255;
    w2t[i] = f2bf(W2[(size_t)k * 64 + n]);
  }
}

// ---------------- GEMM1: H1_bf16[M,256] = x_f32[M,512] @ W1 (cast fused) ---------
// 64x256 tile, BK=32, double-buffered (40 KB LDS -> 4 blocks/CU), one barrier/step.
// Swizzle: 4 slots/row, phys = slot ^ ((row>>1)&3)  (2-way max = free).
__global__ __launch_bounds__(256) void gemm1_mfma(
    const float* __restrict__ x,             // [M][512] fp32
    const unsigned short* __restrict__ w1t,  // [256][512] bf16
    unsigned short* __restrict__ H1,         // [M][256] bf16 out
    int M)
{
  __shared__ unsigned short As[2][64 * 32];   // 2 x 4 KB
  __shared__ unsigned short Bs[2][256 * 32];  // 2 x 16 KB
  const int tid = threadIdx.x;
  const int wid = tid >> 6, lane = tid & 63;
  const int wc = wid;                      // wave col-quadrant (0..3)
  const int m0 = blockIdx.x * 64;

  // A staging: thread -> row ar (0..63), slot ac (0..3)
  const int ar = tid >> 2;
  const int ac = tid & 3;
  const int arow = m0 + ar;
  const int aphys = ac ^ ((ar >> 1) & 3);

  // B staging: wave stages 4 groups of 16 cols; per-lane pre-swizzled source
  const int bq = lane >> 2;                          // col within group
  const int bslotx = (lane & 3) ^ ((lane >> 3) & 3); // source k-slot

  float4 alo, ahi;
  auto loadA = [&](int k0) {
    alo = make_float4(0.f, 0.f, 0.f, 0.f); ahi = alo;
    if (arow < M) {
      alo = *(const float4*)&x[(size_t)arow * 512 + k0 + ac * 8];
      ahi = *(const float4*)&x[(size_t)arow * 512 + k0 + ac * 8 + 4];
    }
  };
  auto writeA = [&](int buf) {
    ushort8 o;
    o[0] = f2bf(alo.x); o[1] = f2bf(alo.y); o[2] = f2bf(alo.z); o[3] = f2bf(alo.w);
    o[4] = f2bf(ahi.x); o[5] = f2bf(ahi.y); o[6] = f2bf(ahi.z); o[7] = f2bf(ahi.w);
    *(ushort8*)((char*)As[buf] + ar * 64 + aphys * 16) = o;
  };
  auto stageB = [&](int k0, int buf) {
#pragma unroll
    for (int i = 0; i < 4; ++i) {
      int g = wid + 4 * i;                 // group 0..15 (16 cols each)
      int col = g * 16 + bq;
      gload_lds16(&w1t[(size_t)col * 512 + k0 + bslotx * 8],
                  (char*)Bs[buf] + g * 1024);
    }
  };

  f32x4 acc[4][4] = {};

  // prologue: stage kt=0 into buf 0
  loadA(0);
  stageB(0, 0);
  writeA(0);
  __syncthreads();

  for (int kt = 0; kt < 16; ++kt) {
    const int cur = kt & 1, nxt = cur ^ 1;
    if (kt < 15) {
      loadA((kt + 1) * 32);        // A global loads -> regs (async)
      stageB((kt + 1) * 32, nxt);  // B direct-to-LDS (async)
    }
    short8 a[4], b[4];
#pragma unroll
    for (int m = 0; m < 4; ++m) {
      int row = m * 16 + (lane & 15);
      int phys = (lane >> 4) ^ ((row >> 1) & 3);
      a[m] = *(const short8*)((const char*)As[cur] + row * 64 + phys * 16);
    }
#pragma unroll
    for (int n = 0; n < 4; ++n) {
      int col = wc * 64 + n * 16 + (lane & 15);
      int phys = (lane >> 4) ^ ((col >> 1) & 3);
      b[n] = *(const short8*)((const char*)Bs[cur] + col * 64 + phys * 16);
    }
#pragma unroll
    for (int m = 0; m < 4; ++m)
#pragma unroll
      for (int n = 0; n < 4; ++n)
        acc[m][n] = __builtin_amdgcn_mfma_f32_16x16x32_bf16(a[m], b[n], acc[m][n], 0, 0, 0);
    if (kt < 15) writeA(nxt);      // waits A loads; B stays in flight
    __syncthreads();               // one barrier per K-step
  }

  const int colbase = wc * 64 + (lane & 15);
#pragma unroll
  for (int m = 0; m < 4; ++m) {
    int rowbase = m0 + m * 16 + (lane >> 4) * 4;
#pragma unroll
    for (int j = 0; j < 4; ++j) {
      int row = rowbase + j;
      if (row < M) {
#pragma unroll
        for (int n = 0; n < 4; ++n)
          H1[(size_t)row * 256 + colbase + n * 16] = f2bf(acc[m][n][j]);
      }
    }
  }
}

// ---------------- GEMM2: H2_bf16[M,64] = relu(bn1(H1AGG_bf16)) @ W2 (MFMA) -------
__global__ __launch_bounds__(256) void gemm2_mfma(
    const unsigned short* __restrict__ A,    // H1AGG bf16 [Mpad][256]
    const unsigned short* __restrict__ w2t,  // [64][256] bf16
    const float* __restrict__ scsh,          // [256] scale | [256] shift
    unsigned short* __restrict__ H2,         // [M][64] bf16 out
    int M)
{
  __shared__ unsigned short As[128 * 64];  // 16 KB
  __shared__ unsigned short Bs[64 * 64];   // 8 KB
  const int tid = threadIdx.x;
  const int wid = tid >> 6, lane = tid & 63;
  const int wr = wid >> 1, wc = wid & 1;
  const int m0 = blockIdx.x * 128;

  const int srow = tid >> 3;
  const int ls = ((tid & 7) ^ (srow & 7)) * 8;
  const unsigned short* gB = &w2t[(size_t)srow * 256 + ls];
  char* lB = (char*)Bs + (size_t)wid * 1024;

  f32x4 acc[4][2] = {};

  for (int kt = 0; kt < 4; ++kt) {
    const int k0 = kt * 64;
#pragma unroll
    for (int i = 0; i < 2; ++i)
      gload_lds16(gB + (size_t)i * 32 * 256 + k0, lB + (size_t)i * 4096);
#pragma unroll
    for (int i = 0; i < 4; ++i) {
      int chunk = tid + 256 * i;
      int r = chunk >> 3, c = chunk & 7;
      int gk = k0 + c * 8;
      ushort8 u = *(const ushort8*)&A[(size_t)(m0 + r) * 256 + gk];
      float4 sc0 = *(const float4*)&scsh[gk];
      float4 sc1 = *(const float4*)&scsh[gk + 4];
      float4 sh0 = *(const float4*)&scsh[256 + gk];
      float4 sh1 = *(const float4*)&scsh[256 + gk + 4];
      ushort8 o;
      o[0] = f2bf(fmaxf(bf2f(u[0]) * sc0.x + sh0.x, 0.f));
      o[1] = f2bf(fmaxf(bf2f(u[1]) * sc0.y + sh0.y, 0.f));
      o[2] = f2bf(fmaxf(bf2f(u[2]) * sc0.z + sh0.z, 0.f));
      o[3] = f2bf(fmaxf(bf2f(u[3]) * sc0.w + sh0.w, 0.f));
      o[4] = f2bf(fmaxf(bf2f(u[4]) * sc1.x + sh1.x, 0.f));
      o[5] = f2bf(fmaxf(bf2f(u[5]) * sc1.y + sh1.y, 0.f));
      o[6] = f2bf(fmaxf(bf2f(u[6]) * sc1.z + sh1.z, 0.f));
      o[7] = f2bf(fmaxf(bf2f(u[7]) * sc1.w + sh1.w, 0.f));
      *(ushort8*)((char*)As + r * 128 + ((c ^ (r & 7)) * 16)) = o;
    }
    __syncthreads();

#pragma unroll
    for (int kk = 0; kk < 2; ++kk) {
      short8 a[4], b[2];
#pragma unroll
      for (int m = 0; m < 4; ++m) {
        int row = wr * 64 + m * 16 + (lane & 15);
        int phys = (kk * 4 + (lane >> 4)) ^ (row & 7);
        a[m] = *(const short8*)((const char*)As + row * 128 + phys * 16);
      }
#pragma unroll
      for (int n = 0; n < 2; ++n) {
        int col = wc * 32 + n * 16 + (lane & 15);
        int phys = (kk * 4 + (lane >> 4)) ^ (col & 7);
        b[n] = *(const short8*)((const char*)Bs + col * 128 + phys * 16);
      }
#pragma unroll
      for (int m = 0; m < 4; ++m)
#pragma unroll
        for (int n = 0; n < 2; ++n)
          acc[m][n] = __builtin_amdgcn_mfma_f32_16x16x32_bf16(a[m], b[n], acc[m][n], 0, 0, 0);
    }
    __syncthreads();
  }

  const int colbase = wc * 32 + (lane & 15);
#pragma unroll
  for (int m = 0; m < 4; ++m) {
    int rowbase = m0 + wr * 64 + m * 16 + (lane >> 4) * 4;
#pragma unroll
    for (int j = 0; j < 4; ++j) {
      int row = rowbase + j;
      if (row < M) {
#pragma unroll
        for (int n = 0; n < 2; ++n)
          H2[(size_t)row * 64 + colbase + n * 16] = f2bf(acc[m][n][j]);
      }
    }
  }
}

// ---------------- CSR build: histogram -> 3-phase scan -> scatter ----------------
__global__ __launch_bounds__(256) void edge_hist(
    const int* __restrict__ rows, int* __restrict__ cnt, int E)
{
  int e = blockIdx.x * 256 + threadIdx.x;
  if (e < E) atomicAdd(&cnt[rows[e]], 1);
}

__global__ __launch_bounds__(256) void scan_blocksum(
    const int* __restrict__ cnt, int* __restrict__ bsum, int Nrows)
{
  int i = blockIdx.x * 256 + threadIdx.x;
  int v = (i < Nrows) ? cnt[i] : 0;
#pragma unroll
  for (int off = 1; off < 64; off <<= 1) v += __shfl_xor(v, off);
  __shared__ int wsum[4];
  if ((threadIdx.x & 63) == 0) wsum[threadIdx.x >> 6] = v;
  __syncthreads();
  if (threadIdx.x == 0)
    bsum[blockIdx.x] = wsum[0] + wsum[1] + wsum[2] + wsum[3];
}

__global__ __launch_bounds__(256) void scan_boff(
    const int* __restrict__ bsum, int* __restrict__ boff, int NB)
{
  __shared__ int lds[256];
  int t = threadIdx.x;
  int v = (t < NB) ? bsum[t] : 0;
  lds[t] = v;
  __syncthreads();
  for (int off = 1; off < 256; off <<= 1) {
    int u = (t >= off) ? lds[t - off] : 0;
    __syncthreads();
    lds[t] += u;
    __syncthreads();
  }
  boff[t] = (t == 0) ? 0 : lds[t - 1];
}

__global__ __launch_bounds__(256) void scan_write(
    const int* __restrict__ cnt, const int* __restrict__ boff,
    int* __restrict__ rowptr, int* __restrict__ cursor, int Nrows, int E)
{
  __shared__ int lds[256];
  int t = threadIdx.x;
  int i = blockIdx.x * 256 + t;
  int v = (i < Nrows) ? cnt[i] : 0;
  lds[t] = v;
  __syncthreads();
  for (int off = 1; off < 256; off <<= 1) {
    int u = (t >= off) ? lds[t - off] : 0;
    __syncthreads();
    lds[t] += u;
    __syncthreads();
  }
  int excl = boff[blockIdx.x] + lds[t] - v;
  if (i < Nrows) { rowptr[i] = excl; cursor[i] = excl; }
  if (i == Nrows) rowptr[i] = E;
}

__global__ __launch_bounds__(256) void edge_scatter(
    const int* __restrict__ rows, const int* __restrict__ cols,
    const float* __restrict__ vals, int* __restrict__ cursor,
    int2* __restrict__ spack, int E)
{
  int e = blockIdx.x * 256 + threadIdx.x;
  if (e < E) {
    int r = rows[e];
    int p = atomicAdd(&cursor[r], 1);
    spack[p] = make_int2(cols[e], __float_as_int(vals[e]));
  }
}

// ---------------- SpMM gather (bf16 D, F=256) -> bf16 out, 8-deep ILP ------------
__global__ __launch_bounds__(256) void spmm_gather_bf(
    const int* __restrict__ rowptr, const int2* __restrict__ sp,
    const unsigned short* __restrict__ D,
    unsigned short* __restrict__ out, int Nrows)
{
  const int lane = threadIdx.x & 63;
  const int r = blockIdx.x * 4 + (threadIdx.x >> 6);
  if (r >= Nrows) return;
  const int s = rowptr[r], e = rowptr[r + 1];
  float4 acc0 = make_float4(0.f, 0.f, 0.f, 0.f);
  float4 acc1 = make_float4(0.f, 0.f, 0.f, 0.f);
  int j = s;
  for (; j + 7 < e; j += 8) {
    int2 p[8];
    ushort4 d[8];
#pragma unroll
    for (int t = 0; t < 8; ++t) p[t] = sp[j + t];
#pragma unroll
    for (int t = 0; t < 8; ++t)
      d[t] = *(const ushort4*)&D[(size_t)p[t].x * 256 + lane * 4];
#pragma unroll
    for (int t = 0; t < 8; t += 2) {
      float v0 = __int_as_float(p[t].y), v1 = __int_as_float(p[t + 1].y);
      acc0.x = fmaf(v0, bf2f(d[t].x), acc0.x); acc0.y = fmaf(v0, bf2f(d[t].y), acc0.y);
      acc0.z = fmaf(v0, bf2f(d[t].z), acc0.z); acc0.w = fmaf(v0, bf2f(d[t].w), acc0.w);
      acc1.x = fmaf(v1, bf2f(d[t + 1].x), acc1.x); acc1.y = fmaf(v1, bf2f(d[t + 1].y), acc1.y);
      acc1.z = fmaf(v1, bf2f(d[t + 1].z), acc1.z); acc1.w = fmaf(v1, bf2f(d[t + 1].w), acc1.w);
    }
  }
  for (; j + 1 < e; j += 2) {
    int2 p0 = sp[j], p1 = sp[j + 1];
    ushort4 d0 = *(const ushort4*)&D[(size_t)p0.x * 256 + lane * 4];
    ushort4 d1 = *(const ushort4*)&D[(size_t)p1.x * 256 + lane * 4];
    float v0 = __int_as_float(p0.y), v1 = __int_as_float(p1.y);
    acc0.x = fmaf(v0, bf2f(d0.x), acc0.x); acc0.y = fmaf(v0, bf2f(d0.y), acc0.y);
    acc0.z = fmaf(v0, bf2f(d0.z), acc0.z); acc0.w = fmaf(v0, bf2f(d0.w), acc0.w);
    acc1.x = fmaf(v1, bf2f(d1.x), acc1.x); acc1.y = fmaf(v1, bf2f(d1.y), acc1.y);
    acc1.z = fmaf(v1, bf2f(d1.z), acc1.z); acc1.w = fmaf(v1, bf2f(d1.w), acc1.w);
  }
  if (j < e) {
    int2 p = sp[j];
    float v = __int_as_float(p.y);
    ushort4 d = *(const ushort4*)&D[(size_t)p.x * 256 + lane * 4];
    acc0.x = fmaf(v, bf2f(d.x), acc0.x); acc0.y = fmaf(v, bf2f(d.y), acc0.y);
    acc0.z = fmaf(v, bf2f(d.z), acc0.z); acc0.w = fmaf(v, bf2f(d.w), acc0.w);
  }
  ushort4 ov;
  ov.x = f2bf(acc0.x + acc1.x); ov.y = f2bf(acc0.y + acc1.y);
  ov.z = f2bf(acc0.z + acc1.z); ov.w = f2bf(acc0.w + acc1.w);
  *(ushort4*)&out[(size_t)r * 256 + lane * 4] = ov;
}

// ---------------- SpMM gather (bf16 D, F=64) -> fp32 out, 8-deep ILP -------------
__global__ __launch_bounds__(256) void spmm_gather_bf64(
    const int* __restrict__ rowptr, const int2* __restrict__ sp,
    const unsigned short* __restrict__ D,
    float* __restrict__ out, int Nrows)
{
  const int lane = threadIdx.x & 63;
  const int r = blockIdx.x * 4 + (threadIdx.x >> 6);
  if (r >= Nrows) return;
  const int s = rowptr[r], e = rowptr[r + 1];
  float acc0 = 0.f, acc1 = 0.f;
  int j = s;
  for (; j + 7 < e; j += 8) {
    int2 p[8];
    float d[8];
#pragma unroll
    for (int t = 0; t < 8; ++t) p[t] = sp[j + t];
#pragma unroll
    for (int t = 0; t < 8; ++t) d[t] = bf2f(D[(size_t)p[t].x * 64 + lane]);
#pragma unroll
    for (int t = 0; t < 8; t += 2) {
      acc0 = fmaf(__int_as_float(p[t].y), d[t], acc0);
      acc1 = fmaf(__int_as_float(p[t + 1].y), d[t + 1], acc1);
    }
  }
  for (; j < e; ++j) {
    int2 p = sp[j];
    acc0 = fmaf(__int_as_float(p.y), bf2f(D[(size_t)p.x * 64 + lane]), acc0);
  }
  out[(size_t)r * 64 + lane] = acc0 + acc1;
}

// ---------------- BN1 stats from bf16 H (C=256), per-block partials --------------
__global__ __launch_bounds__(256) void bn_stats_bf256(
    const unsigned short* __restrict__ H, float* __restrict__ partials, int Nrows)
{
  const int cc = threadIdx.x & 31;    // col chunk (8 cols)
  const int c = cc * 8;
  const int rr = threadIdx.x >> 5;    // 0..7
  float s[8] = {}, q[8] = {};
  for (int r = blockIdx.x * 8 + rr; r < Nrows; r += gridDim.x * 8) {
    ushort8 u = *(const ushort8*)&H[(size_t)r * 256 + c];
#pragma unroll
    for (int j = 0; j < 8; ++j) {
      float f = bf2f(u[j]);
      s[j] += f; q[j] += f * f;
    }
  }
  __shared__ float lds[256][16];
  float* L = lds[threadIdx.x];
#pragma unroll
  for (int j = 0; j < 8; ++j) { L[j] = s[j]; L[8 + j] = q[j]; }
  __syncthreads();
  if (rr == 0) {
#pragma unroll
    for (int r2 = 1; r2 < 8; ++r2) {
      float* Mm = lds[cc + r2 * 32];
#pragma unroll
      for (int j = 0; j < 8; ++j) { s[j] += Mm[j]; q[j] += Mm[8 + j]; }
    }
    float* P = &partials[(size_t)blockIdx.x * 512];
#pragma unroll
    for (int j = 0; j < 8; ++j) { P[c + j] = s[j]; P[256 + c + j] = q[j]; }
  }
}

// ---------------- BN stats fp32 (C=64), per-block partials -----------------------
__global__ __launch_bounds__(256) void bn_stats64(
    const float* __restrict__ H, float* __restrict__ partials, int Nrows)
{
  const int cc = threadIdx.x % 16;
  const int c = cc * 4;
  const int rr = threadIdx.x / 16;   // 0..15
  float4 s = make_float4(0.f, 0.f, 0.f, 0.f);
  float4 q = make_float4(0.f, 0.f, 0.f, 0.f);
  for (int r = blockIdx.x * 16 + rr; r < Nrows; r += gridDim.x * 16) {
    float4 v = *(const float4*)&H[(size_t)r * 64 + c];
    s.x += v.x; s.y += v.y; s.z += v.z; s.w += v.w;
    q.x += v.x * v.x; q.y += v.y * v.y; q.z += v.z * v.z; q.w += v.w * v.w;
  }
  __shared__ float lds[256][8];
  float* L = lds[threadIdx.x];
  L[0] = s.x; L[1] = s.y; L[2] = s.z; L[3] = s.w;
  L[4] = q.x; L[5] = q.y; L[6] = q.z; L[7] = q.w;
  __syncthreads();
  if (rr == 0) {
#pragma unroll
    for (int r2 = 1; r2 < 16; ++r2) {
      float* Mm = lds[cc + r2 * 16];
      s.x += Mm[0]; s.y += Mm[1]; s.z += Mm[2]; s.w += Mm[3];
      q.x += Mm[4]; q.y += Mm[5]; q.z += Mm[6]; q.w += Mm[7];
    }
    float* P = &partials[(size_t)blockIdx.x * 128];
    *(float4*)&P[c] = s;
    *(float4*)&P[64 + c] = q;
  }
}

// ---------------- BN finalize (parallel): one block per channel ------------------
template<int C>
__global__ __launch_bounds__(256) void bn_finalize_par(
    const float* __restrict__ partials,
    const float* __restrict__ gamma, const float* __restrict__ beta,
    float* __restrict__ scsh, int G, float invN)
{
  const int c = blockIdx.x;
  const int t = threadIdx.x;
  float sum = 0.f, sq = 0.f;
  for (int g = t; g < G; g += 256) {
    sum += partials[(size_t)g * 2 * C + c];
    sq  += partials[(size_t)g * 2 * C + C + c];
  }
#pragma unroll
  for (int off = 1; off < 64; off <<= 1) {
    sum += __shfl_xor(sum, off);
    sq  += __shfl_xor(sq, off);
  }
  __shared__ float ws[4][2];
  if ((t & 63) == 0) { ws[t >> 6][0] = sum; ws[t >> 6][1] = sq; }
  __syncthreads();
  if (t == 0) {
    sum = ws[0][0] + ws[1][0] + ws[2][0] + ws[3][0];
    sq  = ws[0][1] + ws[1][1] + ws[2][1] + ws[3][1];
    float mean = sum * invN;
    float var = sq * invN - mean * mean;
    float rstd = rsqrtf(var + 1e-5f);
    float sc = gamma[c] * rstd;
    scsh[c] = sc;
    scsh[C + c] = beta[c] - mean * sc;
  }
}

// ---------------- BN2 apply + log_softmax ----------------------------------------
__global__ __launch_bounds__(256) void bn_lsm(
    const float* __restrict__ H, const float* __restrict__ scsh,
    float* __restrict__ out, int Nrows)
{
  int lane = threadIdx.x & 63;
  int r = blockIdx.x * 4 + (threadIdx.x >> 6);
  if (r >= Nrows) return;
  float y = H[(size_t)r * 64 + lane] * scsh[lane] + scsh[64 + lane];
  float m = y;
#pragma unroll
  for (int off = 32; off >= 1; off >>= 1) m = fmaxf(m, __shfl_xor(m, off));
  float ex = expf(y - m);
  float s = ex;
#pragma unroll
  for (int off = 32; off >= 1; off >>= 1) s += __shfl_xor(s, off);
  out[(size_t)r * 64 + lane] = (y - m) - logf(s);
}

extern "C" void kernel_launch(void* const* d_in, const int* in_sizes, int n_in,
                              void* d_out, int out_size, void* d_ws, size_t ws_size,
                              hipStream_t stream) {
  const float* x      = (const float*)d_in[0];
  const int*   erow   = (const int*)  d_in[1];
  const int*   ecol   = (const int*)  d_in[2];
  const float* eval   = (const float*)d_in[3];
  const float* W1     = (const float*)d_in[4];
  // d_in[5] = b1 : cancels exactly in training-mode BN (shift-invariant)
  const float* gamma1 = (const float*)d_in[6];
  const float* beta1  = (const float*)d_in[7];
  const float* W2     = (const float*)d_in[8];
  // d_in[9] = b2 : cancels in BN2
  const float* gamma2 = (const float*)d_in[10];
  const float* beta2  = (const float*)d_in[11];

  const int N = in_sizes[0] / 512;   // 50000
  const int E = in_sizes[1];         // 800000

  char* ws = (char*)d_ws;
  unsigned short* H1b   = (unsigned short*)(ws + 0);
  float* partials1      = (float*)(ws + 0);
  unsigned short* H2b   = (unsigned short*)(ws + 0);
  float* H2AGG          = (float*)(ws + 12800000);
  unsigned short* H1AGGb= (unsigned short*)(ws + 51200000);
  float* partials2      = (float*)(ws + 51200000);
  unsigned short* w1t   = (unsigned short*)(ws + 76865536);   // 256 KB
  float* scsh1          = (float*)(ws + 77127680);            // 512 f
  float* scsh2          = (float*)(ws + 77129728);            // 128 f
  int*   rowptr         = (int*)(ws + 77130240);
  int*   cnt            = (int*)(ws + 77330244);
  int*   cursor         = (int*)(ws + 77530244);
  int2*  spack          = (int2*)(ws + 77730248);             // E * 8 B (8-aligned)
  int*   bsum           = (int*)(ws + 84130248);
  int*   boff           = (int*)(ws + 84131272);
  unsigned short* w2t   = (unsigned short*)(ws + 84132352);   // 32 KB

  hipMemsetAsync(cnt, 0, (size_t)N * 4, stream);

  const dim3 blk(256);
  const int eblocks = (E + 255) / 256;
  const int NB = (N + 255) / 256;   // 196 <= 256

  // CSR build
  edge_hist<<<eblocks, blk, 0, stream>>>(erow, cnt, E);
  scan_blocksum<<<NB, blk, 0, stream>>>(cnt, bsum, N);
  scan_boff<<<1, blk, 0, stream>>>(bsum, boff, NB);
  scan_write<<<NB + 1, blk, 0, stream>>>(cnt, boff, rowptr, cursor, N, E);
  edge_scatter<<<eblocks, blk, 0, stream>>>(erow, ecol, eval, cursor, spack, E);

  // weight conversions (one kernel)
  cvt_weights<<<576, blk, 0, stream>>>(W1, W2, w1t, w2t);

  // layer 1: H1 = x @ W1 (fp32 in, cast fused, bf16 out) — BK=32 dbuf pipeline
  gemm1_mfma<<<(N + 63) / 64, blk, 0, stream>>>(x, w1t, H1b, N);
  // H1AGG = A @ H1 (gather, bf16 out)
  spmm_gather_bf<<<(N + 3) / 4, blk, 0, stream>>>(rowptr, spack, H1b, H1AGGb, N);
  // BN1
  bn_stats_bf256<<<256, blk, 0, stream>>>(H1AGGb, partials1, N);
  bn_finalize_par<256><<<256, blk, 0, stream>>>(partials1, gamma1, beta1, scsh1, 256, 1.0f / N);
  // layer 2: H2 = relu(bn1(H1AGG)) @ W2 (MFMA, BN fused in A-stage, bf16 out)
  gemm2_mfma<<<(N + 127) / 128, blk, 0, stream>>>(H1AGGb, w2t, scsh1, H2b, N);
  // H2AGG = A @ H2 (gather from bf16, fp32 out)
  spmm_gather_bf64<<<(N + 3) / 4, blk, 0, stream>>>(rowptr, spack, H2b, H2AGG, N);
  // BN2
  bn_stats64<<<256, blk, 0, stream>>>(H2AGG, partials2, N);
  bn_finalize_par<64><<<64, blk, 0, stream>>>(partials2, gamma2, beta2, scsh2, 256, 1.0f / N);
  // BN2 apply + log_softmax
  bn_lsm<<<(N + 3) / 4, blk, 0, stream>>>(H2AGG, scsh2, (float*)d_out, N);
}